// Round 12
// baseline (481.305 us; speedup 1.0000x reference)
//
#include <hip/hip_runtime.h>
#include <hip/hip_bf16.h>
#include <math.h>

// Problem constants (fixed by the reference file)
#define BB 2
#define NN 21760
#define CC 256
#define HH 8
#define PP 21760
#define MROWS (BB * NN)   // 43520 query rows
#define VROWS (BB * PP)   // 43520 value rows

typedef __attribute__((ext_vector_type(8))) short bf16x8;
typedef __attribute__((ext_vector_type(4))) float f32x4;

__device__ __forceinline__ unsigned short f2bf(float f) {
  unsigned u = __float_as_uint(f);
  u += 0x7fff + ((u >> 16) & 1);   // RNE
  return (unsigned short)(u >> 16);
}
__device__ __forceinline__ float bf2f(unsigned short s) {
  return __uint_as_float(((unsigned)s) << 16);
}

// ---------------------------------------------------------------------------
// q, v fp32 -> bf16 (row-major, same shape)
// ---------------------------------------------------------------------------
__global__ __launch_bounds__(256) void conv_bf16(
    const float* __restrict__ q, const float* __restrict__ v,
    unsigned short* __restrict__ qb, unsigned short* __restrict__ vb) {
  size_t i = ((size_t)blockIdx.x * 256 + threadIdx.x) * 8;
  float4 a0 = *(const float4*)(q + i);
  float4 a1 = *(const float4*)(q + i + 4);
  ushort4 o0 = {f2bf(a0.x), f2bf(a0.y), f2bf(a0.z), f2bf(a0.w)};
  ushort4 o1 = {f2bf(a1.x), f2bf(a1.y), f2bf(a1.z), f2bf(a1.w)};
  *(ushort4*)(qb + i) = o0;
  *(ushort4*)(qb + i + 4) = o1;
  float4 b0 = *(const float4*)(v + i);
  float4 b1 = *(const float4*)(v + i + 4);
  ushort4 p0 = {f2bf(b0.x), f2bf(b0.y), f2bf(b0.z), f2bf(b0.w)};
  ushort4 p1 = {f2bf(b1.x), f2bf(b1.y), f2bf(b1.z), f2bf(b1.w)};
  *(ushort4*)(vb + i) = p0;
  *(ushort4*)(vb + i + 4) = p1;
}

// ---------------------------------------------------------------------------
// Weights -> transposed bf16 [N][K].  (Unchanged, proven.)
// ---------------------------------------------------------------------------
__global__ __launch_bounds__(256) void prep_all(
    const float* __restrict__ W_off, const float* __restrict__ W_at,
    const float* __restrict__ W_val,
    const float* __restrict__ W1, const float* __restrict__ W2,
    unsigned short* __restrict__ WoffT, unsigned short* __restrict__ WattnT,
    unsigned short* __restrict__ WvalT,
    unsigned short* __restrict__ W1T, unsigned short* __restrict__ W2T) {
  int i = blockIdx.x * 256 + threadIdx.x;
  if (i < 65536) {                    // WoffT[256][256]
    WoffT[i] = f2bf(W_off[(size_t)(i & 255) * 256 + (i >> 8)]);
  } else if (i < 98304) {             // WattnT[128][256]
    int j = i - 65536;
    WattnT[j] = f2bf(W_at[(size_t)(j & 255) * 128 + (j >> 8)]);
  } else if (i < 163840) {            // WvalT[256][256]
    int j = i - 98304;
    WvalT[j] = f2bf(W_val[(size_t)(j & 255) * 256 + (j >> 8)]);
  } else if (i < 425984) {            // W1T[1024][256]
    int j = i - 163840;
    W1T[j] = f2bf(W1[(size_t)(j & 255) * 1024 + (j >> 8)]);
  } else if (i < 688128) {            // W2T[256][1024]
    int j = i - 425984;
    W2T[j] = f2bf(W2[(size_t)(j & 1023) * 256 + (j >> 10)]);
  }
}

// ---------------------------------------------------------------------------
// W_out -> transposed bf16 [256][256]
// ---------------------------------------------------------------------------
__global__ __launch_bounds__(256) void prep_wout(
    const float* __restrict__ W_out, unsigned short* __restrict__ WoutT) {
  int i = blockIdx.x * 256 + threadIdx.x;   // grid 256 -> i < 65536
  WoutT[i] = f2bf(W_out[(size_t)(i & 255) * 256 + (i >> 8)]);
}

// ---------------------------------------------------------------------------
// Projection GEMM via bf16 MFMA: C[M][NC] = A[M][256] @ BT^T + bias
// 8 waves, 512 threads.  NC=256: M-tile 32; NC=128: M-tile 64.
// EPI: 0 = +bias -> fp32;  1 = +bias, softmax per 16-group -> bf16;
//      3 = +bias -> bf16
// ---------------------------------------------------------------------------
template <int NC, int EPI>
__global__ __launch_bounds__(512, 4) void proj_mfma(
    const unsigned short* __restrict__ A, const unsigned short* __restrict__ BT,
    const float* __restrict__ bias,
    float* __restrict__ outF, unsigned short* __restrict__ outB) {
  constexpr int MTILE = (NC == 128) ? 64 : 32;
  __shared__ __align__(16) char xs[MTILE * 512];

  const int row0 = blockIdx.x * MTILE;
  const int t = threadIdx.x;
  const int w = t >> 6, lane = t & 63;
  const int c = lane & 15, kg = lane >> 4;
  const int mbase = (NC == 128) ? (w >> 2) * 32 : 0;
  const int nbase = (NC == 128) ? (w & 3) * 32 : w * 32;

  // ---- stage A tile (bf16 global -> swizzled LDS) ----
  #pragma unroll
  for (int p = 0; p < MTILE / 16; ++p) {
    int i = t + p * 512;          // 16B chunk id
    int m = i >> 5, c16 = i & 31;
    ushort4 v0 = *(const ushort4*)(A + (size_t)(row0 + m) * 256 + c16 * 8);
    ushort4 v1 = *(const ushort4*)(A + (size_t)(row0 + m) * 256 + c16 * 8 + 4);
    int byte = (m * 512 + c16 * 16) ^ ((m & 7) << 4);
    *(ushort4*)(xs + byte) = v0;
    *(ushort4*)(xs + byte + 8) = v1;
  }
  __syncthreads();

  // ---- GEMM ----
  f32x4 acc[2][2];
  #pragma unroll
  for (int mf = 0; mf < 2; ++mf)
    #pragma unroll
    for (int nf = 0; nf < 2; ++nf) acc[mf][nf] = (f32x4){0.f, 0.f, 0.f, 0.f};
  #pragma unroll
  for (int kc = 0; kc < 8; ++kc) {
    int ab0 = ((mbase + c) * 512 + kc * 64 + kg * 16) ^ ((c & 7) << 4);
    int ab1 = ((mbase + 16 + c) * 512 + kc * 64 + kg * 16) ^ ((c & 7) << 4);
    bf16x8 a0 = *(const bf16x8*)(xs + ab0);
    bf16x8 a1 = *(const bf16x8*)(xs + ab1);
    #pragma unroll
    for (int nf = 0; nf < 2; ++nf) {
      bf16x8 b = *(const bf16x8*)(BT + (size_t)(nbase + nf * 16 + c) * 256 + kc * 32 + kg * 8);
      acc[0][nf] = __builtin_amdgcn_mfma_f32_16x16x32_bf16(a0, b, acc[0][nf], 0, 0, 0);
      acc[1][nf] = __builtin_amdgcn_mfma_f32_16x16x32_bf16(a1, b, acc[1][nf], 0, 0, 0);
    }
  }

  // ---- epilogue ----
  if (EPI == 0) {
    #pragma unroll
    for (int nf = 0; nf < 2; ++nf) {
      int n = nbase + nf * 16 + c;
      float bb = bias[n];
      #pragma unroll
      for (int mf = 0; mf < 2; ++mf)
        #pragma unroll
        for (int i = 0; i < 4; ++i) {
          int m = mbase + mf * 16 + kg * 4 + i;
          outF[(size_t)(row0 + m) * NC + n] = acc[mf][nf][i] + bb;
        }
    }
  } else if (EPI == 3) {
    #pragma unroll
    for (int nf = 0; nf < 2; ++nf) {
      int n = nbase + nf * 16 + c;
      float bb = bias[n];
      #pragma unroll
      for (int mf = 0; mf < 2; ++mf)
        #pragma unroll
        for (int i = 0; i < 4; ++i) {
          int m = mbase + mf * 16 + kg * 4 + i;
          outB[(size_t)(row0 + m) * NC + n] = f2bf(acc[mf][nf][i] + bb);
        }
    }
  } else {
    // softmax over 16-lane groups (one head's 16 logits per group)
    #pragma unroll
    for (int nf = 0; nf < 2; ++nf) {
      int n = nbase + nf * 16 + c;
      float bb = bias[n];
      #pragma unroll
      for (int mf = 0; mf < 2; ++mf)
        #pragma unroll
        for (int i = 0; i < 4; ++i) {
          float vv = acc[mf][nf][i] + bb;
          float mx = vv;
          mx = fmaxf(mx, __shfl_xor(mx, 1, 64));
          mx = fmaxf(mx, __shfl_xor(mx, 2, 64));
          mx = fmaxf(mx, __shfl_xor(mx, 4, 64));
          mx = fmaxf(mx, __shfl_xor(mx, 8, 64));
          float e = expf(vv - mx);
          float s = e;
          s += __shfl_xor(s, 1, 64);
          s += __shfl_xor(s, 2, 64);
          s += __shfl_xor(s, 4, 64);
          s += __shfl_xor(s, 8, 64);
          int m = mbase + mf * 16 + kg * 4 + i;
          outB[(size_t)(row0 + m) * NC + n] = f2bf(e / s);
        }
    }
  }
}

// ---------------------------------------------------------------------------
// Deformable sampling v5b: 4 queries/block, bf16 value gathers, bf16 out.
// ---------------------------------------------------------------------------
__global__ __launch_bounds__(256) void msda_sample(
    const unsigned short* __restrict__ value, const float* __restrict__ off,
    const unsigned short* __restrict__ aw, const float* __restrict__ refp,
    unsigned short* __restrict__ out) {
  __shared__ __align__(16) int4   s_idx[4 * 16 * 8];   // [qi][i][h]
  __shared__ __align__(16) float4 s_w[4 * 16 * 8];
  const int t = threadIdx.x;
  const int bn0 = blockIdx.x * 4;
  const int b = bn0 / NN;

  #pragma unroll
  for (int ss = 0; ss < 2; ++ss) {
    const int s = t + ss * 256;
    const int qi = s >> 7;
    const int j  = s & 127;         // h*16 + l*4 + k
    const int bn = bn0 + qi;
    const int l  = (j >> 2) & 3;
    const int h  = j >> 4;
    const int i  = j & 15;
    const int szl = 128 >> l;
    const int st0l = (l == 0) ? 0 : (l == 1) ? 16384 : (l == 2) ? 20480 : 21504;

    float ox = off[(size_t)bn * 256 + j * 2 + 0];
    float oy = off[(size_t)bn * 256 + j * 2 + 1];
    float a  = bf2f(aw[(size_t)bn * 128 + j]);
    float rx = refp[(size_t)bn * 8 + l * 2 + 0];
    float ry = refp[(size_t)bn * 8 + l * 2 + 1];

    float x = rx * (float)szl + ox - 0.5f;
    float y = ry * (float)szl + oy - 0.5f;
    float x0f = floorf(x), y0f = floorf(y);
    float wx = x - x0f, wy = y - y0f;
    int x0 = (int)x0f, y0 = (int)y0f;
    int x1 = x0 + 1, y1 = y0 + 1;

    bool vx0 = (x0 >= 0) & (x0 < szl);
    bool vx1 = (x1 >= 0) & (x1 < szl);
    bool vy0 = (y0 >= 0) & (y0 < szl);
    bool vy1 = (y1 >= 0) & (y1 < szl);
    int cx0 = min(max(x0, 0), szl - 1);
    int cx1 = min(max(x1, 0), szl - 1);
    int cy0 = min(max(y0, 0), szl - 1);
    int cy1 = min(max(y1, 0), szl - 1);

    int base = st0l * 256 + h * 32;
    int4 iv;
    iv.x = base + (cy0 * szl + cx0) * 256;
    iv.y = base + (cy0 * szl + cx1) * 256;
    iv.z = base + (cy1 * szl + cx0) * 256;
    iv.w = base + (cy1 * szl + cx1) * 256;
    float4 wv;
    wv.x = (vx0 & vy0) ? a * (1.f - wx) * (1.f - wy) : 0.f;
    wv.y = (vx1 & vy0) ? a * wx * (1.f - wy) : 0.f;
    wv.z = (vx0 & vy1) ? a * (1.f - wx) * wy : 0.f;
    wv.w = (vx1 & vy1) ? a * wx * wy : 0.f;

    int slot = (qi * 16 + i) * 8 + h;
    s_idx[slot] = iv;
    s_w[slot] = wv;
  }
  __syncthreads();

  const int qi = t >> 6;
  const int lane = t & 63;
  const int h = lane >> 3, d4 = lane & 7;
  const unsigned short* vcol = value + (size_t)b * PP * 256 + d4 * 4;

  float4 c0 = {0.f, 0.f, 0.f, 0.f}, c1 = {0.f, 0.f, 0.f, 0.f};
  float4 c2 = {0.f, 0.f, 0.f, 0.f}, c3 = {0.f, 0.f, 0.f, 0.f};
  #pragma unroll 4
  for (int i = 0; i < 16; ++i) {
    int slot = (qi * 16 + i) * 8 + h;
    int4 iv = s_idx[slot];
    float4 wv = s_w[slot];
    ushort4 u0 = *(const ushort4*)(vcol + iv.x);
    ushort4 u1 = *(const ushort4*)(vcol + iv.y);
    ushort4 u2 = *(const ushort4*)(vcol + iv.z);
    ushort4 u3 = *(const ushort4*)(vcol + iv.w);
    c0.x += wv.x * bf2f(u0.x); c0.y += wv.x * bf2f(u0.y);
    c0.z += wv.x * bf2f(u0.z); c0.w += wv.x * bf2f(u0.w);
    c1.x += wv.y * bf2f(u1.x); c1.y += wv.y * bf2f(u1.y);
    c1.z += wv.y * bf2f(u1.z); c1.w += wv.y * bf2f(u1.w);
    c2.x += wv.z * bf2f(u2.x); c2.y += wv.z * bf2f(u2.y);
    c2.z += wv.z * bf2f(u2.z); c2.w += wv.z * bf2f(u2.w);
    c3.x += wv.w * bf2f(u3.x); c3.y += wv.w * bf2f(u3.y);
    c3.z += wv.w * bf2f(u3.z); c3.w += wv.w * bf2f(u3.w);
  }
  float4 acc;
  acc.x = (c0.x + c1.x) + (c2.x + c3.x);
  acc.y = (c0.y + c1.y) + (c2.y + c3.y);
  acc.z = (c0.z + c1.z) + (c2.z + c3.z);
  acc.w = (c0.w + c1.w) + (c2.w + c3.w);
  ushort4 ob = {f2bf(acc.x), f2bf(acc.y), f2bf(acc.z), f2bf(acc.w)};
  *(ushort4*)(out + (size_t)(bn0 + qi) * 256 + h * 32 + d4 * 4) = ob;
}

// ---------------------------------------------------------------------------
// Residual + LayerNorm1: x = LN(attn + 2q) * g + be.  One wave per row.
// ---------------------------------------------------------------------------
__global__ __launch_bounds__(256) void resid_ln(
    const float* __restrict__ A, const float* __restrict__ q,
    const float* __restrict__ g, const float* __restrict__ be,
    float* __restrict__ X) {
  const int row = blockIdx.x * 4 + (threadIdx.x >> 6);
  const int lane = threadIdx.x & 63;
  const size_t base = (size_t)row * 256 + lane * 4;
  float4 a = *(const float4*)(A + base);
  float4 qv = *(const float4*)(q + base);
  float4 v;
  v.x = a.x + 2.f * qv.x;
  v.y = a.y + 2.f * qv.y;
  v.z = a.z + 2.f * qv.z;
  v.w = a.w + 2.f * qv.w;
  float s = v.x + v.y + v.z + v.w;
  float s2 = v.x * v.x + v.y * v.y + v.z * v.z + v.w * v.w;
  #pragma unroll
  for (int o = 1; o < 64; o <<= 1) {
    s += __shfl_xor(s, o, 64);
    s2 += __shfl_xor(s2, o, 64);
  }
  float mean = s * (1.f / 256.f);
  float var = s2 * (1.f / 256.f) - mean * mean;
  float rstd = rsqrtf(var + 1e-5f);
  float4 gv = *(const float4*)(g + lane * 4);
  float4 bev = *(const float4*)(be + lane * 4);
  float4 o4;
  o4.x = (v.x - mean) * rstd * gv.x + bev.x;
  o4.y = (v.y - mean) * rstd * gv.y + bev.y;
  o4.z = (v.z - mean) * rstd * gv.z + bev.z;
  o4.w = (v.w - mean) * rstd * gv.w + bev.w;
  *(float4*)(X + base) = o4;
}

// ---------------------------------------------------------------------------
// Fused FFN v4: M-tile=64, 8 waves, hidden in 4 quarters of 256 through a
// 32KB hs buffer.  Each W-fragment load feeds 4 MFMAs (was 2) -> 2x
// arithmetic intensity per L2 load.  acc2[4][2] persists across quarters.
// LDS: xs 32KB + hs 32KB; out_s [64][260] f32 aliases both.  ~65KB -> 2/CU.
// ---------------------------------------------------------------------------
__global__ __launch_bounds__(512, 4) void ffn_mfma(
    const float* __restrict__ X, const unsigned short* __restrict__ W1T,
    const float* __restrict__ b1, const unsigned short* __restrict__ W2T,
    const float* __restrict__ b2, const float* __restrict__ g2,
    const float* __restrict__ be2, float* __restrict__ Out) {
  __shared__ __align__(16) char smem[66560];   // max(32K+32K, 64*260*4)
  char* xs = smem;              // [64][512B] bf16 X tile, swizzled
  char* hs = smem + 32768;      // [64][512B] bf16 quarter-hidden, swizzled
  float* out_s = (float*)smem;  // [64][260] f32, aliases xs+hs

  const int row0 = blockIdx.x * 64;
  const int t = threadIdx.x;
  const int w = t >> 6, lane = t & 63;
  const int c = lane & 15, kg = lane >> 4;

  // ---- stage X tile (fp32 -> bf16 swizzled LDS), 64x256 ----
  for (int i = t; i < 8192; i += 512) {
    int m = i >> 7;
    int np = i & 127;
    float2 xv = *(const float2*)(X + (size_t)(row0 + m) * 256 + np * 2);
    unsigned pk = (unsigned)f2bf(xv.x) | ((unsigned)f2bf(xv.y) << 16);
    int byte = (m * 512 + np * 4) ^ ((m & 7) << 4);
    *(unsigned*)(xs + byte) = pk;
  }
  __syncthreads();

  f32x4 acc2[4][2];   // persistent GEMM2 accumulator across quarters
  #pragma unroll
  for (int mf = 0; mf < 4; ++mf)
    #pragma unroll
    for (int nf = 0; nf < 2; ++nf) acc2[mf][nf] = (f32x4){0.f, 0.f, 0.f, 0.f};

  #pragma unroll
  for (int qq = 0; qq < 4; ++qq) {
    // ---- GEMM1 quarter: hid[64][256] = relu(X @ W1[:, qq*256..]) ----
    // wave w owns local cols [32w, 32w+32); each B-load feeds 4 MFMAs
    f32x4 acc1[4][2];
    #pragma unroll
    for (int mf = 0; mf < 4; ++mf)
      #pragma unroll
      for (int nf = 0; nf < 2; ++nf) acc1[mf][nf] = (f32x4){0.f, 0.f, 0.f, 0.f};
    #pragma unroll
    for (int kc = 0; kc < 8; ++kc) {
      bf16x8 a[4];
      #pragma unroll
      for (int mf = 0; mf < 4; ++mf) {
        int ab = ((mf * 16 + c) * 512 + kc * 64 + kg * 16) ^ ((c & 7) << 4);
        a[mf] = *(const bf16x8*)(xs + ab);
      }
      const unsigned short* wp = W1T + (size_t)(qq * 256 + w * 32) * 256 + kc * 32 + kg * 8;
      #pragma unroll
      for (int nf = 0; nf < 2; ++nf) {
        bf16x8 b = *(const bf16x8*)(wp + (size_t)(nf * 16 + c) * 256);
        #pragma unroll
        for (int mf = 0; mf < 4; ++mf)
          acc1[mf][nf] = __builtin_amdgcn_mfma_f32_16x16x32_bf16(a[mf], b, acc1[mf][nf], 0, 0, 0);
      }
    }
    __syncthreads();   // prior quarter's GEMM2 hs reads complete
    // store quarter-hidden: relu(acc1 + b1) -> hs bf16, swizzled
    #pragma unroll
    for (int nf = 0; nf < 2; ++nf) {
      int nl = w * 32 + nf * 16 + c;           // local col 0..255
      float bb = b1[qq * 256 + nl];
      #pragma unroll
      for (int mf = 0; mf < 4; ++mf) {
        #pragma unroll
        for (int i = 0; i < 4; ++i) {
          int m = mf * 16 + kg * 4 + i;
          float v = fmaxf(acc1[mf][nf][i] + bb, 0.f);
          int byte = (m * 512 + nl * 2) ^ ((m & 7) << 4);
          *(unsigned short*)(hs + byte) = f2bf(v);
        }
      }
    }
    __syncthreads();

    // ---- GEMM2 quarter: acc2 += hid_q @ W2[qq*256.., :] ----
    #pragma unroll
    for (int kc = 0; kc < 8; ++kc) {
      bf16x8 a[4];
      #pragma unroll
      for (int mf = 0; mf < 4; ++mf) {
        int ab = ((mf * 16 + c) * 512 + kc * 64 + kg * 16) ^ ((c & 7) << 4);
        a[mf] = *(const bf16x8*)(hs + ab);
      }
      const unsigned short* wp = W2T + (size_t)(w * 32) * 1024 + qq * 256 + kc * 32 + kg * 8;
      #pragma unroll
      for (int nf = 0; nf < 2; ++nf) {
        bf16x8 b = *(const bf16x8*)(wp + (size_t)(nf * 16 + c) * 1024);
        #pragma unroll
        for (int mf = 0; mf < 4; ++mf)
          acc2[mf][nf] = __builtin_amdgcn_mfma_f32_16x16x32_bf16(a[mf], b, acc2[mf][nf], 0, 0, 0);
      }
    }
  }
  __syncthreads();   // all hs/xs reads complete before out_s overwrites

  // ---- epilogue: + b2 + residual(X fp32) -> out_s ----
  #pragma unroll
  for (int nf = 0; nf < 2; ++nf) {
    int n2 = w * 32 + nf * 16 + c;
    float bb = b2[n2];
    #pragma unroll
    for (int mf = 0; mf < 4; ++mf) {
      #pragma unroll
      for (int i = 0; i < 4; ++i) {
        int m = mf * 16 + kg * 4 + i;
        out_s[m * 260 + n2] = acc2[mf][nf][i] + bb + X[(size_t)(row0 + m) * 256 + n2];
      }
    }
  }
  __syncthreads();

  // ---- LayerNorm2 per row, one wave handles 8 rows ----
  float4 gv = *(const float4*)(g2 + lane * 4);
  float4 bev = *(const float4*)(be2 + lane * 4);
  #pragma unroll
  for (int rr = 0; rr < 8; ++rr) {
    int r = w * 8 + rr;
    float4 v = *(const float4*)(out_s + r * 260 + lane * 4);
    float s = v.x + v.y + v.z + v.w;
    float s2 = v.x * v.x + v.y * v.y + v.z * v.z + v.w * v.w;
    #pragma unroll
    for (int o = 1; o < 64; o <<= 1) {
      s += __shfl_xor(s, o, 64);
      s2 += __shfl_xor(s2, o, 64);
    }
    float mean = s * (1.f / 256.f);
    float var = s2 * (1.f / 256.f) - mean * mean;
    float rstd = rsqrtf(var + 1e-5f);
    float4 o4;
    o4.x = (v.x - mean) * rstd * gv.x + bev.x;
    o4.y = (v.y - mean) * rstd * gv.y + bev.y;
    o4.z = (v.z - mean) * rstd * gv.z + bev.z;
    o4.w = (v.w - mean) * rstd * gv.w + bev.w;
    *(float4*)(Out + (size_t)(row0 + r) * 256 + lane * 4) = o4;
  }
}

// ---------------------------------------------------------------------------
// Launch
// ---------------------------------------------------------------------------
extern "C" void kernel_launch(void* const* d_in, const int* in_sizes, int n_in,
                              void* d_out, int out_size, void* d_ws, size_t ws_size,
                              hipStream_t stream) {
  const float* q     = (const float*)d_in[0];
  const float* v     = (const float*)d_in[2];
  const float* refp  = (const float*)d_in[3];
  const float* W_off = (const float*)d_in[6];
  const float* b_off = (const float*)d_in[7];
  const float* W_at  = (const float*)d_in[8];
  const float* b_at  = (const float*)d_in[9];
  const float* W_val = (const float*)d_in[10];
  const float* b_val = (const float*)d_in[11];
  const float* W_out = (const float*)d_in[12];
  const float* b_out = (const float*)d_in[13];
  const float* W1    = (const float*)d_in[14];
  const float* b1    = (const float*)d_in[15];
  const float* W2    = (const float*)d_in[16];
  const float* b2    = (const float*)d_in[17];
  const float* g1    = (const float*)d_in[18];
  const float* be1   = (const float*)d_in[19];
  const float* g2    = (const float*)d_in[20];
  const float* be2   = (const float*)d_in[21];
  float* out = (float*)d_out;

  // Workspace layout (same as R11)
  float* ws   = (float*)d_ws;
  float* valb = ws;                                   // fp32 [M][256] region
  unsigned short* valbB = (unsigned short*)valb;      // bf16 [M][256] (first half)
  float* offb = valb + (size_t)VROWS * 256;           // fp32 [M][256]
  unsigned short* qb = (unsigned short*)(offb + (size_t)MROWS * 256); // bf16 [M][256]
  unsigned short* vb = qb + (size_t)MROWS * 256;      // bf16 [M][256]
  unsigned short* msdaB = qb;                         // alias: qb dead before msda
  unsigned short* awb = vb + (size_t)MROWS * 256;     // bf16 [M][128]
  unsigned short* WoffT  = awb + (size_t)MROWS * 128; // [256][256]
  unsigned short* WattnT = WoffT + 65536;             // [128][256]
  unsigned short* WvalT  = WattnT + 32768;            // [256][256]
  unsigned short* W1T    = WvalT + 65536;             // [1024][256]
  unsigned short* W2T    = W1T + 262144;              // [256][1024]
  unsigned short* WoutT  = W2T + 262144;              // [256][256] (appended)
  float* attnb = offb;                                // alias: offb dead after msda
  float* xb = valb;                                   // alias: valbB dead after msda

  conv_bf16<<<MROWS * 256 / (256 * 8), 256, 0, stream>>>(q, v, qb, vb);
  prep_all<<<2688, 256, 0, stream>>>(W_off, W_at, W_val, W1, W2,
                                     WoffT, WattnT, WvalT, W1T, W2T);
  prep_wout<<<256, 256, 0, stream>>>(W_out, WoutT);
  // value projection (bf16 out for bf16 sampling)
  proj_mfma<256, 3><<<MROWS / 32, 512, 0, stream>>>(vb, WvalT, b_val, nullptr, valbB);
  // offset projection
  proj_mfma<256, 0><<<MROWS / 32, 512, 0, stream>>>(qb, WoffT, b_off, offb, nullptr);
  // attention-weight projection + softmax (bf16 out)
  proj_mfma<128, 1><<<MROWS / 64, 512, 0, stream>>>(qb, WattnT, b_at, nullptr, awb);
  // deformable bilinear sampling (bf16 value in, bf16 out)
  msda_sample<<<MROWS / 4, 256, 0, stream>>>(valbB, offb, awb, refp, msdaB);
  // out-projection via proven EPI=0 core -> attn + b_out (fp32, into dead offb)
  proj_mfma<256, 0><<<MROWS / 32, 512, 0, stream>>>(msdaB, WoutT, b_out, attnb, nullptr);
  // residual + LayerNorm1
  resid_ln<<<MROWS / 4, 256, 0, stream>>>(attnb, q, g1, be1, xb);
  // fused FFN v4 (M=64, quarter-hidden) + residual + LayerNorm2
  ffn_mfma<<<MROWS / 64, 512, 0, stream>>>(xb, W1T, b1, W2T, b2, g2, be2, out);
}

// Round 13
// 464.166 us; speedup vs baseline: 1.0369x; 1.0369x over previous
//
#include <hip/hip_runtime.h>
#include <hip/hip_bf16.h>
#include <math.h>

// Problem constants (fixed by the reference file)
#define BB 2
#define NN 21760
#define CC 256
#define HH 8
#define PP 21760
#define MROWS (BB * NN)   // 43520 query rows
#define VROWS (BB * PP)   // 43520 value rows

typedef __attribute__((ext_vector_type(8))) short bf16x8;
typedef __attribute__((ext_vector_type(4))) float f32x4;

__device__ __forceinline__ unsigned short f2bf(float f) {
  unsigned u = __float_as_uint(f);
  u += 0x7fff + ((u >> 16) & 1);   // RNE
  return (unsigned short)(u >> 16);
}
__device__ __forceinline__ float bf2f(unsigned short s) {
  return __uint_as_float(((unsigned)s) << 16);
}

// ---------------------------------------------------------------------------
// q, v fp32 -> bf16 (row-major, same shape)
// ---------------------------------------------------------------------------
__global__ __launch_bounds__(256) void conv_bf16(
    const float* __restrict__ q, const float* __restrict__ v,
    unsigned short* __restrict__ qb, unsigned short* __restrict__ vb) {
  size_t i = ((size_t)blockIdx.x * 256 + threadIdx.x) * 8;
  float4 a0 = *(const float4*)(q + i);
  float4 a1 = *(const float4*)(q + i + 4);
  ushort4 o0 = {f2bf(a0.x), f2bf(a0.y), f2bf(a0.z), f2bf(a0.w)};
  ushort4 o1 = {f2bf(a1.x), f2bf(a1.y), f2bf(a1.z), f2bf(a1.w)};
  *(ushort4*)(qb + i) = o0;
  *(ushort4*)(qb + i + 4) = o1;
  float4 b0 = *(const float4*)(v + i);
  float4 b1 = *(const float4*)(v + i + 4);
  ushort4 p0 = {f2bf(b0.x), f2bf(b0.y), f2bf(b0.z), f2bf(b0.w)};
  ushort4 p1 = {f2bf(b1.x), f2bf(b1.y), f2bf(b1.z), f2bf(b1.w)};
  *(ushort4*)(vb + i) = p0;
  *(ushort4*)(vb + i + 4) = p1;
}

// ---------------------------------------------------------------------------
// Weights -> transposed bf16 [N][K].  (Unchanged, proven.)
// ---------------------------------------------------------------------------
__global__ __launch_bounds__(256) void prep_all(
    const float* __restrict__ W_off, const float* __restrict__ W_at,
    const float* __restrict__ W_val,
    const float* __restrict__ W1, const float* __restrict__ W2,
    unsigned short* __restrict__ WoffT, unsigned short* __restrict__ WattnT,
    unsigned short* __restrict__ WvalT,
    unsigned short* __restrict__ W1T, unsigned short* __restrict__ W2T) {
  int i = blockIdx.x * 256 + threadIdx.x;
  if (i < 65536) {                    // WoffT[256][256]
    WoffT[i] = f2bf(W_off[(size_t)(i & 255) * 256 + (i >> 8)]);
  } else if (i < 98304) {             // WattnT[128][256]
    int j = i - 65536;
    WattnT[j] = f2bf(W_at[(size_t)(j & 255) * 128 + (j >> 8)]);
  } else if (i < 163840) {            // WvalT[256][256]
    int j = i - 98304;
    WvalT[j] = f2bf(W_val[(size_t)(j & 255) * 256 + (j >> 8)]);
  } else if (i < 425984) {            // W1T[1024][256]
    int j = i - 163840;
    W1T[j] = f2bf(W1[(size_t)(j & 255) * 1024 + (j >> 8)]);
  } else if (i < 688128) {            // W2T[256][1024]
    int j = i - 425984;
    W2T[j] = f2bf(W2[(size_t)(j & 1023) * 256 + (j >> 10)]);
  }
}

// ---------------------------------------------------------------------------
// W_out -> transposed bf16 [256][256]
// ---------------------------------------------------------------------------
__global__ __launch_bounds__(256) void prep_wout(
    const float* __restrict__ W_out, unsigned short* __restrict__ WoutT) {
  int i = blockIdx.x * 256 + threadIdx.x;   // grid 256 -> i < 65536
  WoutT[i] = f2bf(W_out[(size_t)(i & 255) * 256 + (i >> 8)]);
}

// ---------------------------------------------------------------------------
// Projection GEMM via bf16 MFMA: C[M][NC] = A[M][256] @ BT^T + bias
// 8 waves, 512 threads.  NC=256: M-tile 32; NC=128: M-tile 64.
// EPI: 0 = +bias -> fp32;  1 = +bias, softmax per 16-group -> bf16;
//      3 = +bias -> bf16
// ---------------------------------------------------------------------------
template <int NC, int EPI>
__global__ __launch_bounds__(512, 4) void proj_mfma(
    const unsigned short* __restrict__ A, const unsigned short* __restrict__ BT,
    const float* __restrict__ bias,
    float* __restrict__ outF, unsigned short* __restrict__ outB) {
  constexpr int MTILE = (NC == 128) ? 64 : 32;
  __shared__ __align__(16) char xs[MTILE * 512];

  const int row0 = blockIdx.x * MTILE;
  const int t = threadIdx.x;
  const int w = t >> 6, lane = t & 63;
  const int c = lane & 15, kg = lane >> 4;
  const int mbase = (NC == 128) ? (w >> 2) * 32 : 0;
  const int nbase = (NC == 128) ? (w & 3) * 32 : w * 32;

  // ---- stage A tile (bf16 global -> swizzled LDS) ----
  #pragma unroll
  for (int p = 0; p < MTILE / 16; ++p) {
    int i = t + p * 512;          // 16B chunk id
    int m = i >> 5, c16 = i & 31;
    ushort4 v0 = *(const ushort4*)(A + (size_t)(row0 + m) * 256 + c16 * 8);
    ushort4 v1 = *(const ushort4*)(A + (size_t)(row0 + m) * 256 + c16 * 8 + 4);
    int byte = (m * 512 + c16 * 16) ^ ((m & 7) << 4);
    *(ushort4*)(xs + byte) = v0;
    *(ushort4*)(xs + byte + 8) = v1;
  }
  __syncthreads();

  // ---- GEMM ----
  f32x4 acc[2][2];
  #pragma unroll
  for (int mf = 0; mf < 2; ++mf)
    #pragma unroll
    for (int nf = 0; nf < 2; ++nf) acc[mf][nf] = (f32x4){0.f, 0.f, 0.f, 0.f};
  #pragma unroll
  for (int kc = 0; kc < 8; ++kc) {
    int ab0 = ((mbase + c) * 512 + kc * 64 + kg * 16) ^ ((c & 7) << 4);
    int ab1 = ((mbase + 16 + c) * 512 + kc * 64 + kg * 16) ^ ((c & 7) << 4);
    bf16x8 a0 = *(const bf16x8*)(xs + ab0);
    bf16x8 a1 = *(const bf16x8*)(xs + ab1);
    #pragma unroll
    for (int nf = 0; nf < 2; ++nf) {
      bf16x8 b = *(const bf16x8*)(BT + (size_t)(nbase + nf * 16 + c) * 256 + kc * 32 + kg * 8);
      acc[0][nf] = __builtin_amdgcn_mfma_f32_16x16x32_bf16(a0, b, acc[0][nf], 0, 0, 0);
      acc[1][nf] = __builtin_amdgcn_mfma_f32_16x16x32_bf16(a1, b, acc[1][nf], 0, 0, 0);
    }
  }

  // ---- epilogue ----
  if (EPI == 0) {
    #pragma unroll
    for (int nf = 0; nf < 2; ++nf) {
      int n = nbase + nf * 16 + c;
      float bb = bias[n];
      #pragma unroll
      for (int mf = 0; mf < 2; ++mf)
        #pragma unroll
        for (int i = 0; i < 4; ++i) {
          int m = mbase + mf * 16 + kg * 4 + i;
          outF[(size_t)(row0 + m) * NC + n] = acc[mf][nf][i] + bb;
        }
    }
  } else if (EPI == 3) {
    #pragma unroll
    for (int nf = 0; nf < 2; ++nf) {
      int n = nbase + nf * 16 + c;
      float bb = bias[n];
      #pragma unroll
      for (int mf = 0; mf < 2; ++mf)
        #pragma unroll
        for (int i = 0; i < 4; ++i) {
          int m = mbase + mf * 16 + kg * 4 + i;
          outB[(size_t)(row0 + m) * NC + n] = f2bf(acc[mf][nf][i] + bb);
        }
    }
  } else {
    // softmax over 16-lane groups (one head's 16 logits per group)
    #pragma unroll
    for (int nf = 0; nf < 2; ++nf) {
      int n = nbase + nf * 16 + c;
      float bb = bias[n];
      #pragma unroll
      for (int mf = 0; mf < 2; ++mf)
        #pragma unroll
        for (int i = 0; i < 4; ++i) {
          float vv = acc[mf][nf][i] + bb;
          float mx = vv;
          mx = fmaxf(mx, __shfl_xor(mx, 1, 64));
          mx = fmaxf(mx, __shfl_xor(mx, 2, 64));
          mx = fmaxf(mx, __shfl_xor(mx, 4, 64));
          mx = fmaxf(mx, __shfl_xor(mx, 8, 64));
          float e = expf(vv - mx);
          float s = e;
          s += __shfl_xor(s, 1, 64);
          s += __shfl_xor(s, 2, 64);
          s += __shfl_xor(s, 4, 64);
          s += __shfl_xor(s, 8, 64);
          int m = mbase + mf * 16 + kg * 4 + i;
          outB[(size_t)(row0 + m) * NC + n] = f2bf(e / s);
        }
    }
  }
}

// ---------------------------------------------------------------------------
// Deformable sampling v5b: 4 queries/block, bf16 value gathers, bf16 out.
// ---------------------------------------------------------------------------
__global__ __launch_bounds__(256) void msda_sample(
    const unsigned short* __restrict__ value, const float* __restrict__ off,
    const unsigned short* __restrict__ aw, const float* __restrict__ refp,
    unsigned short* __restrict__ out) {
  __shared__ __align__(16) int4   s_idx[4 * 16 * 8];   // [qi][i][h]
  __shared__ __align__(16) float4 s_w[4 * 16 * 8];
  const int t = threadIdx.x;
  const int bn0 = blockIdx.x * 4;
  const int b = bn0 / NN;

  #pragma unroll
  for (int ss = 0; ss < 2; ++ss) {
    const int s = t + ss * 256;
    const int qi = s >> 7;
    const int j  = s & 127;         // h*16 + l*4 + k
    const int bn = bn0 + qi;
    const int l  = (j >> 2) & 3;
    const int h  = j >> 4;
    const int i  = j & 15;
    const int szl = 128 >> l;
    const int st0l = (l == 0) ? 0 : (l == 1) ? 16384 : (l == 2) ? 20480 : 21504;

    float ox = off[(size_t)bn * 256 + j * 2 + 0];
    float oy = off[(size_t)bn * 256 + j * 2 + 1];
    float a  = bf2f(aw[(size_t)bn * 128 + j]);
    float rx = refp[(size_t)bn * 8 + l * 2 + 0];
    float ry = refp[(size_t)bn * 8 + l * 2 + 1];

    float x = rx * (float)szl + ox - 0.5f;
    float y = ry * (float)szl + oy - 0.5f;
    float x0f = floorf(x), y0f = floorf(y);
    float wx = x - x0f, wy = y - y0f;
    int x0 = (int)x0f, y0 = (int)y0f;
    int x1 = x0 + 1, y1 = y0 + 1;

    bool vx0 = (x0 >= 0) & (x0 < szl);
    bool vx1 = (x1 >= 0) & (x1 < szl);
    bool vy0 = (y0 >= 0) & (y0 < szl);
    bool vy1 = (y1 >= 0) & (y1 < szl);
    int cx0 = min(max(x0, 0), szl - 1);
    int cx1 = min(max(x1, 0), szl - 1);
    int cy0 = min(max(y0, 0), szl - 1);
    int cy1 = min(max(y1, 0), szl - 1);

    int base = st0l * 256 + h * 32;
    int4 iv;
    iv.x = base + (cy0 * szl + cx0) * 256;
    iv.y = base + (cy0 * szl + cx1) * 256;
    iv.z = base + (cy1 * szl + cx0) * 256;
    iv.w = base + (cy1 * szl + cx1) * 256;
    float4 wv;
    wv.x = (vx0 & vy0) ? a * (1.f - wx) * (1.f - wy) : 0.f;
    wv.y = (vx1 & vy0) ? a * wx * (1.f - wy) : 0.f;
    wv.z = (vx0 & vy1) ? a * (1.f - wx) * wy : 0.f;
    wv.w = (vx1 & vy1) ? a * wx * wy : 0.f;

    int slot = (qi * 16 + i) * 8 + h;
    s_idx[slot] = iv;
    s_w[slot] = wv;
  }
  __syncthreads();

  const int qi = t >> 6;
  const int lane = t & 63;
  const int h = lane >> 3, d4 = lane & 7;
  const unsigned short* vcol = value + (size_t)b * PP * 256 + d4 * 4;

  float4 c0 = {0.f, 0.f, 0.f, 0.f}, c1 = {0.f, 0.f, 0.f, 0.f};
  float4 c2 = {0.f, 0.f, 0.f, 0.f}, c3 = {0.f, 0.f, 0.f, 0.f};
  #pragma unroll 4
  for (int i = 0; i < 16; ++i) {
    int slot = (qi * 16 + i) * 8 + h;
    int4 iv = s_idx[slot];
    float4 wv = s_w[slot];
    ushort4 u0 = *(const ushort4*)(vcol + iv.x);
    ushort4 u1 = *(const ushort4*)(vcol + iv.y);
    ushort4 u2 = *(const ushort4*)(vcol + iv.z);
    ushort4 u3 = *(const ushort4*)(vcol + iv.w);
    c0.x += wv.x * bf2f(u0.x); c0.y += wv.x * bf2f(u0.y);
    c0.z += wv.x * bf2f(u0.z); c0.w += wv.x * bf2f(u0.w);
    c1.x += wv.y * bf2f(u1.x); c1.y += wv.y * bf2f(u1.y);
    c1.z += wv.y * bf2f(u1.z); c1.w += wv.y * bf2f(u1.w);
    c2.x += wv.z * bf2f(u2.x); c2.y += wv.z * bf2f(u2.y);
    c2.z += wv.z * bf2f(u2.z); c2.w += wv.z * bf2f(u2.w);
    c3.x += wv.w * bf2f(u3.x); c3.y += wv.w * bf2f(u3.y);
    c3.z += wv.w * bf2f(u3.z); c3.w += wv.w * bf2f(u3.w);
  }
  float4 acc;
  acc.x = (c0.x + c1.x) + (c2.x + c3.x);
  acc.y = (c0.y + c1.y) + (c2.y + c3.y);
  acc.z = (c0.z + c1.z) + (c2.z + c3.z);
  acc.w = (c0.w + c1.w) + (c2.w + c3.w);
  ushort4 ob = {f2bf(acc.x), f2bf(acc.y), f2bf(acc.z), f2bf(acc.w)};
  *(ushort4*)(out + (size_t)(bn0 + qi) * 256 + h * 32 + d4 * 4) = ob;
}

// ---------------------------------------------------------------------------
// Residual + LayerNorm1: x = LN(attn + 2q) * g + be.  One wave per row.
// ---------------------------------------------------------------------------
__global__ __launch_bounds__(256) void resid_ln(
    const float* __restrict__ A, const float* __restrict__ q,
    const float* __restrict__ g, const float* __restrict__ be,
    float* __restrict__ X) {
  const int row = blockIdx.x * 4 + (threadIdx.x >> 6);
  const int lane = threadIdx.x & 63;
  const size_t base = (size_t)row * 256 + lane * 4;
  float4 a = *(const float4*)(A + base);
  float4 qv = *(const float4*)(q + base);
  float4 v;
  v.x = a.x + 2.f * qv.x;
  v.y = a.y + 2.f * qv.y;
  v.z = a.z + 2.f * qv.z;
  v.w = a.w + 2.f * qv.w;
  float s = v.x + v.y + v.z + v.w;
  float s2 = v.x * v.x + v.y * v.y + v.z * v.z + v.w * v.w;
  #pragma unroll
  for (int o = 1; o < 64; o <<= 1) {
    s += __shfl_xor(s, o, 64);
    s2 += __shfl_xor(s2, o, 64);
  }
  float mean = s * (1.f / 256.f);
  float var = s2 * (1.f / 256.f) - mean * mean;
  float rstd = rsqrtf(var + 1e-5f);
  float4 gv = *(const float4*)(g + lane * 4);
  float4 bev = *(const float4*)(be + lane * 4);
  float4 o4;
  o4.x = (v.x - mean) * rstd * gv.x + bev.x;
  o4.y = (v.y - mean) * rstd * gv.y + bev.y;
  o4.z = (v.z - mean) * rstd * gv.z + bev.z;
  o4.w = (v.w - mean) * rstd * gv.w + bev.w;
  *(float4*)(X + base) = o4;
}

// ---------------------------------------------------------------------------
// Fused FFN v2 (proven structure) with __launch_bounds__(512,3):
// raises the unified-register cap (~170) so the scheduler can keep more
// streamed W-fragments in flight.  Occupancy is already reg-capped at
// 3 waves/SIMD (acc1 64 AGPR + acc2 16 AGPR + 64 VGPR = 144), so the
// higher cap costs nothing.  M-tile=32, 8 waves, LDS 80KB.
// ---------------------------------------------------------------------------
__global__ __launch_bounds__(512, 3) void ffn_mfma(
    const float* __restrict__ X, const unsigned short* __restrict__ W1T,
    const float* __restrict__ b1, const unsigned short* __restrict__ W2T,
    const float* __restrict__ b2, const float* __restrict__ g2,
    const float* __restrict__ be2, float* __restrict__ Out) {
  __shared__ __align__(16) char smem[16384 + 65536];
  char* xs = smem;            // 32 x 512 B
  char* hs = smem + 16384;    // 32 x 2048 B
  float* out_s = (float*)(smem + 16384);   // 32 x 260 f32, aliases hs

  const int row0 = blockIdx.x * 32;
  const int t = threadIdx.x;
  const int w = t >> 6, lane = t & 63;
  const int c = lane & 15, kg = lane >> 4;

  for (int i = t; i < 4096; i += 512) {
    int m = i >> 7;
    int np = i & 127;
    float2 xv = *(const float2*)(X + (size_t)(row0 + m) * 256 + np * 2);
    unsigned pk = (unsigned)f2bf(xv.x) | ((unsigned)f2bf(xv.y) << 16);
    int byte = (m * 512 + np * 4) ^ ((m & 7) << 4);
    *(unsigned*)(xs + byte) = pk;
  }
  __syncthreads();

  // ---- GEMM1: hid[32][1024] = relu(X @ W1 + b1) ----
  f32x4 acc1[2][8];
  #pragma unroll
  for (int mf = 0; mf < 2; ++mf)
    #pragma unroll
    for (int nf = 0; nf < 8; ++nf) acc1[mf][nf] = (f32x4){0.f, 0.f, 0.f, 0.f};
  #pragma unroll
  for (int kc = 0; kc < 8; ++kc) {
    int ab0 = (c * 512 + kc * 64 + kg * 16) ^ ((c & 7) << 4);
    int ab1 = ((16 + c) * 512 + kc * 64 + kg * 16) ^ ((c & 7) << 4);
    bf16x8 a0 = *(const bf16x8*)(xs + ab0);
    bf16x8 a1 = *(const bf16x8*)(xs + ab1);
    const unsigned short* wp = W1T + (size_t)(w * 128) * 256 + kc * 32 + kg * 8;
    #pragma unroll
    for (int nf = 0; nf < 8; ++nf) {
      bf16x8 b = *(const bf16x8*)(wp + (size_t)(nf * 16 + c) * 256);
      acc1[0][nf] = __builtin_amdgcn_mfma_f32_16x16x32_bf16(a0, b, acc1[0][nf], 0, 0, 0);
      acc1[1][nf] = __builtin_amdgcn_mfma_f32_16x16x32_bf16(a1, b, acc1[1][nf], 0, 0, 0);
    }
  }
  #pragma unroll
  for (int nf = 0; nf < 8; ++nf) {
    int n = w * 128 + nf * 16 + c;
    float bb = b1[n];
    #pragma unroll
    for (int mf = 0; mf < 2; ++mf) {
      #pragma unroll
      for (int i = 0; i < 4; ++i) {
        int m = mf * 16 + kg * 4 + i;
        float v = fmaxf(acc1[mf][nf][i] + bb, 0.f);
        int byte = (m * 2048 + n * 2) ^ ((m & 7) << 4);
        *(unsigned short*)(hs + byte) = f2bf(v);
      }
    }
  }
  __syncthreads();

  // ---- GEMM2: y[32][256] = hid @ W2 ----
  f32x4 acc2[2][2];
  #pragma unroll
  for (int mf = 0; mf < 2; ++mf)
    #pragma unroll
    for (int nf = 0; nf < 2; ++nf) acc2[mf][nf] = (f32x4){0.f, 0.f, 0.f, 0.f};
  #pragma unroll
  for (int kc = 0; kc < 32; ++kc) {
    int ab0 = (c * 2048 + kc * 64 + kg * 16) ^ ((c & 7) << 4);
    int ab1 = ((16 + c) * 2048 + kc * 64 + kg * 16) ^ ((c & 7) << 4);
    bf16x8 a0 = *(const bf16x8*)(hs + ab0);
    bf16x8 a1 = *(const bf16x8*)(hs + ab1);
    const unsigned short* wp = W2T + (size_t)(w * 32) * 1024 + kc * 32 + kg * 8;
    #pragma unroll
    for (int nf = 0; nf < 2; ++nf) {
      bf16x8 b = *(const bf16x8*)(wp + (size_t)(nf * 16 + c) * 1024);
      acc2[0][nf] = __builtin_amdgcn_mfma_f32_16x16x32_bf16(a0, b, acc2[0][nf], 0, 0, 0);
      acc2[1][nf] = __builtin_amdgcn_mfma_f32_16x16x32_bf16(a1, b, acc2[1][nf], 0, 0, 0);
    }
  }
  __syncthreads();

  #pragma unroll
  for (int nf = 0; nf < 2; ++nf) {
    int n2 = w * 32 + nf * 16 + c;
    float bb = b2[n2];
    #pragma unroll
    for (int mf = 0; mf < 2; ++mf) {
      #pragma unroll
      for (int i = 0; i < 4; ++i) {
        int m = mf * 16 + kg * 4 + i;
        out_s[m * 260 + n2] = acc2[mf][nf][i] + bb + X[(size_t)(row0 + m) * 256 + n2];
      }
    }
  }
  __syncthreads();

  float4 gv = *(const float4*)(g2 + lane * 4);
  float4 bev = *(const float4*)(be2 + lane * 4);
  #pragma unroll
  for (int rr = 0; rr < 4; ++rr) {
    int r = w * 4 + rr;
    float4 v = *(const float4*)(out_s + r * 260 + lane * 4);
    float s = v.x + v.y + v.z + v.w;
    float s2 = v.x * v.x + v.y * v.y + v.z * v.z + v.w * v.w;
    #pragma unroll
    for (int o = 1; o < 64; o <<= 1) {
      s += __shfl_xor(s, o, 64);
      s2 += __shfl_xor(s2, o, 64);
    }
    float mean = s * (1.f / 256.f);
    float var = s2 * (1.f / 256.f) - mean * mean;
    float rstd = rsqrtf(var + 1e-5f);
    float4 o4;
    o4.x = (v.x - mean) * rstd * gv.x + bev.x;
    o4.y = (v.y - mean) * rstd * gv.y + bev.y;
    o4.z = (v.z - mean) * rstd * gv.z + bev.z;
    o4.w = (v.w - mean) * rstd * gv.w + bev.w;
    *(float4*)(Out + (size_t)(row0 + r) * 256 + lane * 4) = o4;
  }
}

// ---------------------------------------------------------------------------
// Launch
// ---------------------------------------------------------------------------
extern "C" void kernel_launch(void* const* d_in, const int* in_sizes, int n_in,
                              void* d_out, int out_size, void* d_ws, size_t ws_size,
                              hipStream_t stream) {
  const float* q     = (const float*)d_in[0];
  const float* v     = (const float*)d_in[2];
  const float* refp  = (const float*)d_in[3];
  const float* W_off = (const float*)d_in[6];
  const float* b_off = (const float*)d_in[7];
  const float* W_at  = (const float*)d_in[8];
  const float* b_at  = (const float*)d_in[9];
  const float* W_val = (const float*)d_in[10];
  const float* b_val = (const float*)d_in[11];
  const float* W_out = (const float*)d_in[12];
  const float* b_out = (const float*)d_in[13];
  const float* W1    = (const float*)d_in[14];
  const float* b1    = (const float*)d_in[15];
  const float* W2    = (const float*)d_in[16];
  const float* b2    = (const float*)d_in[17];
  const float* g1    = (const float*)d_in[18];
  const float* be1   = (const float*)d_in[19];
  const float* g2    = (const float*)d_in[20];
  const float* be2   = (const float*)d_in[21];
  float* out = (float*)d_out;

  // Workspace layout (same as R11)
  float* ws   = (float*)d_ws;
  float* valb = ws;                                   // fp32 [M][256] region
  unsigned short* valbB = (unsigned short*)valb;      // bf16 [M][256] (first half)
  float* offb = valb + (size_t)VROWS * 256;           // fp32 [M][256]
  unsigned short* qb = (unsigned short*)(offb + (size_t)MROWS * 256); // bf16 [M][256]
  unsigned short* vb = qb + (size_t)MROWS * 256;      // bf16 [M][256]
  unsigned short* msdaB = qb;                         // alias: qb dead before msda
  unsigned short* awb = vb + (size_t)MROWS * 256;     // bf16 [M][128]
  unsigned short* WoffT  = awb + (size_t)MROWS * 128; // [256][256]
  unsigned short* WattnT = WoffT + 65536;             // [128][256]
  unsigned short* WvalT  = WattnT + 32768;            // [256][256]
  unsigned short* W1T    = WvalT + 65536;             // [1024][256]
  unsigned short* W2T    = W1T + 262144;              // [256][1024]
  unsigned short* WoutT  = W2T + 262144;              // [256][256] (appended)
  float* attnb = offb;                                // alias: offb dead after msda
  float* xb = valb;                                   // alias: valbB dead after msda

  conv_bf16<<<MROWS * 256 / (256 * 8), 256, 0, stream>>>(q, v, qb, vb);
  prep_all<<<2688, 256, 0, stream>>>(W_off, W_at, W_val, W1, W2,
                                     WoffT, WattnT, WvalT, W1T, W2T);
  prep_wout<<<256, 256, 0, stream>>>(W_out, WoutT);
  // value projection (bf16 out for bf16 sampling)
  proj_mfma<256, 3><<<MROWS / 32, 512, 0, stream>>>(vb, WvalT, b_val, nullptr, valbB);
  // offset projection
  proj_mfma<256, 0><<<MROWS / 32, 512, 0, stream>>>(qb, WoffT, b_off, offb, nullptr);
  // attention-weight projection + softmax (bf16 out)
  proj_mfma<128, 1><<<MROWS / 64, 512, 0, stream>>>(qb, WattnT, b_at, nullptr, awb);
  // deformable bilinear sampling (bf16 value in, bf16 out)
  msda_sample<<<MROWS / 4, 256, 0, stream>>>(valbB, offb, awb, refp, msdaB);
  // out-projection via proven EPI=0 core -> attn + b_out (fp32, into dead offb)
  proj_mfma<256, 0><<<MROWS / 32, 512, 0, stream>>>(msdaB, WoutT, b_out, attnb, nullptr);
  // residual + LayerNorm1
  resid_ln<<<MROWS / 4, 256, 0, stream>>>(attnb, q, g1, be1, xb);
  // fused FFN v2 + residual + LayerNorm2  (launch_bounds 512,3)
  ffn_mfma<<<MROWS / 32, 512, 0, stream>>>(xb, W1T, b1, W2T, b2, g2, be2, out);
}

// Round 14
// 454.827 us; speedup vs baseline: 1.0582x; 1.0205x over previous
//
#include <hip/hip_runtime.h>
#include <hip/hip_bf16.h>
#include <math.h>

// Problem constants (fixed by the reference file)
#define BB 2
#define NN 21760
#define CC 256
#define HH 8
#define PP 21760
#define MROWS (BB * NN)   // 43520 query rows
#define VROWS (BB * PP)   // 43520 value rows

typedef __attribute__((ext_vector_type(8))) short bf16x8;
typedef __attribute__((ext_vector_type(4))) float f32x4;

__device__ __forceinline__ unsigned short f2bf(float f) {
  unsigned u = __float_as_uint(f);
  u += 0x7fff + ((u >> 16) & 1);   // RNE
  return (unsigned short)(u >> 16);
}
__device__ __forceinline__ float bf2f(unsigned short s) {
  return __uint_as_float(((unsigned)s) << 16);
}

// ---------------------------------------------------------------------------
// q, v fp32 -> bf16 (row-major, same shape)
// ---------------------------------------------------------------------------
__global__ __launch_bounds__(256) void conv_bf16(
    const float* __restrict__ q, const float* __restrict__ v,
    unsigned short* __restrict__ qb, unsigned short* __restrict__ vb) {
  size_t i = ((size_t)blockIdx.x * 256 + threadIdx.x) * 8;
  float4 a0 = *(const float4*)(q + i);
  float4 a1 = *(const float4*)(q + i + 4);
  ushort4 o0 = {f2bf(a0.x), f2bf(a0.y), f2bf(a0.z), f2bf(a0.w)};
  ushort4 o1 = {f2bf(a1.x), f2bf(a1.y), f2bf(a1.z), f2bf(a1.w)};
  *(ushort4*)(qb + i) = o0;
  *(ushort4*)(qb + i + 4) = o1;
  float4 b0 = *(const float4*)(v + i);
  float4 b1 = *(const float4*)(v + i + 4);
  ushort4 p0 = {f2bf(b0.x), f2bf(b0.y), f2bf(b0.z), f2bf(b0.w)};
  ushort4 p1 = {f2bf(b1.x), f2bf(b1.y), f2bf(b1.z), f2bf(b1.w)};
  *(ushort4*)(vb + i) = p0;
  *(ushort4*)(vb + i + 4) = p1;
}

// ---------------------------------------------------------------------------
// Weights -> transposed bf16 [N][K].  (Unchanged, proven.)
// ---------------------------------------------------------------------------
__global__ __launch_bounds__(256) void prep_all(
    const float* __restrict__ W_off, const float* __restrict__ W_at,
    const float* __restrict__ W_val,
    const float* __restrict__ W1, const float* __restrict__ W2,
    unsigned short* __restrict__ WoffT, unsigned short* __restrict__ WattnT,
    unsigned short* __restrict__ WvalT,
    unsigned short* __restrict__ W1T, unsigned short* __restrict__ W2T) {
  int i = blockIdx.x * 256 + threadIdx.x;
  if (i < 65536) {                    // WoffT[256][256]
    WoffT[i] = f2bf(W_off[(size_t)(i & 255) * 256 + (i >> 8)]);
  } else if (i < 98304) {             // WattnT[128][256]
    int j = i - 65536;
    WattnT[j] = f2bf(W_at[(size_t)(j & 255) * 128 + (j >> 8)]);
  } else if (i < 163840) {            // WvalT[256][256]
    int j = i - 98304;
    WvalT[j] = f2bf(W_val[(size_t)(j & 255) * 256 + (j >> 8)]);
  } else if (i < 425984) {            // W1T[1024][256]
    int j = i - 163840;
    W1T[j] = f2bf(W1[(size_t)(j & 255) * 1024 + (j >> 8)]);
  } else if (i < 688128) {            // W2T[256][1024]
    int j = i - 425984;
    W2T[j] = f2bf(W2[(size_t)(j & 1023) * 256 + (j >> 10)]);
  }
}

// ---------------------------------------------------------------------------
// W_out -> transposed bf16 [256][256]
// ---------------------------------------------------------------------------
__global__ __launch_bounds__(256) void prep_wout(
    const float* __restrict__ W_out, unsigned short* __restrict__ WoutT) {
  int i = blockIdx.x * 256 + threadIdx.x;   // grid 256 -> i < 65536
  WoutT[i] = f2bf(W_out[(size_t)(i & 255) * 256 + (i >> 8)]);
}

// ---------------------------------------------------------------------------
// Projection GEMM via bf16 MFMA: C[M][NC] = A[M][256] @ BT^T + bias
// 8 waves, 512 threads.  NC=256: M-tile 32; NC=128: M-tile 64.
// EPI: 0 = +bias -> fp32;  1 = +bias, softmax per 16-group -> bf16;
//      3 = +bias -> bf16
// ---------------------------------------------------------------------------
template <int NC, int EPI>
__global__ __launch_bounds__(512, 4) void proj_mfma(
    const unsigned short* __restrict__ A, const unsigned short* __restrict__ BT,
    const float* __restrict__ bias,
    float* __restrict__ outF, unsigned short* __restrict__ outB) {
  constexpr int MTILE = (NC == 128) ? 64 : 32;
  __shared__ __align__(16) char xs[MTILE * 512];

  const int row0 = blockIdx.x * MTILE;
  const int t = threadIdx.x;
  const int w = t >> 6, lane = t & 63;
  const int c = lane & 15, kg = lane >> 4;
  const int mbase = (NC == 128) ? (w >> 2) * 32 : 0;
  const int nbase = (NC == 128) ? (w & 3) * 32 : w * 32;

  // ---- stage A tile (bf16 global -> swizzled LDS) ----
  #pragma unroll
  for (int p = 0; p < MTILE / 16; ++p) {
    int i = t + p * 512;          // 16B chunk id
    int m = i >> 5, c16 = i & 31;
    ushort4 v0 = *(const ushort4*)(A + (size_t)(row0 + m) * 256 + c16 * 8);
    ushort4 v1 = *(const ushort4*)(A + (size_t)(row0 + m) * 256 + c16 * 8 + 4);
    int byte = (m * 512 + c16 * 16) ^ ((m & 7) << 4);
    *(ushort4*)(xs + byte) = v0;
    *(ushort4*)(xs + byte + 8) = v1;
  }
  __syncthreads();

  // ---- GEMM ----
  f32x4 acc[2][2];
  #pragma unroll
  for (int mf = 0; mf < 2; ++mf)
    #pragma unroll
    for (int nf = 0; nf < 2; ++nf) acc[mf][nf] = (f32x4){0.f, 0.f, 0.f, 0.f};
  #pragma unroll
  for (int kc = 0; kc < 8; ++kc) {
    int ab0 = ((mbase + c) * 512 + kc * 64 + kg * 16) ^ ((c & 7) << 4);
    int ab1 = ((mbase + 16 + c) * 512 + kc * 64 + kg * 16) ^ ((c & 7) << 4);
    bf16x8 a0 = *(const bf16x8*)(xs + ab0);
    bf16x8 a1 = *(const bf16x8*)(xs + ab1);
    #pragma unroll
    for (int nf = 0; nf < 2; ++nf) {
      bf16x8 b = *(const bf16x8*)(BT + (size_t)(nbase + nf * 16 + c) * 256 + kc * 32 + kg * 8);
      acc[0][nf] = __builtin_amdgcn_mfma_f32_16x16x32_bf16(a0, b, acc[0][nf], 0, 0, 0);
      acc[1][nf] = __builtin_amdgcn_mfma_f32_16x16x32_bf16(a1, b, acc[1][nf], 0, 0, 0);
    }
  }

  // ---- epilogue ----
  if (EPI == 0) {
    #pragma unroll
    for (int nf = 0; nf < 2; ++nf) {
      int n = nbase + nf * 16 + c;
      float bb = bias[n];
      #pragma unroll
      for (int mf = 0; mf < 2; ++mf)
        #pragma unroll
        for (int i = 0; i < 4; ++i) {
          int m = mbase + mf * 16 + kg * 4 + i;
          outF[(size_t)(row0 + m) * NC + n] = acc[mf][nf][i] + bb;
        }
    }
  } else if (EPI == 3) {
    #pragma unroll
    for (int nf = 0; nf < 2; ++nf) {
      int n = nbase + nf * 16 + c;
      float bb = bias[n];
      #pragma unroll
      for (int mf = 0; mf < 2; ++mf)
        #pragma unroll
        for (int i = 0; i < 4; ++i) {
          int m = mbase + mf * 16 + kg * 4 + i;
          outB[(size_t)(row0 + m) * NC + n] = f2bf(acc[mf][nf][i] + bb);
        }
    }
  } else {
    // softmax over 16-lane groups (one head's 16 logits per group)
    #pragma unroll
    for (int nf = 0; nf < 2; ++nf) {
      int n = nbase + nf * 16 + c;
      float bb = bias[n];
      #pragma unroll
      for (int mf = 0; mf < 2; ++mf)
        #pragma unroll
        for (int i = 0; i < 4; ++i) {
          float vv = acc[mf][nf][i] + bb;
          float mx = vv;
          mx = fmaxf(mx, __shfl_xor(mx, 1, 64));
          mx = fmaxf(mx, __shfl_xor(mx, 2, 64));
          mx = fmaxf(mx, __shfl_xor(mx, 4, 64));
          mx = fmaxf(mx, __shfl_xor(mx, 8, 64));
          float e = expf(vv - mx);
          float s = e;
          s += __shfl_xor(s, 1, 64);
          s += __shfl_xor(s, 2, 64);
          s += __shfl_xor(s, 4, 64);
          s += __shfl_xor(s, 8, 64);
          int m = mbase + mf * 16 + kg * 4 + i;
          outB[(size_t)(row0 + m) * NC + n] = f2bf(e / s);
        }
    }
  }
}

// ---------------------------------------------------------------------------
// Deformable sampling v6: 4 queries/block, bf16 value gathers, bf16 OFF
// (packed u32 read), bf16 out.
// ---------------------------------------------------------------------------
__global__ __launch_bounds__(256) void msda_sample(
    const unsigned short* __restrict__ value, const unsigned short* __restrict__ off,
    const unsigned short* __restrict__ aw, const float* __restrict__ refp,
    unsigned short* __restrict__ out) {
  __shared__ __align__(16) int4   s_idx[4 * 16 * 8];   // [qi][i][h]
  __shared__ __align__(16) float4 s_w[4 * 16 * 8];
  const int t = threadIdx.x;
  const int bn0 = blockIdx.x * 4;
  const int b = bn0 / NN;

  #pragma unroll
  for (int ss = 0; ss < 2; ++ss) {
    const int s = t + ss * 256;
    const int qi = s >> 7;
    const int j  = s & 127;         // h*16 + l*4 + k
    const int bn = bn0 + qi;
    const int l  = (j >> 2) & 3;
    const int h  = j >> 4;
    const int i  = j & 15;
    const int szl = 128 >> l;
    const int st0l = (l == 0) ? 0 : (l == 1) ? 16384 : (l == 2) ? 20480 : 21504;

    unsigned op = *(const unsigned*)(off + (size_t)bn * 256 + j * 2);
    float ox = bf2f((unsigned short)(op & 0xffff));
    float oy = bf2f((unsigned short)(op >> 16));
    float a  = bf2f(aw[(size_t)bn * 128 + j]);
    float rx = refp[(size_t)bn * 8 + l * 2 + 0];
    float ry = refp[(size_t)bn * 8 + l * 2 + 1];

    float x = rx * (float)szl + ox - 0.5f;
    float y = ry * (float)szl + oy - 0.5f;
    float x0f = floorf(x), y0f = floorf(y);
    float wx = x - x0f, wy = y - y0f;
    int x0 = (int)x0f, y0 = (int)y0f;
    int x1 = x0 + 1, y1 = y0 + 1;

    bool vx0 = (x0 >= 0) & (x0 < szl);
    bool vx1 = (x1 >= 0) & (x1 < szl);
    bool vy0 = (y0 >= 0) & (y0 < szl);
    bool vy1 = (y1 >= 0) & (y1 < szl);
    int cx0 = min(max(x0, 0), szl - 1);
    int cx1 = min(max(x1, 0), szl - 1);
    int cy0 = min(max(y0, 0), szl - 1);
    int cy1 = min(max(y1, 0), szl - 1);

    int base = st0l * 256 + h * 32;
    int4 iv;
    iv.x = base + (cy0 * szl + cx0) * 256;
    iv.y = base + (cy0 * szl + cx1) * 256;
    iv.z = base + (cy1 * szl + cx0) * 256;
    iv.w = base + (cy1 * szl + cx1) * 256;
    float4 wv;
    wv.x = (vx0 & vy0) ? a * (1.f - wx) * (1.f - wy) : 0.f;
    wv.y = (vx1 & vy0) ? a * wx * (1.f - wy) : 0.f;
    wv.z = (vx0 & vy1) ? a * (1.f - wx) * wy : 0.f;
    wv.w = (vx1 & vy1) ? a * wx * wy : 0.f;

    int slot = (qi * 16 + i) * 8 + h;
    s_idx[slot] = iv;
    s_w[slot] = wv;
  }
  __syncthreads();

  const int qi = t >> 6;
  const int lane = t & 63;
  const int h = lane >> 3, d4 = lane & 7;
  const unsigned short* vcol = value + (size_t)b * PP * 256 + d4 * 4;

  float4 c0 = {0.f, 0.f, 0.f, 0.f}, c1 = {0.f, 0.f, 0.f, 0.f};
  float4 c2 = {0.f, 0.f, 0.f, 0.f}, c3 = {0.f, 0.f, 0.f, 0.f};
  #pragma unroll 4
  for (int i = 0; i < 16; ++i) {
    int slot = (qi * 16 + i) * 8 + h;
    int4 iv = s_idx[slot];
    float4 wv = s_w[slot];
    ushort4 u0 = *(const ushort4*)(vcol + iv.x);
    ushort4 u1 = *(const ushort4*)(vcol + iv.y);
    ushort4 u2 = *(const ushort4*)(vcol + iv.z);
    ushort4 u3 = *(const ushort4*)(vcol + iv.w);
    c0.x += wv.x * bf2f(u0.x); c0.y += wv.x * bf2f(u0.y);
    c0.z += wv.x * bf2f(u0.z); c0.w += wv.x * bf2f(u0.w);
    c1.x += wv.y * bf2f(u1.x); c1.y += wv.y * bf2f(u1.y);
    c1.z += wv.y * bf2f(u1.z); c1.w += wv.y * bf2f(u1.w);
    c2.x += wv.z * bf2f(u2.x); c2.y += wv.z * bf2f(u2.y);
    c2.z += wv.z * bf2f(u2.z); c2.w += wv.z * bf2f(u2.w);
    c3.x += wv.w * bf2f(u3.x); c3.y += wv.w * bf2f(u3.y);
    c3.z += wv.w * bf2f(u3.z); c3.w += wv.w * bf2f(u3.w);
  }
  float4 acc;
  acc.x = (c0.x + c1.x) + (c2.x + c3.x);
  acc.y = (c0.y + c1.y) + (c2.y + c3.y);
  acc.z = (c0.z + c1.z) + (c2.z + c3.z);
  acc.w = (c0.w + c1.w) + (c2.w + c3.w);
  ushort4 ob = {f2bf(acc.x), f2bf(acc.y), f2bf(acc.z), f2bf(acc.w)};
  *(ushort4*)(out + (size_t)(bn0 + qi) * 256 + h * 32 + d4 * 4) = ob;
}

// ---------------------------------------------------------------------------
// Residual + LayerNorm1: x = LN(attn + 2q) * g + be.  One wave per row.
// ---------------------------------------------------------------------------
__global__ __launch_bounds__(256) void resid_ln(
    const float* __restrict__ A, const float* __restrict__ q,
    const float* __restrict__ g, const float* __restrict__ be,
    float* __restrict__ X) {
  const int row = blockIdx.x * 4 + (threadIdx.x >> 6);
  const int lane = threadIdx.x & 63;
  const size_t base = (size_t)row * 256 + lane * 4;
  float4 a = *(const float4*)(A + base);
  float4 qv = *(const float4*)(q + base);
  float4 v;
  v.x = a.x + 2.f * qv.x;
  v.y = a.y + 2.f * qv.y;
  v.z = a.z + 2.f * qv.z;
  v.w = a.w + 2.f * qv.w;
  float s = v.x + v.y + v.z + v.w;
  float s2 = v.x * v.x + v.y * v.y + v.z * v.z + v.w * v.w;
  #pragma unroll
  for (int o = 1; o < 64; o <<= 1) {
    s += __shfl_xor(s, o, 64);
    s2 += __shfl_xor(s2, o, 64);
  }
  float mean = s * (1.f / 256.f);
  float var = s2 * (1.f / 256.f) - mean * mean;
  float rstd = rsqrtf(var + 1e-5f);
  float4 gv = *(const float4*)(g + lane * 4);
  float4 bev = *(const float4*)(be + lane * 4);
  float4 o4;
  o4.x = (v.x - mean) * rstd * gv.x + bev.x;
  o4.y = (v.y - mean) * rstd * gv.y + bev.y;
  o4.z = (v.z - mean) * rstd * gv.z + bev.z;
  o4.w = (v.w - mean) * rstd * gv.w + bev.w;
  *(float4*)(X + base) = o4;
}

// ---------------------------------------------------------------------------
// Fused FFN v5: v2 structure + GEMM1 split into two nf-halves (acc1 32 AGPR)
// + explicit B-fragment double-buffer in both GEMMs (guaranteed 4-deep /
// 2-deep load pipelining).  Peak unified regs ~100 < 128 cap -> occupancy
// unchanged vs v2.  M-tile=32, 8 waves, LDS 80KB, launch_bounds(512,4).
// ---------------------------------------------------------------------------
__global__ __launch_bounds__(512, 4) void ffn_mfma(
    const float* __restrict__ X, const unsigned short* __restrict__ W1T,
    const float* __restrict__ b1, const unsigned short* __restrict__ W2T,
    const float* __restrict__ b2, const float* __restrict__ g2,
    const float* __restrict__ be2, float* __restrict__ Out) {
  __shared__ __align__(16) char smem[16384 + 65536];
  char* xs = smem;            // 32 x 512 B
  char* hs = smem + 16384;    // 32 x 2048 B
  float* out_s = (float*)(smem + 16384);   // 32 x 260 f32, aliases hs

  const int row0 = blockIdx.x * 32;
  const int t = threadIdx.x;
  const int w = t >> 6, lane = t & 63;
  const int c = lane & 15, kg = lane >> 4;

  for (int i = t; i < 4096; i += 512) {
    int m = i >> 7;
    int np = i & 127;
    float2 xv = *(const float2*)(X + (size_t)(row0 + m) * 256 + np * 2);
    unsigned pk = (unsigned)f2bf(xv.x) | ((unsigned)f2bf(xv.y) << 16);
    int byte = (m * 512 + np * 4) ^ ((m & 7) << 4);
    *(unsigned*)(xs + byte) = pk;
  }
  __syncthreads();

  // ---- GEMM1 in two nf-halves (64 cols each), B double-buffered ----
  #pragma unroll
  for (int half = 0; half < 2; ++half) {
    f32x4 acc1[2][4];
    #pragma unroll
    for (int mf = 0; mf < 2; ++mf)
      #pragma unroll
      for (int nf = 0; nf < 4; ++nf) acc1[mf][nf] = (f32x4){0.f, 0.f, 0.f, 0.f};

    const unsigned short* wp1 = W1T + (size_t)(w * 128 + half * 64) * 256 + kg * 8;
    bf16x8 bcur[4];
    #pragma unroll
    for (int nf = 0; nf < 4; ++nf)
      bcur[nf] = *(const bf16x8*)(wp1 + (size_t)(nf * 16 + c) * 256);
    #pragma unroll
    for (int kc = 0; kc < 8; ++kc) {
      bf16x8 bnext[4];
      #pragma unroll
      for (int nf = 0; nf < 4; ++nf)
        bnext[nf] = (kc < 7)
            ? *(const bf16x8*)(wp1 + (size_t)(nf * 16 + c) * 256 + (kc + 1) * 32)
            : bcur[nf];
      int ab0 = (c * 512 + kc * 64 + kg * 16) ^ ((c & 7) << 4);
      int ab1 = ((16 + c) * 512 + kc * 64 + kg * 16) ^ ((c & 7) << 4);
      bf16x8 a0 = *(const bf16x8*)(xs + ab0);
      bf16x8 a1 = *(const bf16x8*)(xs + ab1);
      #pragma unroll
      for (int nf = 0; nf < 4; ++nf) {
        acc1[0][nf] = __builtin_amdgcn_mfma_f32_16x16x32_bf16(a0, bcur[nf], acc1[0][nf], 0, 0, 0);
        acc1[1][nf] = __builtin_amdgcn_mfma_f32_16x16x32_bf16(a1, bcur[nf], acc1[1][nf], 0, 0, 0);
      }
      #pragma unroll
      for (int nf = 0; nf < 4; ++nf) bcur[nf] = bnext[nf];
    }
    // store this half's hidden: relu(acc1 + b1) -> hs bf16, swizzled
    #pragma unroll
    for (int nf = 0; nf < 4; ++nf) {
      int n = w * 128 + half * 64 + nf * 16 + c;
      float bb = b1[n];
      #pragma unroll
      for (int mf = 0; mf < 2; ++mf) {
        #pragma unroll
        for (int i = 0; i < 4; ++i) {
          int m = mf * 16 + kg * 4 + i;
          float v = fmaxf(acc1[mf][nf][i] + bb, 0.f);
          int byte = (m * 2048 + n * 2) ^ ((m & 7) << 4);
          *(unsigned short*)(hs + byte) = f2bf(v);
        }
      }
    }
  }
  __syncthreads();

  // ---- GEMM2: y[32][256] = hid @ W2, B double-buffered ----
  f32x4 acc2[2][2];
  #pragma unroll
  for (int mf = 0; mf < 2; ++mf)
    #pragma unroll
    for (int nf = 0; nf < 2; ++nf) acc2[mf][nf] = (f32x4){0.f, 0.f, 0.f, 0.f};
  const unsigned short* wp2 = W2T + (size_t)(w * 32) * 1024 + kg * 8;
  bf16x8 b2cur[2];
  #pragma unroll
  for (int nf = 0; nf < 2; ++nf)
    b2cur[nf] = *(const bf16x8*)(wp2 + (size_t)(nf * 16 + c) * 1024);
  #pragma unroll
  for (int kc = 0; kc < 32; ++kc) {
    bf16x8 b2next[2];
    #pragma unroll
    for (int nf = 0; nf < 2; ++nf)
      b2next[nf] = (kc < 31)
          ? *(const bf16x8*)(wp2 + (size_t)(nf * 16 + c) * 1024 + (kc + 1) * 32)
          : b2cur[nf];
    int ab0 = (c * 2048 + kc * 64 + kg * 16) ^ ((c & 7) << 4);
    int ab1 = ((16 + c) * 2048 + kc * 64 + kg * 16) ^ ((c & 7) << 4);
    bf16x8 a0 = *(const bf16x8*)(hs + ab0);
    bf16x8 a1 = *(const bf16x8*)(hs + ab1);
    #pragma unroll
    for (int nf = 0; nf < 2; ++nf) {
      acc2[0][nf] = __builtin_amdgcn_mfma_f32_16x16x32_bf16(a0, b2cur[nf], acc2[0][nf], 0, 0, 0);
      acc2[1][nf] = __builtin_amdgcn_mfma_f32_16x16x32_bf16(a1, b2cur[nf], acc2[1][nf], 0, 0, 0);
    }
    #pragma unroll
    for (int nf = 0; nf < 2; ++nf) b2cur[nf] = b2next[nf];
  }
  __syncthreads();

  #pragma unroll
  for (int nf = 0; nf < 2; ++nf) {
    int n2 = w * 32 + nf * 16 + c;
    float bb = b2[n2];
    #pragma unroll
    for (int mf = 0; mf < 2; ++mf) {
      #pragma unroll
      for (int i = 0; i < 4; ++i) {
        int m = mf * 16 + kg * 4 + i;
        out_s[m * 260 + n2] = acc2[mf][nf][i] + bb + X[(size_t)(row0 + m) * 256 + n2];
      }
    }
  }
  __syncthreads();

  float4 gv = *(const float4*)(g2 + lane * 4);
  float4 bev = *(const float4*)(be2 + lane * 4);
  #pragma unroll
  for (int rr = 0; rr < 4; ++rr) {
    int r = w * 4 + rr;
    float4 v = *(const float4*)(out_s + r * 260 + lane * 4);
    float s = v.x + v.y + v.z + v.w;
    float s2 = v.x * v.x + v.y * v.y + v.z * v.z + v.w * v.w;
    #pragma unroll
    for (int o = 1; o < 64; o <<= 1) {
      s += __shfl_xor(s, o, 64);
      s2 += __shfl_xor(s2, o, 64);
    }
    float mean = s * (1.f / 256.f);
    float var = s2 * (1.f / 256.f) - mean * mean;
    float rstd = rsqrtf(var + 1e-5f);
    float4 o4;
    o4.x = (v.x - mean) * rstd * gv.x + bev.x;
    o4.y = (v.y - mean) * rstd * gv.y + bev.y;
    o4.z = (v.z - mean) * rstd * gv.z + bev.z;
    o4.w = (v.w - mean) * rstd * gv.w + bev.w;
    *(float4*)(Out + (size_t)(row0 + r) * 256 + lane * 4) = o4;
  }
}

// ---------------------------------------------------------------------------
// Launch
// ---------------------------------------------------------------------------
extern "C" void kernel_launch(void* const* d_in, const int* in_sizes, int n_in,
                              void* d_out, int out_size, void* d_ws, size_t ws_size,
                              hipStream_t stream) {
  const float* q     = (const float*)d_in[0];
  const float* v     = (const float*)d_in[2];
  const float* refp  = (const float*)d_in[3];
  const float* W_off = (const float*)d_in[6];
  const float* b_off = (const float*)d_in[7];
  const float* W_at  = (const float*)d_in[8];
  const float* b_at  = (const float*)d_in[9];
  const float* W_val = (const float*)d_in[10];
  const float* b_val = (const float*)d_in[11];
  const float* W_out = (const float*)d_in[12];
  const float* b_out = (const float*)d_in[13];
  const float* W1    = (const float*)d_in[14];
  const float* b1    = (const float*)d_in[15];
  const float* W2    = (const float*)d_in[16];
  const float* b2    = (const float*)d_in[17];
  const float* g1    = (const float*)d_in[18];
  const float* be1   = (const float*)d_in[19];
  const float* g2    = (const float*)d_in[20];
  const float* be2   = (const float*)d_in[21];
  float* out = (float*)d_out;

  // Workspace layout (same as R11)
  float* ws   = (float*)d_ws;
  float* valb = ws;                                   // fp32 [M][256] region
  unsigned short* valbB = (unsigned short*)valb;      // bf16 [M][256] (first half)
  float* offb = valb + (size_t)VROWS * 256;           // fp32 [M][256] region
  unsigned short* offbB = (unsigned short*)offb;      // bf16 [M][256] (first half)
  unsigned short* qb = (unsigned short*)(offb + (size_t)MROWS * 256); // bf16 [M][256]
  unsigned short* vb = qb + (size_t)MROWS * 256;      // bf16 [M][256]
  unsigned short* msdaB = qb;                         // alias: qb dead before msda
  unsigned short* awb = vb + (size_t)MROWS * 256;     // bf16 [M][128]
  unsigned short* WoffT  = awb + (size_t)MROWS * 128; // [256][256]
  unsigned short* WattnT = WoffT + 65536;             // [128][256]
  unsigned short* WvalT  = WattnT + 32768;            // [256][256]
  unsigned short* W1T    = WvalT + 65536;             // [1024][256]
  unsigned short* W2T    = W1T + 262144;              // [256][1024]
  unsigned short* WoutT  = W2T + 262144;              // [256][256] (appended)
  float* attnb = offb;                                // alias: offbB dead after msda
  float* xb = valb;                                   // alias: valbB dead after msda

  conv_bf16<<<MROWS * 256 / (256 * 8), 256, 0, stream>>>(q, v, qb, vb);
  prep_all<<<2688, 256, 0, stream>>>(W_off, W_at, W_val, W1, W2,
                                     WoffT, WattnT, WvalT, W1T, W2T);
  prep_wout<<<256, 256, 0, stream>>>(W_out, WoutT);
  // value projection (bf16 out for bf16 sampling)
  proj_mfma<256, 3><<<MROWS / 32, 512, 0, stream>>>(vb, WvalT, b_val, nullptr, valbB);
  // offset projection (bf16 out)
  proj_mfma<256, 3><<<MROWS / 32, 512, 0, stream>>>(qb, WoffT, b_off, nullptr, offbB);
  // attention-weight projection + softmax (bf16 out)
  proj_mfma<128, 1><<<MROWS / 64, 512, 0, stream>>>(qb, WattnT, b_at, nullptr, awb);
  // deformable bilinear sampling (bf16 value/off in, bf16 out)
  msda_sample<<<MROWS / 4, 256, 0, stream>>>(valbB, offbB, awb, refp, msdaB);
  // out-projection via proven EPI=0 core -> attn + b_out (fp32, into dead offb region)
  proj_mfma<256, 0><<<MROWS / 32, 512, 0, stream>>>(msdaB, WoutT, b_out, attnb, nullptr);
  // residual + LayerNorm1
  resid_ln<<<MROWS / 4, 256, 0, stream>>>(attnb, q, g1, be1, xb);
  // fused FFN v5 + residual + LayerNorm2
  ffn_mfma<<<MROWS / 32, 512, 0, stream>>>(xb, W1T, b1, W2T, b2, g2, be2, out);
}

// Round 16
// 442.465 us; speedup vs baseline: 1.0878x; 1.0279x over previous
//
#include <hip/hip_runtime.h>
#include <hip/hip_bf16.h>
#include <math.h>

// Problem constants (fixed by the reference file)
#define BB 2
#define NN 21760
#define CC 256
#define HH 8
#define PP 21760
#define MROWS (BB * NN)   // 43520 query rows
#define VROWS (BB * PP)   // 43520 value rows

typedef __attribute__((ext_vector_type(8))) short bf16x8;
typedef __attribute__((ext_vector_type(4))) float f32x4;

__device__ __forceinline__ unsigned short f2bf(float f) {
  unsigned u = __float_as_uint(f);
  u += 0x7fff + ((u >> 16) & 1);   // RNE
  return (unsigned short)(u >> 16);
}
__device__ __forceinline__ float bf2f(unsigned short s) {
  return __uint_as_float(((unsigned)s) << 16);
}

// ---------------------------------------------------------------------------
// Weights -> transposed bf16 [N][K].  (Unchanged, proven.)
// ---------------------------------------------------------------------------
__global__ __launch_bounds__(256) void prep_all(
    const float* __restrict__ W_off, const float* __restrict__ W_at,
    const float* __restrict__ W_val,
    const float* __restrict__ W1, const float* __restrict__ W2,
    unsigned short* __restrict__ WoffT, unsigned short* __restrict__ WattnT,
    unsigned short* __restrict__ WvalT,
    unsigned short* __restrict__ W1T, unsigned short* __restrict__ W2T) {
  int i = blockIdx.x * 256 + threadIdx.x;
  if (i < 65536) {                    // WoffT[256][256]
    WoffT[i] = f2bf(W_off[(size_t)(i & 255) * 256 + (i >> 8)]);
  } else if (i < 98304) {             // WattnT[128][256]
    int j = i - 65536;
    WattnT[j] = f2bf(W_at[(size_t)(j & 255) * 128 + (j >> 8)]);
  } else if (i < 163840) {            // WvalT[256][256]
    int j = i - 98304;
    WvalT[j] = f2bf(W_val[(size_t)(j & 255) * 256 + (j >> 8)]);
  } else if (i < 425984) {            // W1T[1024][256]
    int j = i - 163840;
    W1T[j] = f2bf(W1[(size_t)(j & 255) * 1024 + (j >> 8)]);
  } else if (i < 688128) {            // W2T[256][1024]
    int j = i - 425984;
    W2T[j] = f2bf(W2[(size_t)(j & 1023) * 256 + (j >> 10)]);
  }
}

// ---------------------------------------------------------------------------
// W_out -> transposed bf16 [256][256]
// ---------------------------------------------------------------------------
__global__ __launch_bounds__(256) void prep_wout(
    const float* __restrict__ W_out, unsigned short* __restrict__ WoutT) {
  int i = blockIdx.x * 256 + threadIdx.x;   // grid 256 -> i < 65536
  WoutT[i] = f2bf(W_out[(size_t)(i & 255) * 256 + (i >> 8)]);
}

// ---------------------------------------------------------------------------
// Projection GEMM via bf16 MFMA: C[M][NC] = A[M][256] @ BT^T + bias
// 8 waves, 512 threads.  NC=256: M-tile 32; NC=128: M-tile 64.
// EPI: 0 = +bias -> fp32;  1 = +bias, softmax per 16-group -> bf16;
//      3 = +bias -> bf16
// FSRC: 0 = A is bf16 [M][256];  1 = A is fp32 [M][256] (staged with the
//       byte-for-byte ffn-proven fp32->bf16 staging loop)
// ---------------------------------------------------------------------------
template <int NC, int EPI, int FSRC>
__global__ __launch_bounds__(512, 4) void proj_mfma(
    const void* __restrict__ Ain, const unsigned short* __restrict__ BT,
    const float* __restrict__ bias,
    float* __restrict__ outF, unsigned short* __restrict__ outB) {
  constexpr int MTILE = (NC == 128) ? 64 : 32;
  __shared__ __align__(16) char xs[MTILE * 512];

  const int row0 = blockIdx.x * MTILE;
  const int t = threadIdx.x;
  const int w = t >> 6, lane = t & 63;
  const int c = lane & 15, kg = lane >> 4;
  const int mbase = (NC == 128) ? (w >> 2) * 32 : 0;
  const int nbase = (NC == 128) ? (w & 3) * 32 : w * 32;

  // ---- stage A tile -> swizzled bf16 LDS ----
  if (FSRC) {
    const float* A = (const float*)Ain;
    for (int i = t; i < MTILE * 128; i += 512) {
      int m = i >> 7;
      int np = i & 127;
      float2 xv = *(const float2*)(A + (size_t)(row0 + m) * 256 + np * 2);
      unsigned pk = (unsigned)f2bf(xv.x) | ((unsigned)f2bf(xv.y) << 16);
      int byte = (m * 512 + np * 4) ^ ((m & 7) << 4);
      *(unsigned*)(xs + byte) = pk;
    }
  } else {
    const unsigned short* A = (const unsigned short*)Ain;
    #pragma unroll
    for (int p = 0; p < MTILE / 16; ++p) {
      int i = t + p * 512;          // 16B chunk id
      int m = i >> 5, c16 = i & 31;
      ushort4 v0 = *(const ushort4*)(A + (size_t)(row0 + m) * 256 + c16 * 8);
      ushort4 v1 = *(const ushort4*)(A + (size_t)(row0 + m) * 256 + c16 * 8 + 4);
      int byte = (m * 512 + c16 * 16) ^ ((m & 7) << 4);
      *(ushort4*)(xs + byte) = v0;
      *(ushort4*)(xs + byte + 8) = v1;
    }
  }
  __syncthreads();

  // ---- GEMM ----
  f32x4 acc[2][2];
  #pragma unroll
  for (int mf = 0; mf < 2; ++mf)
    #pragma unroll
    for (int nf = 0; nf < 2; ++nf) acc[mf][nf] = (f32x4){0.f, 0.f, 0.f, 0.f};
  #pragma unroll
  for (int kc = 0; kc < 8; ++kc) {
    int ab0 = ((mbase + c) * 512 + kc * 64 + kg * 16) ^ ((c & 7) << 4);
    int ab1 = ((mbase + 16 + c) * 512 + kc * 64 + kg * 16) ^ ((c & 7) << 4);
    bf16x8 a0 = *(const bf16x8*)(xs + ab0);
    bf16x8 a1 = *(const bf16x8*)(xs + ab1);
    #pragma unroll
    for (int nf = 0; nf < 2; ++nf) {
      bf16x8 b = *(const bf16x8*)(BT + (size_t)(nbase + nf * 16 + c) * 256 + kc * 32 + kg * 8);
      acc[0][nf] = __builtin_amdgcn_mfma_f32_16x16x32_bf16(a0, b, acc[0][nf], 0, 0, 0);
      acc[1][nf] = __builtin_amdgcn_mfma_f32_16x16x32_bf16(a1, b, acc[1][nf], 0, 0, 0);
    }
  }

  // ---- epilogue ----
  if (EPI == 0) {
    #pragma unroll
    for (int nf = 0; nf < 2; ++nf) {
      int n = nbase + nf * 16 + c;
      float bb = bias[n];
      #pragma unroll
      for (int mf = 0; mf < 2; ++mf)
        #pragma unroll
        for (int i = 0; i < 4; ++i) {
          int m = mbase + mf * 16 + kg * 4 + i;
          outF[(size_t)(row0 + m) * NC + n] = acc[mf][nf][i] + bb;
        }
    }
  } else if (EPI == 3) {
    #pragma unroll
    for (int nf = 0; nf < 2; ++nf) {
      int n = nbase + nf * 16 + c;
      float bb = bias[n];
      #pragma unroll
      for (int mf = 0; mf < 2; ++mf)
        #pragma unroll
        for (int i = 0; i < 4; ++i) {
          int m = mbase + mf * 16 + kg * 4 + i;
          outB[(size_t)(row0 + m) * NC + n] = f2bf(acc[mf][nf][i] + bb);
        }
    }
  } else {
    // softmax over 16-lane groups (one head's 16 logits per group)
    #pragma unroll
    for (int nf = 0; nf < 2; ++nf) {
      int n = nbase + nf * 16 + c;
      float bb = bias[n];
      #pragma unroll
      for (int mf = 0; mf < 2; ++mf)
        #pragma unroll
        for (int i = 0; i < 4; ++i) {
          float vv = acc[mf][nf][i] + bb;
          float mx = vv;
          mx = fmaxf(mx, __shfl_xor(mx, 1, 64));
          mx = fmaxf(mx, __shfl_xor(mx, 2, 64));
          mx = fmaxf(mx, __shfl_xor(mx, 4, 64));
          mx = fmaxf(mx, __shfl_xor(mx, 8, 64));
          float e = expf(vv - mx);
          float s = e;
          s += __shfl_xor(s, 1, 64);
          s += __shfl_xor(s, 2, 64);
          s += __shfl_xor(s, 4, 64);
          s += __shfl_xor(s, 8, 64);
          int m = mbase + mf * 16 + kg * 4 + i;
          outB[(size_t)(row0 + m) * NC + n] = f2bf(e / s);
        }
    }
  }
}

// ---------------------------------------------------------------------------
// Deformable sampling v6: 4 queries/block, bf16 value gathers, bf16 off
// (packed u32 read), bf16 out.  (Unchanged, proven.)
// ---------------------------------------------------------------------------
__global__ __launch_bounds__(256) void msda_sample(
    const unsigned short* __restrict__ value, const unsigned short* __restrict__ off,
    const unsigned short* __restrict__ aw, const float* __restrict__ refp,
    unsigned short* __restrict__ out) {
  __shared__ __align__(16) int4   s_idx[4 * 16 * 8];   // [qi][i][h]
  __shared__ __align__(16) float4 s_w[4 * 16 * 8];
  const int t = threadIdx.x;
  const int bn0 = blockIdx.x * 4;
  const int b = bn0 / NN;

  #pragma unroll
  for (int ss = 0; ss < 2; ++ss) {
    const int s = t + ss * 256;
    const int qi = s >> 7;
    const int j  = s & 127;         // h*16 + l*4 + k
    const int bn = bn0 + qi;
    const int l  = (j >> 2) & 3;
    const int h  = j >> 4;
    const int i  = j & 15;
    const int szl = 128 >> l;
    const int st0l = (l == 0) ? 0 : (l == 1) ? 16384 : (l == 2) ? 20480 : 21504;

    unsigned op = *(const unsigned*)(off + (size_t)bn * 256 + j * 2);
    float ox = bf2f((unsigned short)(op & 0xffff));
    float oy = bf2f((unsigned short)(op >> 16));
    float a  = bf2f(aw[(size_t)bn * 128 + j]);
    float rx = refp[(size_t)bn * 8 + l * 2 + 0];
    float ry = refp[(size_t)bn * 8 + l * 2 + 1];

    float x = rx * (float)szl + ox - 0.5f;
    float y = ry * (float)szl + oy - 0.5f;
    float x0f = floorf(x), y0f = floorf(y);
    float wx = x - x0f, wy = y - y0f;
    int x0 = (int)x0f, y0 = (int)y0f;
    int x1 = x0 + 1, y1 = y0 + 1;

    bool vx0 = (x0 >= 0) & (x0 < szl);
    bool vx1 = (x1 >= 0) & (x1 < szl);
    bool vy0 = (y0 >= 0) & (y0 < szl);
    bool vy1 = (y1 >= 0) & (y1 < szl);
    int cx0 = min(max(x0, 0), szl - 1);
    int cx1 = min(max(x1, 0), szl - 1);
    int cy0 = min(max(y0, 0), szl - 1);
    int cy1 = min(max(y1, 0), szl - 1);

    int base = st0l * 256 + h * 32;
    int4 iv;
    iv.x = base + (cy0 * szl + cx0) * 256;
    iv.y = base + (cy0 * szl + cx1) * 256;
    iv.z = base + (cy1 * szl + cx0) * 256;
    iv.w = base + (cy1 * szl + cx1) * 256;
    float4 wv;
    wv.x = (vx0 & vy0) ? a * (1.f - wx) * (1.f - wy) : 0.f;
    wv.y = (vx1 & vy0) ? a * wx * (1.f - wy) : 0.f;
    wv.z = (vx0 & vy1) ? a * (1.f - wx) * wy : 0.f;
    wv.w = (vx1 & vy1) ? a * wx * wy : 0.f;

    int slot = (qi * 16 + i) * 8 + h;
    s_idx[slot] = iv;
    s_w[slot] = wv;
  }
  __syncthreads();

  const int qi = t >> 6;
  const int lane = t & 63;
  const int h = lane >> 3, d4 = lane & 7;
  const unsigned short* vcol = value + (size_t)b * PP * 256 + d4 * 4;

  float4 c0 = {0.f, 0.f, 0.f, 0.f}, c1 = {0.f, 0.f, 0.f, 0.f};
  float4 c2 = {0.f, 0.f, 0.f, 0.f}, c3 = {0.f, 0.f, 0.f, 0.f};
  #pragma unroll 4
  for (int i = 0; i < 16; ++i) {
    int slot = (qi * 16 + i) * 8 + h;
    int4 iv = s_idx[slot];
    float4 wv = s_w[slot];
    ushort4 u0 = *(const ushort4*)(vcol + iv.x);
    ushort4 u1 = *(const ushort4*)(vcol + iv.y);
    ushort4 u2 = *(const ushort4*)(vcol + iv.z);
    ushort4 u3 = *(const ushort4*)(vcol + iv.w);
    c0.x += wv.x * bf2f(u0.x); c0.y += wv.x * bf2f(u0.y);
    c0.z += wv.x * bf2f(u0.z); c0.w += wv.x * bf2f(u0.w);
    c1.x += wv.y * bf2f(u1.x); c1.y += wv.y * bf2f(u1.y);
    c1.z += wv.y * bf2f(u1.z); c1.w += wv.y * bf2f(u1.w);
    c2.x += wv.z * bf2f(u2.x); c2.y += wv.z * bf2f(u2.y);
    c2.z += wv.z * bf2f(u2.z); c2.w += wv.z * bf2f(u2.w);
    c3.x += wv.w * bf2f(u3.x); c3.y += wv.w * bf2f(u3.y);
    c3.z += wv.w * bf2f(u3.z); c3.w += wv.w * bf2f(u3.w);
  }
  float4 acc;
  acc.x = (c0.x + c1.x) + (c2.x + c3.x);
  acc.y = (c0.y + c1.y) + (c2.y + c3.y);
  acc.z = (c0.z + c1.z) + (c2.z + c3.z);
  acc.w = (c0.w + c1.w) + (c2.w + c3.w);
  ushort4 ob = {f2bf(acc.x), f2bf(acc.y), f2bf(acc.z), f2bf(acc.w)};
  *(ushort4*)(out + (size_t)(bn0 + qi) * 256 + h * 32 + d4 * 4) = ob;
}

// ---------------------------------------------------------------------------
// Residual + LayerNorm1: x = LN(attn + 2q) * g + be.  One wave per row.
// (Proven R11-R14.)
// ---------------------------------------------------------------------------
__global__ __launch_bounds__(256) void resid_ln(
    const float* __restrict__ A, const float* __restrict__ q,
    const float* __restrict__ g, const float* __restrict__ be,
    float* __restrict__ X) {
  const int row = blockIdx.x * 4 + (threadIdx.x >> 6);
  const int lane = threadIdx.x & 63;
  const size_t base = (size_t)row * 256 + lane * 4;
  float4 a = *(const float4*)(A + base);
  float4 qv = *(const float4*)(q + base);
  float4 v;
  v.x = a.x + 2.f * qv.x;
  v.y = a.y + 2.f * qv.y;
  v.z = a.z + 2.f * qv.z;
  v.w = a.w + 2.f * qv.w;
  float s = v.x + v.y + v.z + v.w;
  float s2 = v.x * v.x + v.y * v.y + v.z * v.z + v.w * v.w;
  #pragma unroll
  for (int o = 1; o < 64; o <<= 1) {
    s += __shfl_xor(s, o, 64);
    s2 += __shfl_xor(s2, o, 64);
  }
  float mean = s * (1.f / 256.f);
  float var = s2 * (1.f / 256.f) - mean * mean;
  float rstd = rsqrtf(var + 1e-5f);
  float4 gv = *(const float4*)(g + lane * 4);
  float4 bev = *(const float4*)(be + lane * 4);
  float4 o4;
  o4.x = (v.x - mean) * rstd * gv.x + bev.x;
  o4.y = (v.y - mean) * rstd * gv.y + bev.y;
  o4.z = (v.z - mean) * rstd * gv.z + bev.z;
  o4.w = (v.w - mean) * rstd * gv.w + bev.w;
  *(float4*)(X + base) = o4;
}

// ---------------------------------------------------------------------------
// Fused FFN v5 (R14, proven): v2 structure + GEMM1 nf-halves + explicit
// B double-buffer.  M-tile=32, 8 waves, LDS 80KB, launch_bounds(512,4).
// ---------------------------------------------------------------------------
__global__ __launch_bounds__(512, 4) void ffn_mfma(
    const float* __restrict__ X, const unsigned short* __restrict__ W1T,
    const float* __restrict__ b1, const unsigned short* __restrict__ W2T,
    const float* __restrict__ b2, const float* __restrict__ g2,
    const float* __restrict__ be2, float* __restrict__ Out) {
  __shared__ __align__(16) char smem[16384 + 65536];
  char* xs = smem;            // 32 x 512 B
  char* hs = smem + 16384;    // 32 x 2048 B
  float* out_s = (float*)(smem + 16384);   // 32 x 260 f32, aliases hs

  const int row0 = blockIdx.x * 32;
  const int t = threadIdx.x;
  const int w = t >> 6, lane = t & 63;
  const int c = lane & 15, kg = lane >> 4;

  for (int i = t; i < 4096; i += 512) {
    int m = i >> 7;
    int np = i & 127;
    float2 xv = *(const float2*)(X + (size_t)(row0 + m) * 256 + np * 2);
    unsigned pk = (unsigned)f2bf(xv.x) | ((unsigned)f2bf(xv.y) << 16);
    int byte = (m * 512 + np * 4) ^ ((m & 7) << 4);
    *(unsigned*)(xs + byte) = pk;
  }
  __syncthreads();

  // ---- GEMM1 in two nf-halves (64 cols each), B double-buffered ----
  #pragma unroll
  for (int half = 0; half < 2; ++half) {
    f32x4 acc1[2][4];
    #pragma unroll
    for (int mf = 0; mf < 2; ++mf)
      #pragma unroll
      for (int nf = 0; nf < 4; ++nf) acc1[mf][nf] = (f32x4){0.f, 0.f, 0.f, 0.f};

    const unsigned short* wp1 = W1T + (size_t)(w * 128 + half * 64) * 256 + kg * 8;
    bf16x8 bcur[4];
    #pragma unroll
    for (int nf = 0; nf < 4; ++nf)
      bcur[nf] = *(const bf16x8*)(wp1 + (size_t)(nf * 16 + c) * 256);
    #pragma unroll
    for (int kc = 0; kc < 8; ++kc) {
      bf16x8 bnext[4];
      #pragma unroll
      for (int nf = 0; nf < 4; ++nf)
        bnext[nf] = (kc < 7)
            ? *(const bf16x8*)(wp1 + (size_t)(nf * 16 + c) * 256 + (kc + 1) * 32)
            : bcur[nf];
      int ab0 = (c * 512 + kc * 64 + kg * 16) ^ ((c & 7) << 4);
      int ab1 = ((16 + c) * 512 + kc * 64 + kg * 16) ^ ((c & 7) << 4);
      bf16x8 a0 = *(const bf16x8*)(xs + ab0);
      bf16x8 a1 = *(const bf16x8*)(xs + ab1);
      #pragma unroll
      for (int nf = 0; nf < 4; ++nf) {
        acc1[0][nf] = __builtin_amdgcn_mfma_f32_16x16x32_bf16(a0, bcur[nf], acc1[0][nf], 0, 0, 0);
        acc1[1][nf] = __builtin_amdgcn_mfma_f32_16x16x32_bf16(a1, bcur[nf], acc1[1][nf], 0, 0, 0);
      }
      #pragma unroll
      for (int nf = 0; nf < 4; ++nf) bcur[nf] = bnext[nf];
    }
    // store this half's hidden: relu(acc1 + b1) -> hs bf16, swizzled
    #pragma unroll
    for (int nf = 0; nf < 4; ++nf) {
      int n = w * 128 + half * 64 + nf * 16 + c;
      float bb = b1[n];
      #pragma unroll
      for (int mf = 0; mf < 2; ++mf) {
        #pragma unroll
        for (int i = 0; i < 4; ++i) {
          int m = mf * 16 + kg * 4 + i;
          float v = fmaxf(acc1[mf][nf][i] + bb, 0.f);
          int byte = (m * 2048 + n * 2) ^ ((m & 7) << 4);
          *(unsigned short*)(hs + byte) = f2bf(v);
        }
      }
    }
  }
  __syncthreads();

  // ---- GEMM2: y[32][256] = hid @ W2, B double-buffered ----
  f32x4 acc2[2][2];
  #pragma unroll
  for (int mf = 0; mf < 2; ++mf)
    #pragma unroll
    for (int nf = 0; nf < 2; ++nf) acc2[mf][nf] = (f32x4){0.f, 0.f, 0.f, 0.f};
  const unsigned short* wp2 = W2T + (size_t)(w * 32) * 1024 + kg * 8;
  bf16x8 b2cur[2];
  #pragma unroll
  for (int nf = 0; nf < 2; ++nf)
    b2cur[nf] = *(const bf16x8*)(wp2 + (size_t)(nf * 16 + c) * 1024);
  #pragma unroll
  for (int kc = 0; kc < 32; ++kc) {
    bf16x8 b2next[2];
    #pragma unroll
    for (int nf = 0; nf < 2; ++nf)
      b2next[nf] = (kc < 31)
          ? *(const bf16x8*)(wp2 + (size_t)(nf * 16 + c) * 1024 + (kc + 1) * 32)
          : b2cur[nf];
    int ab0 = (c * 2048 + kc * 64 + kg * 16) ^ ((c & 7) << 4);
    int ab1 = ((16 + c) * 2048 + kc * 64 + kg * 16) ^ ((c & 7) << 4);
    bf16x8 a0 = *(const bf16x8*)(hs + ab0);
    bf16x8 a1 = *(const bf16x8*)(hs + ab1);
    #pragma unroll
    for (int nf = 0; nf < 2; ++nf) {
      acc2[0][nf] = __builtin_amdgcn_mfma_f32_16x16x32_bf16(a0, b2cur[nf], acc2[0][nf], 0, 0, 0);
      acc2[1][nf] = __builtin_amdgcn_mfma_f32_16x16x32_bf16(a1, b2cur[nf], acc2[1][nf], 0, 0, 0);
    }
    #pragma unroll
    for (int nf = 0; nf < 2; ++nf) b2cur[nf] = b2next[nf];
  }
  __syncthreads();

  #pragma unroll
  for (int nf = 0; nf < 2; ++nf) {
    int n2 = w * 32 + nf * 16 + c;
    float bb = b2[n2];
    #pragma unroll
    for (int mf = 0; mf < 2; ++mf) {
      #pragma unroll
      for (int i = 0; i < 4; ++i) {
        int m = mf * 16 + kg * 4 + i;
        out_s[m * 260 + n2] = acc2[mf][nf][i] + bb + X[(size_t)(row0 + m) * 256 + n2];
      }
    }
  }
  __syncthreads();

  float4 gv = *(const float4*)(g2 + lane * 4);
  float4 bev = *(const float4*)(be2 + lane * 4);
  #pragma unroll
  for (int rr = 0; rr < 4; ++rr) {
    int r = w * 4 + rr;
    float4 v = *(const float4*)(out_s + r * 260 + lane * 4);
    float s = v.x + v.y + v.z + v.w;
    float s2 = v.x * v.x + v.y * v.y + v.z * v.z + v.w * v.w;
    #pragma unroll
    for (int o = 1; o < 64; o <<= 1) {
      s += __shfl_xor(s, o, 64);
      s2 += __shfl_xor(s2, o, 64);
    }
    float mean = s * (1.f / 256.f);
    float var = s2 * (1.f / 256.f) - mean * mean;
    float rstd = rsqrtf(var + 1e-5f);
    float4 o4;
    o4.x = (v.x - mean) * rstd * gv.x + bev.x;
    o4.y = (v.y - mean) * rstd * gv.y + bev.y;
    o4.z = (v.z - mean) * rstd * gv.z + bev.z;
    o4.w = (v.w - mean) * rstd * gv.w + bev.w;
    *(float4*)(Out + (size_t)(row0 + r) * 256 + lane * 4) = o4;
  }
}

// ---------------------------------------------------------------------------
// Launch
// ---------------------------------------------------------------------------
extern "C" void kernel_launch(void* const* d_in, const int* in_sizes, int n_in,
                              void* d_out, int out_size, void* d_ws, size_t ws_size,
                              hipStream_t stream) {
  const float* q     = (const float*)d_in[0];
  const float* v     = (const float*)d_in[2];
  const float* refp  = (const float*)d_in[3];
  const float* W_off = (const float*)d_in[6];
  const float* b_off = (const float*)d_in[7];
  const float* W_at  = (const float*)d_in[8];
  const float* b_at  = (const float*)d_in[9];
  const float* W_val = (const float*)d_in[10];
  const float* b_val = (const float*)d_in[11];
  const float* W_out = (const float*)d_in[12];
  const float* b_out = (const float*)d_in[13];
  const float* W1    = (const float*)d_in[14];
  const float* b1    = (const float*)d_in[15];
  const float* W2    = (const float*)d_in[16];
  const float* b2    = (const float*)d_in[17];
  const float* g1    = (const float*)d_in[18];
  const float* be1   = (const float*)d_in[19];
  const float* g2    = (const float*)d_in[20];
  const float* be2   = (const float*)d_in[21];
  float* out = (float*)d_out;

  // Workspace layout (exactly R14; qb/vb slots retained, now unused inputs)
  float* ws   = (float*)d_ws;
  float* valb = ws;                                   // fp32 [M][256] region
  unsigned short* valbB = (unsigned short*)valb;      // bf16 [M][256] (first half)
  float* offb = valb + (size_t)VROWS * 256;           // fp32 [M][256] region
  unsigned short* offbB = (unsigned short*)offb;      // bf16 [M][256] (first half)
  unsigned short* qb = (unsigned short*)(offb + (size_t)MROWS * 256); // slot
  unsigned short* vb = qb + (size_t)MROWS * 256;      // slot
  unsigned short* msdaB = qb;                         // msda output (bf16 M][256])
  unsigned short* awb = vb + (size_t)MROWS * 256;     // bf16 [M][128]
  unsigned short* WoffT  = awb + (size_t)MROWS * 128; // [256][256]
  unsigned short* WattnT = WoffT + 65536;             // [128][256]
  unsigned short* WvalT  = WattnT + 32768;            // [256][256]
  unsigned short* W1T    = WvalT + 65536;             // [1024][256]
  unsigned short* W2T    = W1T + 262144;              // [256][1024]
  unsigned short* WoutT  = W2T + 262144;              // [256][256]
  float* attnb = offb;                                // alias: offbB dead after msda
  float* xb = valb;                                   // alias: valbB dead after msda

  prep_all<<<2688, 256, 0, stream>>>(W_off, W_at, W_val, W1, W2,
                                     WoffT, WattnT, WvalT, W1T, W2T);
  prep_wout<<<256, 256, 0, stream>>>(W_out, WoutT);
  // value projection: fp32 v in, bf16 out
  proj_mfma<256, 3, 1><<<MROWS / 32, 512, 0, stream>>>(v, WvalT, b_val, nullptr, valbB);
  // offset projection: fp32 q in, bf16 out
  proj_mfma<256, 3, 1><<<MROWS / 32, 512, 0, stream>>>(q, WoffT, b_off, nullptr, offbB);
  // attention-weight projection + softmax: fp32 q in, bf16 out
  proj_mfma<128, 1, 1><<<MROWS / 64, 512, 0, stream>>>(q, WattnT, b_at, nullptr, awb);
  // deformable bilinear sampling (bf16 value/off in, bf16 out; into qb slot)
  msda_sample<<<MROWS / 4, 256, 0, stream>>>(valbB, offbB, awb, refp, msdaB);
  // out-projection: bf16 msda in -> fp32 attn (into dead offb region)
  proj_mfma<256, 0, 0><<<MROWS / 32, 512, 0, stream>>>(msdaB, WoutT, b_out, attnb, nullptr);
  // residual + LayerNorm1 (separate, proven)
  resid_ln<<<MROWS / 4, 256, 0, stream>>>(attnb, q, g1, be1, xb);
  // fused FFN v5 + residual + LayerNorm2 (R14, proven)
  ffn_mfma<<<MROWS / 32, 512, 0, stream>>>(xb, W1T, b1, W2T, b2, g2, be2, out);
}

// Round 17
// 438.279 us; speedup vs baseline: 1.0982x; 1.0096x over previous
//
#include <hip/hip_runtime.h>
#include <hip/hip_bf16.h>
#include <math.h>

// Problem constants (fixed by the reference file)
#define BB 2
#define NN 21760
#define CC 256
#define HH 8
#define PP 21760
#define MROWS (BB * NN)   // 43520 query rows
#define VROWS (BB * PP)   // 43520 value rows

typedef __attribute__((ext_vector_type(8))) short bf16x8;
typedef __attribute__((ext_vector_type(4))) float f32x4;

__device__ __forceinline__ unsigned short f2bf(float f) {
  unsigned u = __float_as_uint(f);
  u += 0x7fff + ((u >> 16) & 1);   // RNE
  return (unsigned short)(u >> 16);
}
__device__ __forceinline__ float bf2f(unsigned short s) {
  return __uint_as_float(((unsigned)s) << 16);
}
// packed-u32 bf16 pair -> two floats (lo = bits[15:0], hi = bits[31:16])
__device__ __forceinline__ float bflo(unsigned u) { return __uint_as_float(u << 16); }
__device__ __forceinline__ float bfhi(unsigned u) { return __uint_as_float(u & 0xffff0000u); }

// ---------------------------------------------------------------------------
// Weights -> transposed bf16 [N][K].  (Unchanged, proven.)
// ---------------------------------------------------------------------------
__global__ __launch_bounds__(256) void prep_all(
    const float* __restrict__ W_off, const float* __restrict__ W_at,
    const float* __restrict__ W_val,
    const float* __restrict__ W1, const float* __restrict__ W2,
    unsigned short* __restrict__ WoffT, unsigned short* __restrict__ WattnT,
    unsigned short* __restrict__ WvalT,
    unsigned short* __restrict__ W1T, unsigned short* __restrict__ W2T) {
  int i = blockIdx.x * 256 + threadIdx.x;
  if (i < 65536) {                    // WoffT[256][256]
    WoffT[i] = f2bf(W_off[(size_t)(i & 255) * 256 + (i >> 8)]);
  } else if (i < 98304) {             // WattnT[128][256]
    int j = i - 65536;
    WattnT[j] = f2bf(W_at[(size_t)(j & 255) * 128 + (j >> 8)]);
  } else if (i < 163840) {            // WvalT[256][256]
    int j = i - 98304;
    WvalT[j] = f2bf(W_val[(size_t)(j & 255) * 256 + (j >> 8)]);
  } else if (i < 425984) {            // W1T[1024][256]
    int j = i - 163840;
    W1T[j] = f2bf(W1[(size_t)(j & 255) * 1024 + (j >> 8)]);
  } else if (i < 688128) {            // W2T[256][1024]
    int j = i - 425984;
    W2T[j] = f2bf(W2[(size_t)(j & 1023) * 256 + (j >> 10)]);
  }
}

// ---------------------------------------------------------------------------
// W_out -> transposed bf16 [256][256]
// ---------------------------------------------------------------------------
__global__ __launch_bounds__(256) void prep_wout(
    const float* __restrict__ W_out, unsigned short* __restrict__ WoutT) {
  int i = blockIdx.x * 256 + threadIdx.x;   // grid 256 -> i < 65536
  WoutT[i] = f2bf(W_out[(size_t)(i & 255) * 256 + (i >> 8)]);
}

// ---------------------------------------------------------------------------
// Projection GEMM via bf16 MFMA: C[M][NC] = A[M][256] @ BT^T + bias
// 8 waves, 512 threads.  NC=256: M-tile 32; NC=128: M-tile 64.
// EPI: 0 = +bias -> fp32;  1 = +bias, softmax per 16-group -> bf16;
//      3 = +bias -> bf16
// FSRC: 0 = A bf16;  1 = A fp32 (staged with the ffn-proven convert loop)
// ---------------------------------------------------------------------------
template <int NC, int EPI, int FSRC>
__global__ __launch_bounds__(512, 4) void proj_mfma(
    const void* __restrict__ Ain, const unsigned short* __restrict__ BT,
    const float* __restrict__ bias,
    float* __restrict__ outF, unsigned short* __restrict__ outB) {
  constexpr int MTILE = (NC == 128) ? 64 : 32;
  __shared__ __align__(16) char xs[MTILE * 512];

  const int row0 = blockIdx.x * MTILE;
  const int t = threadIdx.x;
  const int w = t >> 6, lane = t & 63;
  const int c = lane & 15, kg = lane >> 4;
  const int mbase = (NC == 128) ? (w >> 2) * 32 : 0;
  const int nbase = (NC == 128) ? (w & 3) * 32 : w * 32;

  // ---- stage A tile -> swizzled bf16 LDS ----
  if (FSRC) {
    const float* A = (const float*)Ain;
    for (int i = t; i < MTILE * 128; i += 512) {
      int m = i >> 7;
      int np = i & 127;
      float2 xv = *(const float2*)(A + (size_t)(row0 + m) * 256 + np * 2);
      unsigned pk = (unsigned)f2bf(xv.x) | ((unsigned)f2bf(xv.y) << 16);
      int byte = (m * 512 + np * 4) ^ ((m & 7) << 4);
      *(unsigned*)(xs + byte) = pk;
    }
  } else {
    const unsigned short* A = (const unsigned short*)Ain;
    #pragma unroll
    for (int p = 0; p < MTILE / 16; ++p) {
      int i = t + p * 512;          // 16B chunk id
      int m = i >> 5, c16 = i & 31;
      ushort4 v0 = *(const ushort4*)(A + (size_t)(row0 + m) * 256 + c16 * 8);
      ushort4 v1 = *(const ushort4*)(A + (size_t)(row0 + m) * 256 + c16 * 8 + 4);
      int byte = (m * 512 + c16 * 16) ^ ((m & 7) << 4);
      *(ushort4*)(xs + byte) = v0;
      *(ushort4*)(xs + byte + 8) = v1;
    }
  }
  __syncthreads();

  // ---- GEMM ----
  f32x4 acc[2][2];
  #pragma unroll
  for (int mf = 0; mf < 2; ++mf)
    #pragma unroll
    for (int nf = 0; nf < 2; ++nf) acc[mf][nf] = (f32x4){0.f, 0.f, 0.f, 0.f};
  #pragma unroll
  for (int kc = 0; kc < 8; ++kc) {
    int ab0 = ((mbase + c) * 512 + kc * 64 + kg * 16) ^ ((c & 7) << 4);
    int ab1 = ((mbase + 16 + c) * 512 + kc * 64 + kg * 16) ^ ((c & 7) << 4);
    bf16x8 a0 = *(const bf16x8*)(xs + ab0);
    bf16x8 a1 = *(const bf16x8*)(xs + ab1);
    #pragma unroll
    for (int nf = 0; nf < 2; ++nf) {
      bf16x8 b = *(const bf16x8*)(BT + (size_t)(nbase + nf * 16 + c) * 256 + kc * 32 + kg * 8);
      acc[0][nf] = __builtin_amdgcn_mfma_f32_16x16x32_bf16(a0, b, acc[0][nf], 0, 0, 0);
      acc[1][nf] = __builtin_amdgcn_mfma_f32_16x16x32_bf16(a1, b, acc[1][nf], 0, 0, 0);
    }
  }

  // ---- epilogue ----
  if (EPI == 0) {
    #pragma unroll
    for (int nf = 0; nf < 2; ++nf) {
      int n = nbase + nf * 16 + c;
      float bb = bias[n];
      #pragma unroll
      for (int mf = 0; mf < 2; ++mf)
        #pragma unroll
        for (int i = 0; i < 4; ++i) {
          int m = mbase + mf * 16 + kg * 4 + i;
          outF[(size_t)(row0 + m) * NC + n] = acc[mf][nf][i] + bb;
        }
    }
  } else if (EPI == 3) {
    #pragma unroll
    for (int nf = 0; nf < 2; ++nf) {
      int n = nbase + nf * 16 + c;
      float bb = bias[n];
      #pragma unroll
      for (int mf = 0; mf < 2; ++mf)
        #pragma unroll
        for (int i = 0; i < 4; ++i) {
          int m = mbase + mf * 16 + kg * 4 + i;
          outB[(size_t)(row0 + m) * NC + n] = f2bf(acc[mf][nf][i] + bb);
        }
    }
  } else {
    // softmax over 16-lane groups (one head's 16 logits per group)
    #pragma unroll
    for (int nf = 0; nf < 2; ++nf) {
      int n = nbase + nf * 16 + c;
      float bb = bias[n];
      #pragma unroll
      for (int mf = 0; mf < 2; ++mf)
        #pragma unroll
        for (int i = 0; i < 4; ++i) {
          float vv = acc[mf][nf][i] + bb;
          float mx = vv;
          mx = fmaxf(mx, __shfl_xor(mx, 1, 64));
          mx = fmaxf(mx, __shfl_xor(mx, 2, 64));
          mx = fmaxf(mx, __shfl_xor(mx, 4, 64));
          mx = fmaxf(mx, __shfl_xor(mx, 8, 64));
          float e = expf(vv - mx);
          float s = e;
          s += __shfl_xor(s, 1, 64);
          s += __shfl_xor(s, 2, 64);
          s += __shfl_xor(s, 4, 64);
          s += __shfl_xor(s, 8, 64);
          int m = mbase + mf * 16 + kg * 4 + i;
          outB[(size_t)(row0 + m) * NC + n] = f2bf(e / s);
        }
    }
  }
}

// ---------------------------------------------------------------------------
// Deformable sampling v7: 8 queries/block, 2 queries/wave.
// Phase 2 lane = (qi2 = lane>>5, h = (lane>>2)&7, d8 = lane&3); each lane
// gathers ushort8 (16B) per corner -> half the gather instructions of v6.
// ---------------------------------------------------------------------------
__global__ __launch_bounds__(256) void msda_sample(
    const unsigned short* __restrict__ value, const unsigned short* __restrict__ off,
    const unsigned short* __restrict__ aw, const float* __restrict__ refp,
    unsigned short* __restrict__ out) {
  __shared__ __align__(16) int4   s_idx[8 * 16 * 8];   // [qi][i][h], 16 KB
  __shared__ __align__(16) float4 s_w[8 * 16 * 8];     // 16 KB
  const int t = threadIdx.x;
  const int bn0 = blockIdx.x * 8;
  const int b = bn0 / NN;   // NN % 8 == 0: all 8 queries share b

  // ---- phase 1: sampling parameters (4 samples per thread) ----
  #pragma unroll
  for (int ss = 0; ss < 4; ++ss) {
    const int s = t + ss * 256;     // 0..1023
    const int qi = s >> 7;          // 0..7
    const int j  = s & 127;         // h*16 + l*4 + k
    const int bn = bn0 + qi;
    const int l  = (j >> 2) & 3;
    const int h  = j >> 4;
    const int i  = j & 15;
    const int szl = 128 >> l;
    const int st0l = (l == 0) ? 0 : (l == 1) ? 16384 : (l == 2) ? 20480 : 21504;

    unsigned op = *(const unsigned*)(off + (size_t)bn * 256 + j * 2);
    float ox = bflo(op);
    float oy = bfhi(op);
    float a  = bf2f(aw[(size_t)bn * 128 + j]);
    float rx = refp[(size_t)bn * 8 + l * 2 + 0];
    float ry = refp[(size_t)bn * 8 + l * 2 + 1];

    float x = rx * (float)szl + ox - 0.5f;
    float y = ry * (float)szl + oy - 0.5f;
    float x0f = floorf(x), y0f = floorf(y);
    float wx = x - x0f, wy = y - y0f;
    int x0 = (int)x0f, y0 = (int)y0f;
    int x1 = x0 + 1, y1 = y0 + 1;

    bool vx0 = (x0 >= 0) & (x0 < szl);
    bool vx1 = (x1 >= 0) & (x1 < szl);
    bool vy0 = (y0 >= 0) & (y0 < szl);
    bool vy1 = (y1 >= 0) & (y1 < szl);
    int cx0 = min(max(x0, 0), szl - 1);
    int cx1 = min(max(x1, 0), szl - 1);
    int cy0 = min(max(y0, 0), szl - 1);
    int cy1 = min(max(y1, 0), szl - 1);

    int base = st0l * 256 + h * 32;
    int4 iv;
    iv.x = base + (cy0 * szl + cx0) * 256;
    iv.y = base + (cy0 * szl + cx1) * 256;
    iv.z = base + (cy1 * szl + cx0) * 256;
    iv.w = base + (cy1 * szl + cx1) * 256;
    float4 wv;
    wv.x = (vx0 & vy0) ? a * (1.f - wx) * (1.f - wy) : 0.f;
    wv.y = (vx1 & vy0) ? a * wx * (1.f - wy) : 0.f;
    wv.z = (vx0 & vy1) ? a * (1.f - wx) * wy : 0.f;
    wv.w = (vx1 & vy1) ? a * wx * wy : 0.f;

    int slot = (qi * 16 + i) * 8 + h;
    s_idx[slot] = iv;
    s_w[slot] = wv;
  }
  __syncthreads();

  // ---- phase 2: 16B gathers; wave serves 2 queries ----
  const int wv_ = t >> 6;
  const int lane = t & 63;
  const int qi = wv_ * 2 + (lane >> 5);     // 0..7
  const int h = (lane >> 2) & 7;
  const int d8 = lane & 3;                  // 8-element group within d
  const unsigned short* vcol = value + (size_t)b * PP * 256 + d8 * 8;

  // 4 corners x 8 floats accumulators
  float4 a0a = {0,0,0,0}, a0b = {0,0,0,0}, a1a = {0,0,0,0}, a1b = {0,0,0,0};
  float4 a2a = {0,0,0,0}, a2b = {0,0,0,0}, a3a = {0,0,0,0}, a3b = {0,0,0,0};
  #pragma unroll 4
  for (int i = 0; i < 16; ++i) {
    int slot = (qi * 16 + i) * 8 + h;
    int4 iv = s_idx[slot];
    float4 wv = s_w[slot];
    int4 u0 = *(const int4*)(vcol + iv.x);   // 8 bf16
    int4 u1 = *(const int4*)(vcol + iv.y);
    int4 u2 = *(const int4*)(vcol + iv.z);
    int4 u3 = *(const int4*)(vcol + iv.w);
    a0a.x += wv.x * bflo(u0.x); a0a.y += wv.x * bfhi(u0.x);
    a0a.z += wv.x * bflo(u0.y); a0a.w += wv.x * bfhi(u0.y);
    a0b.x += wv.x * bflo(u0.z); a0b.y += wv.x * bfhi(u0.z);
    a0b.z += wv.x * bflo(u0.w); a0b.w += wv.x * bfhi(u0.w);
    a1a.x += wv.y * bflo(u1.x); a1a.y += wv.y * bfhi(u1.x);
    a1a.z += wv.y * bflo(u1.y); a1a.w += wv.y * bfhi(u1.y);
    a1b.x += wv.y * bflo(u1.z); a1b.y += wv.y * bfhi(u1.z);
    a1b.z += wv.y * bflo(u1.w); a1b.w += wv.y * bfhi(u1.w);
    a2a.x += wv.z * bflo(u2.x); a2a.y += wv.z * bfhi(u2.x);
    a2a.z += wv.z * bflo(u2.y); a2a.w += wv.z * bfhi(u2.y);
    a2b.x += wv.z * bflo(u2.z); a2b.y += wv.z * bfhi(u2.z);
    a2b.z += wv.z * bflo(u2.w); a2b.w += wv.z * bfhi(u2.w);
    a3a.x += wv.w * bflo(u3.x); a3a.y += wv.w * bfhi(u3.x);
    a3a.z += wv.w * bflo(u3.y); a3a.w += wv.w * bfhi(u3.y);
    a3b.x += wv.w * bflo(u3.z); a3b.y += wv.w * bfhi(u3.z);
    a3b.z += wv.w * bflo(u3.w); a3b.w += wv.w * bfhi(u3.w);
  }
  float4 ra, rb;
  ra.x = (a0a.x + a1a.x) + (a2a.x + a3a.x);
  ra.y = (a0a.y + a1a.y) + (a2a.y + a3a.y);
  ra.z = (a0a.z + a1a.z) + (a2a.z + a3a.z);
  ra.w = (a0a.w + a1a.w) + (a2a.w + a3a.w);
  rb.x = (a0b.x + a1b.x) + (a2b.x + a3b.x);
  rb.y = (a0b.y + a1b.y) + (a2b.y + a3b.y);
  rb.z = (a0b.z + a1b.z) + (a2b.z + a3b.z);
  rb.w = (a0b.w + a1b.w) + (a2b.w + a3b.w);
  // pack 8 bf16 -> 16B store
  int4 ob;
  ob.x = (int)((unsigned)f2bf(ra.x) | ((unsigned)f2bf(ra.y) << 16));
  ob.y = (int)((unsigned)f2bf(ra.z) | ((unsigned)f2bf(ra.w) << 16));
  ob.z = (int)((unsigned)f2bf(rb.x) | ((unsigned)f2bf(rb.y) << 16));
  ob.w = (int)((unsigned)f2bf(rb.z) | ((unsigned)f2bf(rb.w) << 16));
  *(int4*)(out + (size_t)(bn0 + qi) * 256 + h * 32 + d8 * 8) = ob;
}

// ---------------------------------------------------------------------------
// Residual + LayerNorm1: x = LN(attn + 2q) * g + be.  One wave per row.
// (Proven R11-R16.)
// ---------------------------------------------------------------------------
__global__ __launch_bounds__(256) void resid_ln(
    const float* __restrict__ A, const float* __restrict__ q,
    const float* __restrict__ g, const float* __restrict__ be,
    float* __restrict__ X) {
  const int row = blockIdx.x * 4 + (threadIdx.x >> 6);
  const int lane = threadIdx.x & 63;
  const size_t base = (size_t)row * 256 + lane * 4;
  float4 a = *(const float4*)(A + base);
  float4 qv = *(const float4*)(q + base);
  float4 v;
  v.x = a.x + 2.f * qv.x;
  v.y = a.y + 2.f * qv.y;
  v.z = a.z + 2.f * qv.z;
  v.w = a.w + 2.f * qv.w;
  float s = v.x + v.y + v.z + v.w;
  float s2 = v.x * v.x + v.y * v.y + v.z * v.z + v.w * v.w;
  #pragma unroll
  for (int o = 1; o < 64; o <<= 1) {
    s += __shfl_xor(s, o, 64);
    s2 += __shfl_xor(s2, o, 64);
  }
  float mean = s * (1.f / 256.f);
  float var = s2 * (1.f / 256.f) - mean * mean;
  float rstd = rsqrtf(var + 1e-5f);
  float4 gv = *(const float4*)(g + lane * 4);
  float4 bev = *(const float4*)(be + lane * 4);
  float4 o4;
  o4.x = (v.x - mean) * rstd * gv.x + bev.x;
  o4.y = (v.y - mean) * rstd * gv.y + bev.y;
  o4.z = (v.z - mean) * rstd * gv.z + bev.z;
  o4.w = (v.w - mean) * rstd * gv.w + bev.w;
  *(float4*)(X + base) = o4;
}

// ---------------------------------------------------------------------------
// Fused FFN v5 (R14/R16, proven): v2 structure + GEMM1 nf-halves + explicit
// B double-buffer.  M-tile=32, 8 waves, LDS 80KB, launch_bounds(512,4).
// ---------------------------------------------------------------------------
__global__ __launch_bounds__(512, 4) void ffn_mfma(
    const float* __restrict__ X, const unsigned short* __restrict__ W1T,
    const float* __restrict__ b1, const unsigned short* __restrict__ W2T,
    const float* __restrict__ b2, const float* __restrict__ g2,
    const float* __restrict__ be2, float* __restrict__ Out) {
  __shared__ __align__(16) char smem[16384 + 65536];
  char* xs = smem;            // 32 x 512 B
  char* hs = smem + 16384;    // 32 x 2048 B
  float* out_s = (float*)(smem + 16384);   // 32 x 260 f32, aliases hs

  const int row0 = blockIdx.x * 32;
  const int t = threadIdx.x;
  const int w = t >> 6, lane = t & 63;
  const int c = lane & 15, kg = lane >> 4;

  for (int i = t; i < 4096; i += 512) {
    int m = i >> 7;
    int np = i & 127;
    float2 xv = *(const float2*)(X + (size_t)(row0 + m) * 256 + np * 2);
    unsigned pk = (unsigned)f2bf(xv.x) | ((unsigned)f2bf(xv.y) << 16);
    int byte = (m * 512 + np * 4) ^ ((m & 7) << 4);
    *(unsigned*)(xs + byte) = pk;
  }
  __syncthreads();

  // ---- GEMM1 in two nf-halves (64 cols each), B double-buffered ----
  #pragma unroll
  for (int half = 0; half < 2; ++half) {
    f32x4 acc1[2][4];
    #pragma unroll
    for (int mf = 0; mf < 2; ++mf)
      #pragma unroll
      for (int nf = 0; nf < 4; ++nf) acc1[mf][nf] = (f32x4){0.f, 0.f, 0.f, 0.f};

    const unsigned short* wp1 = W1T + (size_t)(w * 128 + half * 64) * 256 + kg * 8;
    bf16x8 bcur[4];
    #pragma unroll
    for (int nf = 0; nf < 4; ++nf)
      bcur[nf] = *(const bf16x8*)(wp1 + (size_t)(nf * 16 + c) * 256);
    #pragma unroll
    for (int kc = 0; kc < 8; ++kc) {
      bf16x8 bnext[4];
      #pragma unroll
      for (int nf = 0; nf < 4; ++nf)
        bnext[nf] = (kc < 7)
            ? *(const bf16x8*)(wp1 + (size_t)(nf * 16 + c) * 256 + (kc + 1) * 32)
            : bcur[nf];
      int ab0 = (c * 512 + kc * 64 + kg * 16) ^ ((c & 7) << 4);
      int ab1 = ((16 + c) * 512 + kc * 64 + kg * 16) ^ ((c & 7) << 4);
      bf16x8 a0 = *(const bf16x8*)(xs + ab0);
      bf16x8 a1 = *(const bf16x8*)(xs + ab1);
      #pragma unroll
      for (int nf = 0; nf < 4; ++nf) {
        acc1[0][nf] = __builtin_amdgcn_mfma_f32_16x16x32_bf16(a0, bcur[nf], acc1[0][nf], 0, 0, 0);
        acc1[1][nf] = __builtin_amdgcn_mfma_f32_16x16x32_bf16(a1, bcur[nf], acc1[1][nf], 0, 0, 0);
      }
      #pragma unroll
      for (int nf = 0; nf < 4; ++nf) bcur[nf] = bnext[nf];
    }
    // store this half's hidden: relu(acc1 + b1) -> hs bf16, swizzled
    #pragma unroll
    for (int nf = 0; nf < 4; ++nf) {
      int n = w * 128 + half * 64 + nf * 16 + c;
      float bb = b1[n];
      #pragma unroll
      for (int mf = 0; mf < 2; ++mf) {
        #pragma unroll
        for (int i = 0; i < 4; ++i) {
          int m = mf * 16 + kg * 4 + i;
          float v = fmaxf(acc1[mf][nf][i] + bb, 0.f);
          int byte = (m * 2048 + n * 2) ^ ((m & 7) << 4);
          *(unsigned short*)(hs + byte) = f2bf(v);
        }
      }
    }
  }
  __syncthreads();

  // ---- GEMM2: y[32][256] = hid @ W2, B double-buffered ----
  f32x4 acc2[2][2];
  #pragma unroll
  for (int mf = 0; mf < 2; ++mf)
    #pragma unroll
    for (int nf = 0; nf < 2; ++nf) acc2[mf][nf] = (f32x4){0.f, 0.f, 0.f, 0.f};
  const unsigned short* wp2 = W2T + (size_t)(w * 32) * 1024 + kg * 8;
  bf16x8 b2cur[2];
  #pragma unroll
  for (int nf = 0; nf < 2; ++nf)
    b2cur[nf] = *(const bf16x8*)(wp2 + (size_t)(nf * 16 + c) * 1024);
  #pragma unroll
  for (int kc = 0; kc < 32; ++kc) {
    bf16x8 b2next[2];
    #pragma unroll
    for (int nf = 0; nf < 2; ++nf)
      b2next[nf] = (kc < 31)
          ? *(const bf16x8*)(wp2 + (size_t)(nf * 16 + c) * 1024 + (kc + 1) * 32)
          : b2cur[nf];
    int ab0 = (c * 2048 + kc * 64 + kg * 16) ^ ((c & 7) << 4);
    int ab1 = ((16 + c) * 2048 + kc * 64 + kg * 16) ^ ((c & 7) << 4);
    bf16x8 a0 = *(const bf16x8*)(hs + ab0);
    bf16x8 a1 = *(const bf16x8*)(hs + ab1);
    #pragma unroll
    for (int nf = 0; nf < 2; ++nf) {
      acc2[0][nf] = __builtin_amdgcn_mfma_f32_16x16x32_bf16(a0, b2cur[nf], acc2[0][nf], 0, 0, 0);
      acc2[1][nf] = __builtin_amdgcn_mfma_f32_16x16x32_bf16(a1, b2cur[nf], acc2[1][nf], 0, 0, 0);
    }
    #pragma unroll
    for (int nf = 0; nf < 2; ++nf) b2cur[nf] = b2next[nf];
  }
  __syncthreads();

  #pragma unroll
  for (int nf = 0; nf < 2; ++nf) {
    int n2 = w * 32 + nf * 16 + c;
    float bb = b2[n2];
    #pragma unroll
    for (int mf = 0; mf < 2; ++mf) {
      #pragma unroll
      for (int i = 0; i < 4; ++i) {
        int m = mf * 16 + kg * 4 + i;
        out_s[m * 260 + n2] = acc2[mf][nf][i] + bb + X[(size_t)(row0 + m) * 256 + n2];
      }
    }
  }
  __syncthreads();

  float4 gv = *(const float4*)(g2 + lane * 4);
  float4 bev = *(const float4*)(be2 + lane * 4);
  #pragma unroll
  for (int rr = 0; rr < 4; ++rr) {
    int r = w * 4 + rr;
    float4 v = *(const float4*)(out_s + r * 260 + lane * 4);
    float s = v.x + v.y + v.z + v.w;
    float s2 = v.x * v.x + v.y * v.y + v.z * v.z + v.w * v.w;
    #pragma unroll
    for (int o = 1; o < 64; o <<= 1) {
      s += __shfl_xor(s, o, 64);
      s2 += __shfl_xor(s2, o, 64);
    }
    float mean = s * (1.f / 256.f);
    float var = s2 * (1.f / 256.f) - mean * mean;
    float rstd = rsqrtf(var + 1e-5f);
    float4 o4;
    o4.x = (v.x - mean) * rstd * gv.x + bev.x;
    o4.y = (v.y - mean) * rstd * gv.y + bev.y;
    o4.z = (v.z - mean) * rstd * gv.z + bev.z;
    o4.w = (v.w - mean) * rstd * gv.w + bev.w;
    *(float4*)(Out + (size_t)(row0 + r) * 256 + lane * 4) = o4;
  }
}

// ---------------------------------------------------------------------------
// Launch
// ---------------------------------------------------------------------------
extern "C" void kernel_launch(void* const* d_in, const int* in_sizes, int n_in,
                              void* d_out, int out_size, void* d_ws, size_t ws_size,
                              hipStream_t stream) {
  const float* q     = (const float*)d_in[0];
  const float* v     = (const float*)d_in[2];
  const float* refp  = (const float*)d_in[3];
  const float* W_off = (const float*)d_in[6];
  const float* b_off = (const float*)d_in[7];
  const float* W_at  = (const float*)d_in[8];
  const float* b_at  = (const float*)d_in[9];
  const float* W_val = (const float*)d_in[10];
  const float* b_val = (const float*)d_in[11];
  const float* W_out = (const float*)d_in[12];
  const float* b_out = (const float*)d_in[13];
  const float* W1    = (const float*)d_in[14];
  const float* b1    = (const float*)d_in[15];
  const float* W2    = (const float*)d_in[16];
  const float* b2    = (const float*)d_in[17];
  const float* g1    = (const float*)d_in[18];
  const float* be1   = (const float*)d_in[19];
  const float* g2    = (const float*)d_in[20];
  const float* be2   = (const float*)d_in[21];
  float* out = (float*)d_out;

  // Workspace layout (exactly R16)
  float* ws   = (float*)d_ws;
  float* valb = ws;                                   // fp32 [M][256] region
  unsigned short* valbB = (unsigned short*)valb;      // bf16 [M][256]
  float* offb = valb + (size_t)VROWS * 256;           // fp32 [M][256] region
  unsigned short* offbB = (unsigned short*)offb;      // bf16 [M][256]
  unsigned short* qb = (unsigned short*)(offb + (size_t)MROWS * 256); // slot
  unsigned short* vb = qb + (size_t)MROWS * 256;      // slot
  unsigned short* msdaB = qb;                         // msda output bf16 [M][256]
  unsigned short* awb = vb + (size_t)MROWS * 256;     // bf16 [M][128]
  unsigned short* WoffT  = awb + (size_t)MROWS * 128; // [256][256]
  unsigned short* WattnT = WoffT + 65536;             // [128][256]
  unsigned short* WvalT  = WattnT + 32768;            // [256][256]
  unsigned short* W1T    = WvalT + 65536;             // [1024][256]
  unsigned short* W2T    = W1T + 262144;              // [256][1024]
  unsigned short* WoutT  = W2T + 262144;              // [256][256]
  float* attnb = offb;                                // alias: offbB dead after msda
  float* xb = valb;                                   // alias: valbB dead after msda

  prep_all<<<2688, 256, 0, stream>>>(W_off, W_at, W_val, W1, W2,
                                     WoffT, WattnT, WvalT, W1T, W2T);
  prep_wout<<<256, 256, 0, stream>>>(W_out, WoutT);
  // value projection: fp32 v in, bf16 out
  proj_mfma<256, 3, 1><<<MROWS / 32, 512, 0, stream>>>(v, WvalT, b_val, nullptr, valbB);
  // offset projection: fp32 q in, bf16 out
  proj_mfma<256, 3, 1><<<MROWS / 32, 512, 0, stream>>>(q, WoffT, b_off, nullptr, offbB);
  // attention-weight projection + softmax: fp32 q in, bf16 out
  proj_mfma<128, 1, 1><<<MROWS / 64, 512, 0, stream>>>(q, WattnT, b_at, nullptr, awb);
  // deformable bilinear sampling v7 (8 queries/block, 16B gathers)
  msda_sample<<<MROWS / 8, 256, 0, stream>>>(valbB, offbB, awb, refp, msdaB);
  // out-projection: bf16 msda in -> fp32 attn (into dead offb region)
  proj_mfma<256, 0, 0><<<MROWS / 32, 512, 0, stream>>>(msdaB, WoutT, b_out, attnb, nullptr);
  // residual + LayerNorm1 (separate, proven)
  resid_ln<<<MROWS / 4, 256, 0, stream>>>(attnb, q, g1, be1, xb);
  // fused FFN v5 + residual + LayerNorm2 (proven)
  ffn_mfma<<<MROWS / 32, 512, 0, stream>>>(xb, W1T, b1, W2T, b2, g2, be2, out);
}

// Round 18
// 428.720 us; speedup vs baseline: 1.1227x; 1.0223x over previous
//
#include <hip/hip_runtime.h>
#include <hip/hip_bf16.h>
#include <math.h>

// Problem constants (fixed by the reference file)
#define BB 2
#define NN 21760
#define CC 256
#define HH 8
#define PP 21760
#define MROWS (BB * NN)   // 43520 query rows
#define VROWS (BB * PP)   // 43520 value rows

typedef __attribute__((ext_vector_type(8))) short bf16x8;
typedef __attribute__((ext_vector_type(4))) float f32x4;

__device__ __forceinline__ unsigned short f2bf(float f) {
  unsigned u = __float_as_uint(f);
  u += 0x7fff + ((u >> 16) & 1);   // RNE
  return (unsigned short)(u >> 16);
}
__device__ __forceinline__ float bf2f(unsigned short s) {
  return __uint_as_float(((unsigned)s) << 16);
}
// packed-u32 bf16 pair -> two floats (lo = bits[15:0], hi = bits[31:16])
__device__ __forceinline__ float bflo(unsigned u) { return __uint_as_float(u << 16); }
__device__ __forceinline__ float bfhi(unsigned u) { return __uint_as_float(u & 0xffff0000u); }

// ---------------------------------------------------------------------------
// Weights -> transposed bf16 [N][K].  R7-proven 6-weight version.
// 753664 total elements, grid 2944.
// ---------------------------------------------------------------------------
__global__ __launch_bounds__(256) void prep_all(
    const float* __restrict__ W_off, const float* __restrict__ W_at,
    const float* __restrict__ W_val, const float* __restrict__ W_out,
    const float* __restrict__ W1, const float* __restrict__ W2,
    unsigned short* __restrict__ WoffT, unsigned short* __restrict__ WattnT,
    unsigned short* __restrict__ WvalT, unsigned short* __restrict__ WoutT,
    unsigned short* __restrict__ W1T, unsigned short* __restrict__ W2T) {
  int i = blockIdx.x * 256 + threadIdx.x;
  if (i < 65536) {                    // WoffT[256][256]
    WoffT[i] = f2bf(W_off[(size_t)(i & 255) * 256 + (i >> 8)]);
  } else if (i < 98304) {             // WattnT[128][256]
    int j = i - 65536;
    WattnT[j] = f2bf(W_at[(size_t)(j & 255) * 128 + (j >> 8)]);
  } else if (i < 163840) {            // WvalT[256][256]
    int j = i - 98304;
    WvalT[j] = f2bf(W_val[(size_t)(j & 255) * 256 + (j >> 8)]);
  } else if (i < 229376) {            // WoutT[256][256]
    int j = i - 163840;
    WoutT[j] = f2bf(W_out[(size_t)(j & 255) * 256 + (j >> 8)]);
  } else if (i < 491520) {            // W1T[1024][256]
    int j = i - 229376;
    W1T[j] = f2bf(W1[(size_t)(j & 255) * 1024 + (j >> 8)]);
  } else if (i < 753664) {            // W2T[256][1024]
    int j = i - 491520;
    W2T[j] = f2bf(W2[(size_t)(j & 1023) * 256 + (j >> 10)]);
  }
}

// ---------------------------------------------------------------------------
// Projection GEMM via bf16 MFMA: C[M][NC] = A[M][256] @ BT^T + bias
// 8 waves, 512 threads.  NC=256: M-tile 32.
// EPI: 0 = +bias -> fp32;  3 = +bias -> bf16
// FSRC: 0 = A bf16;  1 = A fp32 (staged with the ffn-proven convert loop)
// ---------------------------------------------------------------------------
template <int NC, int EPI, int FSRC>
__global__ __launch_bounds__(512, 4) void proj_mfma(
    const void* __restrict__ Ain, const unsigned short* __restrict__ BT,
    const float* __restrict__ bias,
    float* __restrict__ outF, unsigned short* __restrict__ outB) {
  constexpr int MTILE = 32;
  __shared__ __align__(16) char xs[MTILE * 512];

  const int row0 = blockIdx.x * MTILE;
  const int t = threadIdx.x;
  const int w = t >> 6, lane = t & 63;
  const int c = lane & 15, kg = lane >> 4;
  const int nbase = w * 32;

  // ---- stage A tile -> swizzled bf16 LDS ----
  if (FSRC) {
    const float* A = (const float*)Ain;
    for (int i = t; i < MTILE * 128; i += 512) {
      int m = i >> 7;
      int np = i & 127;
      float2 xv = *(const float2*)(A + (size_t)(row0 + m) * 256 + np * 2);
      unsigned pk = (unsigned)f2bf(xv.x) | ((unsigned)f2bf(xv.y) << 16);
      int byte = (m * 512 + np * 4) ^ ((m & 7) << 4);
      *(unsigned*)(xs + byte) = pk;
    }
  } else {
    const unsigned short* A = (const unsigned short*)Ain;
    #pragma unroll
    for (int p = 0; p < MTILE / 16; ++p) {
      int i = t + p * 512;          // 16B chunk id
      int m = i >> 5, c16 = i & 31;
      ushort4 v0 = *(const ushort4*)(A + (size_t)(row0 + m) * 256 + c16 * 8);
      ushort4 v1 = *(const ushort4*)(A + (size_t)(row0 + m) * 256 + c16 * 8 + 4);
      int byte = (m * 512 + c16 * 16) ^ ((m & 7) << 4);
      *(ushort4*)(xs + byte) = v0;
      *(ushort4*)(xs + byte + 8) = v1;
    }
  }
  __syncthreads();

  // ---- GEMM ----
  f32x4 acc[2][2];
  #pragma unroll
  for (int mf = 0; mf < 2; ++mf)
    #pragma unroll
    for (int nf = 0; nf < 2; ++nf) acc[mf][nf] = (f32x4){0.f, 0.f, 0.f, 0.f};
  #pragma unroll
  for (int kc = 0; kc < 8; ++kc) {
    int ab0 = (c * 512 + kc * 64 + kg * 16) ^ ((c & 7) << 4);
    int ab1 = ((16 + c) * 512 + kc * 64 + kg * 16) ^ ((c & 7) << 4);
    bf16x8 a0 = *(const bf16x8*)(xs + ab0);
    bf16x8 a1 = *(const bf16x8*)(xs + ab1);
    #pragma unroll
    for (int nf = 0; nf < 2; ++nf) {
      bf16x8 b = *(const bf16x8*)(BT + (size_t)(nbase + nf * 16 + c) * 256 + kc * 32 + kg * 8);
      acc[0][nf] = __builtin_amdgcn_mfma_f32_16x16x32_bf16(a0, b, acc[0][nf], 0, 0, 0);
      acc[1][nf] = __builtin_amdgcn_mfma_f32_16x16x32_bf16(a1, b, acc[1][nf], 0, 0, 0);
    }
  }

  // ---- epilogue ----
  if (EPI == 0) {
    #pragma unroll
    for (int nf = 0; nf < 2; ++nf) {
      int n = nbase + nf * 16 + c;
      float bb = bias[n];
      #pragma unroll
      for (int mf = 0; mf < 2; ++mf)
        #pragma unroll
        for (int i = 0; i < 4; ++i) {
          int m = mf * 16 + kg * 4 + i;
          outF[(size_t)(row0 + m) * NC + n] = acc[mf][nf][i] + bb;
        }
    }
  } else {
    #pragma unroll
    for (int nf = 0; nf < 2; ++nf) {
      int n = nbase + nf * 16 + c;
      float bb = bias[n];
      #pragma unroll
      for (int mf = 0; mf < 2; ++mf)
        #pragma unroll
        for (int i = 0; i < 4; ++i) {
          int m = mf * 16 + kg * 4 + i;
          outB[(size_t)(row0 + m) * NC + n] = f2bf(acc[mf][nf][i] + bb);
        }
    }
  }
}

// ---------------------------------------------------------------------------
// Fused q-projection: C[M][384] = q @ [W_off | W_attn]^T.
// WqT = [384][256] (WoffT rows 0..255, WattnT rows 256..383 — adjacent in ws).
// 8 waves x 48 cols, acc[2][3].  Per nf-frag (16-aligned), region is
// wave-uniform: n<256 -> off (bf16 store), n>=256 -> attn (16-lane softmax).
// Staging + GEMM core + both epilogues are the proven pieces.
// ---------------------------------------------------------------------------
__global__ __launch_bounds__(512, 4) void proj_qfused(
    const float* __restrict__ Q, const unsigned short* __restrict__ WqT,
    const float* __restrict__ b_off, const float* __restrict__ b_at,
    unsigned short* __restrict__ offB, unsigned short* __restrict__ awB) {
  __shared__ __align__(16) char xs[32 * 512];

  const int row0 = blockIdx.x * 32;
  const int t = threadIdx.x;
  const int w = t >> 6, lane = t & 63;
  const int c = lane & 15, kg = lane >> 4;
  const int nbase = w * 48;

  // ---- stage q tile (fp32 -> bf16 swizzled LDS), ffn-proven ----
  for (int i = t; i < 4096; i += 512) {
    int m = i >> 7;
    int np = i & 127;
    float2 xv = *(const float2*)(Q + (size_t)(row0 + m) * 256 + np * 2);
    unsigned pk = (unsigned)f2bf(xv.x) | ((unsigned)f2bf(xv.y) << 16);
    int byte = (m * 512 + np * 4) ^ ((m & 7) << 4);
    *(unsigned*)(xs + byte) = pk;
  }
  __syncthreads();

  // ---- GEMM: acc[2][3] over 48 cols ----
  f32x4 acc[2][3];
  #pragma unroll
  for (int mf = 0; mf < 2; ++mf)
    #pragma unroll
    for (int nf = 0; nf < 3; ++nf) acc[mf][nf] = (f32x4){0.f, 0.f, 0.f, 0.f};
  #pragma unroll
  for (int kc = 0; kc < 8; ++kc) {
    int ab0 = (c * 512 + kc * 64 + kg * 16) ^ ((c & 7) << 4);
    int ab1 = ((16 + c) * 512 + kc * 64 + kg * 16) ^ ((c & 7) << 4);
    bf16x8 a0 = *(const bf16x8*)(xs + ab0);
    bf16x8 a1 = *(const bf16x8*)(xs + ab1);
    #pragma unroll
    for (int nf = 0; nf < 3; ++nf) {
      bf16x8 b = *(const bf16x8*)(WqT + (size_t)(nbase + nf * 16 + c) * 256 + kc * 32 + kg * 8);
      acc[0][nf] = __builtin_amdgcn_mfma_f32_16x16x32_bf16(a0, b, acc[0][nf], 0, 0, 0);
      acc[1][nf] = __builtin_amdgcn_mfma_f32_16x16x32_bf16(a1, b, acc[1][nf], 0, 0, 0);
    }
  }

  // ---- epilogue: per nf-frag, off (n<256) or attn softmax (n>=256) ----
  #pragma unroll
  for (int nf = 0; nf < 3; ++nf) {
    int n = nbase + nf * 16 + c;
    if (nbase + nf * 16 < 256) {
      // off region: +b_off -> bf16 (EPI3 code)
      float bb = b_off[n];
      #pragma unroll
      for (int mf = 0; mf < 2; ++mf)
        #pragma unroll
        for (int i = 0; i < 4; ++i) {
          int m = mf * 16 + kg * 4 + i;
          offB[(size_t)(row0 + m) * 256 + n] = f2bf(acc[mf][nf][i] + bb);
        }
    } else {
      // attn region: +b_at, softmax over the 16 c-lanes (EPI1 code)
      int na = n - 256;
      float bb = b_at[na];
      #pragma unroll
      for (int mf = 0; mf < 2; ++mf)
        #pragma unroll
        for (int i = 0; i < 4; ++i) {
          float vv = acc[mf][nf][i] + bb;
          float mx = vv;
          mx = fmaxf(mx, __shfl_xor(mx, 1, 64));
          mx = fmaxf(mx, __shfl_xor(mx, 2, 64));
          mx = fmaxf(mx, __shfl_xor(mx, 4, 64));
          mx = fmaxf(mx, __shfl_xor(mx, 8, 64));
          float e = expf(vv - mx);
          float s = e;
          s += __shfl_xor(s, 1, 64);
          s += __shfl_xor(s, 2, 64);
          s += __shfl_xor(s, 4, 64);
          s += __shfl_xor(s, 8, 64);
          int m = mf * 16 + kg * 4 + i;
          awB[(size_t)(row0 + m) * 128 + na] = f2bf(e / s);
        }
    }
  }
}

// ---------------------------------------------------------------------------
// Deformable sampling v7 (R17, proven): 8 queries/block, 16B gathers.
// ---------------------------------------------------------------------------
__global__ __launch_bounds__(256) void msda_sample(
    const unsigned short* __restrict__ value, const unsigned short* __restrict__ off,
    const unsigned short* __restrict__ aw, const float* __restrict__ refp,
    unsigned short* __restrict__ out) {
  __shared__ __align__(16) int4   s_idx[8 * 16 * 8];   // [qi][i][h]
  __shared__ __align__(16) float4 s_w[8 * 16 * 8];
  const int t = threadIdx.x;
  const int bn0 = blockIdx.x * 8;
  const int b = bn0 / NN;

  #pragma unroll
  for (int ss = 0; ss < 4; ++ss) {
    const int s = t + ss * 256;
    const int qi = s >> 7;
    const int j  = s & 127;         // h*16 + l*4 + k
    const int bn = bn0 + qi;
    const int l  = (j >> 2) & 3;
    const int h  = j >> 4;
    const int i  = j & 15;
    const int szl = 128 >> l;
    const int st0l = (l == 0) ? 0 : (l == 1) ? 16384 : (l == 2) ? 20480 : 21504;

    unsigned op = *(const unsigned*)(off + (size_t)bn * 256 + j * 2);
    float ox = bflo(op);
    float oy = bfhi(op);
    float a  = bf2f(aw[(size_t)bn * 128 + j]);
    float rx = refp[(size_t)bn * 8 + l * 2 + 0];
    float ry = refp[(size_t)bn * 8 + l * 2 + 1];

    float x = rx * (float)szl + ox - 0.5f;
    float y = ry * (float)szl + oy - 0.5f;
    float x0f = floorf(x), y0f = floorf(y);
    float wx = x - x0f, wy = y - y0f;
    int x0 = (int)x0f, y0 = (int)y0f;
    int x1 = x0 + 1, y1 = y0 + 1;

    bool vx0 = (x0 >= 0) & (x0 < szl);
    bool vx1 = (x1 >= 0) & (x1 < szl);
    bool vy0 = (y0 >= 0) & (y0 < szl);
    bool vy1 = (y1 >= 0) & (y1 < szl);
    int cx0 = min(max(x0, 0), szl - 1);
    int cx1 = min(max(x1, 0), szl - 1);
    int cy0 = min(max(y0, 0), szl - 1);
    int cy1 = min(max(y1, 0), szl - 1);

    int base = st0l * 256 + h * 32;
    int4 iv;
    iv.x = base + (cy0 * szl + cx0) * 256;
    iv.y = base + (cy0 * szl + cx1) * 256;
    iv.z = base + (cy1 * szl + cx0) * 256;
    iv.w = base + (cy1 * szl + cx1) * 256;
    float4 wv;
    wv.x = (vx0 & vy0) ? a * (1.f - wx) * (1.f - wy) : 0.f;
    wv.y = (vx1 & vy0) ? a * wx * (1.f - wy) : 0.f;
    wv.z = (vx0 & vy1) ? a * (1.f - wx) * wy : 0.f;
    wv.w = (vx1 & vy1) ? a * wx * wy : 0.f;

    int slot = (qi * 16 + i) * 8 + h;
    s_idx[slot] = iv;
    s_w[slot] = wv;
  }
  __syncthreads();

  const int wv_ = t >> 6;
  const int lane = t & 63;
  const int qi = wv_ * 2 + (lane >> 5);
  const int h = (lane >> 2) & 7;
  const int d8 = lane & 3;
  const unsigned short* vcol = value + (size_t)b * PP * 256 + d8 * 8;

  float4 a0a = {0,0,0,0}, a0b = {0,0,0,0}, a1a = {0,0,0,0}, a1b = {0,0,0,0};
  float4 a2a = {0,0,0,0}, a2b = {0,0,0,0}, a3a = {0,0,0,0}, a3b = {0,0,0,0};
  #pragma unroll 4
  for (int i = 0; i < 16; ++i) {
    int slot = (qi * 16 + i) * 8 + h;
    int4 iv = s_idx[slot];
    float4 wv = s_w[slot];
    int4 u0 = *(const int4*)(vcol + iv.x);
    int4 u1 = *(const int4*)(vcol + iv.y);
    int4 u2 = *(const int4*)(vcol + iv.z);
    int4 u3 = *(const int4*)(vcol + iv.w);
    a0a.x += wv.x * bflo(u0.x); a0a.y += wv.x * bfhi(u0.x);
    a0a.z += wv.x * bflo(u0.y); a0a.w += wv.x * bfhi(u0.y);
    a0b.x += wv.x * bflo(u0.z); a0b.y += wv.x * bfhi(u0.z);
    a0b.z += wv.x * bflo(u0.w); a0b.w += wv.x * bfhi(u0.w);
    a1a.x += wv.y * bflo(u1.x); a1a.y += wv.y * bfhi(u1.x);
    a1a.z += wv.y * bflo(u1.y); a1a.w += wv.y * bfhi(u1.y);
    a1b.x += wv.y * bflo(u1.z); a1b.y += wv.y * bfhi(u1.z);
    a1b.z += wv.y * bflo(u1.w); a1b.w += wv.y * bfhi(u1.w);
    a2a.x += wv.z * bflo(u2.x); a2a.y += wv.z * bfhi(u2.x);
    a2a.z += wv.z * bflo(u2.y); a2a.w += wv.z * bfhi(u2.y);
    a2b.x += wv.z * bflo(u2.z); a2b.y += wv.z * bfhi(u2.z);
    a2b.z += wv.z * bflo(u2.w); a2b.w += wv.z * bfhi(u2.w);
    a3a.x += wv.w * bflo(u3.x); a3a.y += wv.w * bfhi(u3.x);
    a3a.z += wv.w * bflo(u3.y); a3a.w += wv.w * bfhi(u3.y);
    a3b.x += wv.w * bflo(u3.z); a3b.y += wv.w * bfhi(u3.z);
    a3b.z += wv.w * bflo(u3.w); a3b.w += wv.w * bfhi(u3.w);
  }
  float4 ra, rb;
  ra.x = (a0a.x + a1a.x) + (a2a.x + a3a.x);
  ra.y = (a0a.y + a1a.y) + (a2a.y + a3a.y);
  ra.z = (a0a.z + a1a.z) + (a2a.z + a3a.z);
  ra.w = (a0a.w + a1a.w) + (a2a.w + a3a.w);
  rb.x = (a0b.x + a1b.x) + (a2b.x + a3b.x);
  rb.y = (a0b.y + a1b.y) + (a2b.y + a3b.y);
  rb.z = (a0b.z + a1b.z) + (a2b.z + a3b.z);
  rb.w = (a0b.w + a1b.w) + (a2b.w + a3b.w);
  int4 ob;
  ob.x = (int)((unsigned)f2bf(ra.x) | ((unsigned)f2bf(ra.y) << 16));
  ob.y = (int)((unsigned)f2bf(ra.z) | ((unsigned)f2bf(ra.w) << 16));
  ob.z = (int)((unsigned)f2bf(rb.x) | ((unsigned)f2bf(rb.y) << 16));
  ob.w = (int)((unsigned)f2bf(rb.z) | ((unsigned)f2bf(rb.w) << 16));
  *(int4*)(out + (size_t)(bn0 + qi) * 256 + h * 32 + d8 * 8) = ob;
}

// ---------------------------------------------------------------------------
// Residual + LayerNorm1: x = LN(attn + 2q) * g + be.  One wave per row.
// ---------------------------------------------------------------------------
__global__ __launch_bounds__(256) void resid_ln(
    const float* __restrict__ A, const float* __restrict__ q,
    const float* __restrict__ g, const float* __restrict__ be,
    float* __restrict__ X) {
  const int row = blockIdx.x * 4 + (threadIdx.x >> 6);
  const int lane = threadIdx.x & 63;
  const size_t base = (size_t)row * 256 + lane * 4;
  float4 a = *(const float4*)(A + base);
  float4 qv = *(const float4*)(q + base);
  float4 v;
  v.x = a.x + 2.f * qv.x;
  v.y = a.y + 2.f * qv.y;
  v.z = a.z + 2.f * qv.z;
  v.w = a.w + 2.f * qv.w;
  float s = v.x + v.y + v.z + v.w;
  float s2 = v.x * v.x + v.y * v.y + v.z * v.z + v.w * v.w;
  #pragma unroll
  for (int o = 1; o < 64; o <<= 1) {
    s += __shfl_xor(s, o, 64);
    s2 += __shfl_xor(s2, o, 64);
  }
  float mean = s * (1.f / 256.f);
  float var = s2 * (1.f / 256.f) - mean * mean;
  float rstd = rsqrtf(var + 1e-5f);
  float4 gv = *(const float4*)(g + lane * 4);
  float4 bev = *(const float4*)(be + lane * 4);
  float4 o4;
  o4.x = (v.x - mean) * rstd * gv.x + bev.x;
  o4.y = (v.y - mean) * rstd * gv.y + bev.y;
  o4.z = (v.z - mean) * rstd * gv.z + bev.z;
  o4.w = (v.w - mean) * rstd * gv.w + bev.w;
  *(float4*)(X + base) = o4;
}

// ---------------------------------------------------------------------------
// Fused FFN v5 (proven): M-tile=32, 8 waves, LDS 80KB, launch_bounds(512,4).
// ---------------------------------------------------------------------------
__global__ __launch_bounds__(512, 4) void ffn_mfma(
    const float* __restrict__ X, const unsigned short* __restrict__ W1T,
    const float* __restrict__ b1, const unsigned short* __restrict__ W2T,
    const float* __restrict__ b2, const float* __restrict__ g2,
    const float* __restrict__ be2, float* __restrict__ Out) {
  __shared__ __align__(16) char smem[16384 + 65536];
  char* xs = smem;            // 32 x 512 B
  char* hs = smem + 16384;    // 32 x 2048 B
  float* out_s = (float*)(smem + 16384);   // 32 x 260 f32, aliases hs

  const int row0 = blockIdx.x * 32;
  const int t = threadIdx.x;
  const int w = t >> 6, lane = t & 63;
  const int c = lane & 15, kg = lane >> 4;

  for (int i = t; i < 4096; i += 512) {
    int m = i >> 7;
    int np = i & 127;
    float2 xv = *(const float2*)(X + (size_t)(row0 + m) * 256 + np * 2);
    unsigned pk = (unsigned)f2bf(xv.x) | ((unsigned)f2bf(xv.y) << 16);
    int byte = (m * 512 + np * 4) ^ ((m & 7) << 4);
    *(unsigned*)(xs + byte) = pk;
  }
  __syncthreads();

  // ---- GEMM1 in two nf-halves (64 cols each), B double-buffered ----
  #pragma unroll
  for (int half = 0; half < 2; ++half) {
    f32x4 acc1[2][4];
    #pragma unroll
    for (int mf = 0; mf < 2; ++mf)
      #pragma unroll
      for (int nf = 0; nf < 4; ++nf) acc1[mf][nf] = (f32x4){0.f, 0.f, 0.f, 0.f};

    const unsigned short* wp1 = W1T + (size_t)(w * 128 + half * 64) * 256 + kg * 8;
    bf16x8 bcur[4];
    #pragma unroll
    for (int nf = 0; nf < 4; ++nf)
      bcur[nf] = *(const bf16x8*)(wp1 + (size_t)(nf * 16 + c) * 256);
    #pragma unroll
    for (int kc = 0; kc < 8; ++kc) {
      bf16x8 bnext[4];
      #pragma unroll
      for (int nf = 0; nf < 4; ++nf)
        bnext[nf] = (kc < 7)
            ? *(const bf16x8*)(wp1 + (size_t)(nf * 16 + c) * 256 + (kc + 1) * 32)
            : bcur[nf];
      int ab0 = (c * 512 + kc * 64 + kg * 16) ^ ((c & 7) << 4);
      int ab1 = ((16 + c) * 512 + kc * 64 + kg * 16) ^ ((c & 7) << 4);
      bf16x8 a0 = *(const bf16x8*)(xs + ab0);
      bf16x8 a1 = *(const bf16x8*)(xs + ab1);
      #pragma unroll
      for (int nf = 0; nf < 4; ++nf) {
        acc1[0][nf] = __builtin_amdgcn_mfma_f32_16x16x32_bf16(a0, bcur[nf], acc1[0][nf], 0, 0, 0);
        acc1[1][nf] = __builtin_amdgcn_mfma_f32_16x16x32_bf16(a1, bcur[nf], acc1[1][nf], 0, 0, 0);
      }
      #pragma unroll
      for (int nf = 0; nf < 4; ++nf) bcur[nf] = bnext[nf];
    }
    // store this half's hidden: relu(acc1 + b1) -> hs bf16, swizzled
    #pragma unroll
    for (int nf = 0; nf < 4; ++nf) {
      int n = w * 128 + half * 64 + nf * 16 + c;
      float bb = b1[n];
      #pragma unroll
      for (int mf = 0; mf < 2; ++mf) {
        #pragma unroll
        for (int i = 0; i < 4; ++i) {
          int m = mf * 16 + kg * 4 + i;
          float v = fmaxf(acc1[mf][nf][i] + bb, 0.f);
          int byte = (m * 2048 + n * 2) ^ ((m & 7) << 4);
          *(unsigned short*)(hs + byte) = f2bf(v);
        }
      }
    }
  }
  __syncthreads();

  // ---- GEMM2: y[32][256] = hid @ W2, B double-buffered ----
  f32x4 acc2[2][2];
  #pragma unroll
  for (int mf = 0; mf < 2; ++mf)
    #pragma unroll
    for (int nf = 0; nf < 2; ++nf) acc2[mf][nf] = (f32x4){0.f, 0.f, 0.f, 0.f};
  const unsigned short* wp2 = W2T + (size_t)(w * 32) * 1024 + kg * 8;
  bf16x8 b2cur[2];
  #pragma unroll
  for (int nf = 0; nf < 2; ++nf)
    b2cur[nf] = *(const bf16x8*)(wp2 + (size_t)(nf * 16 + c) * 1024);
  #pragma unroll
  for (int kc = 0; kc < 32; ++kc) {
    bf16x8 b2next[2];
    #pragma unroll
    for (int nf = 0; nf < 2; ++nf)
      b2next[nf] = (kc < 31)
          ? *(const bf16x8*)(wp2 + (size_t)(nf * 16 + c) * 1024 + (kc + 1) * 32)
          : b2cur[nf];
    int ab0 = (c * 2048 + kc * 64 + kg * 16) ^ ((c & 7) << 4);
    int ab1 = ((16 + c) * 2048 + kc * 64 + kg * 16) ^ ((c & 7) << 4);
    bf16x8 a0 = *(const bf16x8*)(hs + ab0);
    bf16x8 a1 = *(const bf16x8*)(hs + ab1);
    #pragma unroll
    for (int nf = 0; nf < 2; ++nf) {
      acc2[0][nf] = __builtin_amdgcn_mfma_f32_16x16x32_bf16(a0, b2cur[nf], acc2[0][nf], 0, 0, 0);
      acc2[1][nf] = __builtin_amdgcn_mfma_f32_16x16x32_bf16(a1, b2cur[nf], acc2[1][nf], 0, 0, 0);
    }
    #pragma unroll
    for (int nf = 0; nf < 2; ++nf) b2cur[nf] = b2next[nf];
  }
  __syncthreads();

  #pragma unroll
  for (int nf = 0; nf < 2; ++nf) {
    int n2 = w * 32 + nf * 16 + c;
    float bb = b2[n2];
    #pragma unroll
    for (int mf = 0; mf < 2; ++mf) {
      #pragma unroll
      for (int i = 0; i < 4; ++i) {
        int m = mf * 16 + kg * 4 + i;
        out_s[m * 260 + n2] = acc2[mf][nf][i] + bb + X[(size_t)(row0 + m) * 256 + n2];
      }
    }
  }
  __syncthreads();

  float4 gv = *(const float4*)(g2 + lane * 4);
  float4 bev = *(const float4*)(be2 + lane * 4);
  #pragma unroll
  for (int rr = 0; rr < 4; ++rr) {
    int r = w * 4 + rr;
    float4 v = *(const float4*)(out_s + r * 260 + lane * 4);
    float s = v.x + v.y + v.z + v.w;
    float s2 = v.x * v.x + v.y * v.y + v.z * v.z + v.w * v.w;
    #pragma unroll
    for (int o = 1; o < 64; o <<= 1) {
      s += __shfl_xor(s, o, 64);
      s2 += __shfl_xor(s2, o, 64);
    }
    float mean = s * (1.f / 256.f);
    float var = s2 * (1.f / 256.f) - mean * mean;
    float rstd = rsqrtf(var + 1e-5f);
    float4 o4;
    o4.x = (v.x - mean) * rstd * gv.x + bev.x;
    o4.y = (v.y - mean) * rstd * gv.y + bev.y;
    o4.z = (v.z - mean) * rstd * gv.z + bev.z;
    o4.w = (v.w - mean) * rstd * gv.w + bev.w;
    *(float4*)(Out + (size_t)(row0 + r) * 256 + lane * 4) = o4;
  }
}

// ---------------------------------------------------------------------------
// Launch
// ---------------------------------------------------------------------------
extern "C" void kernel_launch(void* const* d_in, const int* in_sizes, int n_in,
                              void* d_out, int out_size, void* d_ws, size_t ws_size,
                              hipStream_t stream) {
  const float* q     = (const float*)d_in[0];
  const float* v     = (const float*)d_in[2];
  const float* refp  = (const float*)d_in[3];
  const float* W_off = (const float*)d_in[6];
  const float* b_off = (const float*)d_in[7];
  const float* W_at  = (const float*)d_in[8];
  const float* b_at  = (const float*)d_in[9];
  const float* W_val = (const float*)d_in[10];
  const float* b_val = (const float*)d_in[11];
  const float* W_out = (const float*)d_in[12];
  const float* b_out = (const float*)d_in[13];
  const float* W1    = (const float*)d_in[14];
  const float* b1    = (const float*)d_in[15];
  const float* W2    = (const float*)d_in[16];
  const float* b2    = (const float*)d_in[17];
  const float* g1    = (const float*)d_in[18];
  const float* be1   = (const float*)d_in[19];
  const float* g2    = (const float*)d_in[20];
  const float* be2   = (const float*)d_in[21];
  float* out = (float*)d_out;

  // Workspace layout (same as R16/R17; WoffT+WattnT adjacent = WqT[384][256])
  float* ws   = (float*)d_ws;
  float* valb = ws;                                   // fp32 [M][256] region
  unsigned short* valbB = (unsigned short*)valb;      // bf16 [M][256]
  float* offb = valb + (size_t)VROWS * 256;           // fp32 [M][256] region
  unsigned short* offbB = (unsigned short*)offb;      // bf16 [M][256]
  unsigned short* qb = (unsigned short*)(offb + (size_t)MROWS * 256); // slot
  unsigned short* vb = qb + (size_t)MROWS * 256;      // slot
  unsigned short* msdaB = qb;                         // msda output bf16 [M][256]
  unsigned short* awb = vb + (size_t)MROWS * 256;     // bf16 [M][128]
  unsigned short* WoffT  = awb + (size_t)MROWS * 128; // [256][256]  (= WqT base)
  unsigned short* WattnT = WoffT + 65536;             // [128][256]  (WqT rows 256..383)
  unsigned short* WvalT  = WattnT + 32768;            // [256][256]
  unsigned short* W1T    = WvalT + 65536;             // [1024][256]
  unsigned short* W2T    = W1T + 262144;              // [256][1024]
  unsigned short* WoutT  = W2T + 262144;              // [256][256]
  float* attnb = offb;                                // alias: offbB dead after msda
  float* xb = valb;                                   // alias: valbB dead after msda

  prep_all<<<2944, 256, 0, stream>>>(W_off, W_at, W_val, W_out, W1, W2,
                                     WoffT, WattnT, WvalT, WoutT, W1T, W2T);
  // value projection: fp32 v in, bf16 out
  proj_mfma<256, 3, 1><<<MROWS / 32, 512, 0, stream>>>(v, WvalT, b_val, nullptr, valbB);
  // fused offset + attention-weight projection (one q staging)
  proj_qfused<<<MROWS / 32, 512, 0, stream>>>(q, WoffT, b_off, b_at, offbB, awb);
  // deformable bilinear sampling v7
  msda_sample<<<MROWS / 8, 256, 0, stream>>>(valbB, offbB, awb, refp, msdaB);
  // out-projection: bf16 msda in -> fp32 attn (into dead offb region)
  proj_mfma<256, 0, 0><<<MROWS / 32, 512, 0, stream>>>(msdaB, WoutT, b_out, attnb, nullptr);
  // residual + LayerNorm1 (separate, proven)
  resid_ln<<<MROWS / 4, 256, 0, stream>>>(attnb, q, g1, be1, xb);
  // fused FFN v5 + residual + LayerNorm2 (proven)
  ffn_mfma<<<MROWS / 32, 512, 0, stream>>>(xb, W1T, b1, W2T, b2, g2, be2, out);
}

// Round 19
// 407.534 us; speedup vs baseline: 1.1810x; 1.0520x over previous
//
#include <hip/hip_runtime.h>
#include <hip/hip_bf16.h>
#include <math.h>

// Problem constants (fixed by the reference file)
#define BB 2
#define NN 21760
#define CC 256
#define HH 8
#define PP 21760
#define MROWS (BB * NN)   // 43520 query rows
#define VROWS (BB * PP)   // 43520 value rows

typedef __attribute__((ext_vector_type(8))) short bf16x8;
typedef __attribute__((ext_vector_type(4))) float f32x4;

__device__ __forceinline__ unsigned short f2bf(float f) {
  unsigned u = __float_as_uint(f);
  u += 0x7fff + ((u >> 16) & 1);   // RNE
  return (unsigned short)(u >> 16);
}
__device__ __forceinline__ float bf2f(unsigned short s) {
  return __uint_as_float(((unsigned)s) << 16);
}
// packed-u32 bf16 pair -> two floats (lo = bits[15:0], hi = bits[31:16])
__device__ __forceinline__ float bflo(unsigned u) { return __uint_as_float(u << 16); }
__device__ __forceinline__ float bfhi(unsigned u) { return __uint_as_float(u & 0xffff0000u); }

// ---------------------------------------------------------------------------
// Weights -> transposed bf16 [N][K].  R7-proven 6-weight version.
// ---------------------------------------------------------------------------
__global__ __launch_bounds__(256) void prep_all(
    const float* __restrict__ W_off, const float* __restrict__ W_at,
    const float* __restrict__ W_val, const float* __restrict__ W_out,
    const float* __restrict__ W1, const float* __restrict__ W2,
    unsigned short* __restrict__ WoffT, unsigned short* __restrict__ WattnT,
    unsigned short* __restrict__ WvalT, unsigned short* __restrict__ WoutT,
    unsigned short* __restrict__ W1T, unsigned short* __restrict__ W2T) {
  int i = blockIdx.x * 256 + threadIdx.x;
  if (i < 65536) {                    // WoffT[256][256]
    WoffT[i] = f2bf(W_off[(size_t)(i & 255) * 256 + (i >> 8)]);
  } else if (i < 98304) {             // WattnT[128][256]
    int j = i - 65536;
    WattnT[j] = f2bf(W_at[(size_t)(j & 255) * 128 + (j >> 8)]);
  } else if (i < 163840) {            // WvalT[256][256]
    int j = i - 98304;
    WvalT[j] = f2bf(W_val[(size_t)(j & 255) * 256 + (j >> 8)]);
  } else if (i < 229376) {            // WoutT[256][256]
    int j = i - 163840;
    WoutT[j] = f2bf(W_out[(size_t)(j & 255) * 256 + (j >> 8)]);
  } else if (i < 491520) {            // W1T[1024][256]
    int j = i - 229376;
    W1T[j] = f2bf(W1[(size_t)(j & 255) * 1024 + (j >> 8)]);
  } else if (i < 753664) {            // W2T[256][1024]
    int j = i - 491520;
    W2T[j] = f2bf(W2[(size_t)(j & 1023) * 256 + (j >> 10)]);
  }
}

// ---------------------------------------------------------------------------
// Projection GEMM via bf16 MFMA: C[M][NC] = A[M][256] @ BT^T + bias
// 8 waves, 512 threads.  M-tile 32.
// EPI: 0 = +bias -> fp32;  3 = +bias -> bf16
// FSRC: 0 = A bf16;  1 = A fp32 (staged with the ffn-proven convert loop)
// ---------------------------------------------------------------------------
template <int NC, int EPI, int FSRC>
__global__ __launch_bounds__(512, 4) void proj_mfma(
    const void* __restrict__ Ain, const unsigned short* __restrict__ BT,
    const float* __restrict__ bias,
    float* __restrict__ outF, unsigned short* __restrict__ outB) {
  constexpr int MTILE = 32;
  __shared__ __align__(16) char xs[MTILE * 512];

  const int row0 = blockIdx.x * MTILE;
  const int t = threadIdx.x;
  const int w = t >> 6, lane = t & 63;
  const int c = lane & 15, kg = lane >> 4;
  const int nbase = w * 32;

  // ---- stage A tile -> swizzled bf16 LDS ----
  if (FSRC) {
    const float* A = (const float*)Ain;
    for (int i = t; i < MTILE * 128; i += 512) {
      int m = i >> 7;
      int np = i & 127;
      float2 xv = *(const float2*)(A + (size_t)(row0 + m) * 256 + np * 2);
      unsigned pk = (unsigned)f2bf(xv.x) | ((unsigned)f2bf(xv.y) << 16);
      int byte = (m * 512 + np * 4) ^ ((m & 7) << 4);
      *(unsigned*)(xs + byte) = pk;
    }
  } else {
    const unsigned short* A = (const unsigned short*)Ain;
    #pragma unroll
    for (int p = 0; p < MTILE / 16; ++p) {
      int i = t + p * 512;          // 16B chunk id
      int m = i >> 5, c16 = i & 31;
      ushort4 v0 = *(const ushort4*)(A + (size_t)(row0 + m) * 256 + c16 * 8);
      ushort4 v1 = *(const ushort4*)(A + (size_t)(row0 + m) * 256 + c16 * 8 + 4);
      int byte = (m * 512 + c16 * 16) ^ ((m & 7) << 4);
      *(ushort4*)(xs + byte) = v0;
      *(ushort4*)(xs + byte + 8) = v1;
    }
  }
  __syncthreads();

  // ---- GEMM ----
  f32x4 acc[2][2];
  #pragma unroll
  for (int mf = 0; mf < 2; ++mf)
    #pragma unroll
    for (int nf = 0; nf < 2; ++nf) acc[mf][nf] = (f32x4){0.f, 0.f, 0.f, 0.f};
  #pragma unroll
  for (int kc = 0; kc < 8; ++kc) {
    int ab0 = (c * 512 + kc * 64 + kg * 16) ^ ((c & 7) << 4);
    int ab1 = ((16 + c) * 512 + kc * 64 + kg * 16) ^ ((c & 7) << 4);
    bf16x8 a0 = *(const bf16x8*)(xs + ab0);
    bf16x8 a1 = *(const bf16x8*)(xs + ab1);
    #pragma unroll
    for (int nf = 0; nf < 2; ++nf) {
      bf16x8 b = *(const bf16x8*)(BT + (size_t)(nbase + nf * 16 + c) * 256 + kc * 32 + kg * 8);
      acc[0][nf] = __builtin_amdgcn_mfma_f32_16x16x32_bf16(a0, b, acc[0][nf], 0, 0, 0);
      acc[1][nf] = __builtin_amdgcn_mfma_f32_16x16x32_bf16(a1, b, acc[1][nf], 0, 0, 0);
    }
  }

  // ---- epilogue ----
  if (EPI == 0) {
    #pragma unroll
    for (int nf = 0; nf < 2; ++nf) {
      int n = nbase + nf * 16 + c;
      float bb = bias[n];
      #pragma unroll
      for (int mf = 0; mf < 2; ++mf)
        #pragma unroll
        for (int i = 0; i < 4; ++i) {
          int m = mf * 16 + kg * 4 + i;
          outF[(size_t)(row0 + m) * NC + n] = acc[mf][nf][i] + bb;
        }
    }
  } else {
    #pragma unroll
    for (int nf = 0; nf < 2; ++nf) {
      int n = nbase + nf * 16 + c;
      float bb = bias[n];
      #pragma unroll
      for (int mf = 0; mf < 2; ++mf)
        #pragma unroll
        for (int i = 0; i < 4; ++i) {
          int m = mf * 16 + kg * 4 + i;
          outB[(size_t)(row0 + m) * NC + n] = f2bf(acc[mf][nf][i] + bb);
        }
    }
  }
}

// ---------------------------------------------------------------------------
// Fused q-projection (R18, proven): C[M][384] = q @ [W_off | W_attn]^T.
// ---------------------------------------------------------------------------
__global__ __launch_bounds__(512, 4) void proj_qfused(
    const float* __restrict__ Q, const unsigned short* __restrict__ WqT,
    const float* __restrict__ b_off, const float* __restrict__ b_at,
    unsigned short* __restrict__ offB, unsigned short* __restrict__ awB) {
  __shared__ __align__(16) char xs[32 * 512];

  const int row0 = blockIdx.x * 32;
  const int t = threadIdx.x;
  const int w = t >> 6, lane = t & 63;
  const int c = lane & 15, kg = lane >> 4;
  const int nbase = w * 48;

  for (int i = t; i < 4096; i += 512) {
    int m = i >> 7;
    int np = i & 127;
    float2 xv = *(const float2*)(Q + (size_t)(row0 + m) * 256 + np * 2);
    unsigned pk = (unsigned)f2bf(xv.x) | ((unsigned)f2bf(xv.y) << 16);
    int byte = (m * 512 + np * 4) ^ ((m & 7) << 4);
    *(unsigned*)(xs + byte) = pk;
  }
  __syncthreads();

  f32x4 acc[2][3];
  #pragma unroll
  for (int mf = 0; mf < 2; ++mf)
    #pragma unroll
    for (int nf = 0; nf < 3; ++nf) acc[mf][nf] = (f32x4){0.f, 0.f, 0.f, 0.f};
  #pragma unroll
  for (int kc = 0; kc < 8; ++kc) {
    int ab0 = (c * 512 + kc * 64 + kg * 16) ^ ((c & 7) << 4);
    int ab1 = ((16 + c) * 512 + kc * 64 + kg * 16) ^ ((c & 7) << 4);
    bf16x8 a0 = *(const bf16x8*)(xs + ab0);
    bf16x8 a1 = *(const bf16x8*)(xs + ab1);
    #pragma unroll
    for (int nf = 0; nf < 3; ++nf) {
      bf16x8 b = *(const bf16x8*)(WqT + (size_t)(nbase + nf * 16 + c) * 256 + kc * 32 + kg * 8);
      acc[0][nf] = __builtin_amdgcn_mfma_f32_16x16x32_bf16(a0, b, acc[0][nf], 0, 0, 0);
      acc[1][nf] = __builtin_amdgcn_mfma_f32_16x16x32_bf16(a1, b, acc[1][nf], 0, 0, 0);
    }
  }

  #pragma unroll
  for (int nf = 0; nf < 3; ++nf) {
    int n = nbase + nf * 16 + c;
    if (nbase + nf * 16 < 256) {
      float bb = b_off[n];
      #pragma unroll
      for (int mf = 0; mf < 2; ++mf)
        #pragma unroll
        for (int i = 0; i < 4; ++i) {
          int m = mf * 16 + kg * 4 + i;
          offB[(size_t)(row0 + m) * 256 + n] = f2bf(acc[mf][nf][i] + bb);
        }
    } else {
      int na = n - 256;
      float bb = b_at[na];
      #pragma unroll
      for (int mf = 0; mf < 2; ++mf)
        #pragma unroll
        for (int i = 0; i < 4; ++i) {
          float vv = acc[mf][nf][i] + bb;
          float mx = vv;
          mx = fmaxf(mx, __shfl_xor(mx, 1, 64));
          mx = fmaxf(mx, __shfl_xor(mx, 2, 64));
          mx = fmaxf(mx, __shfl_xor(mx, 4, 64));
          mx = fmaxf(mx, __shfl_xor(mx, 8, 64));
          float e = expf(vv - mx);
          float s = e;
          s += __shfl_xor(s, 1, 64);
          s += __shfl_xor(s, 2, 64);
          s += __shfl_xor(s, 4, 64);
          s += __shfl_xor(s, 8, 64);
          int m = mf * 16 + kg * 4 + i;
          awB[(size_t)(row0 + m) * 128 + na] = f2bf(e / s);
        }
    }
  }
}

// ---------------------------------------------------------------------------
// Deformable sampling v7 (proven): 8 queries/block, 16B gathers.
// ---------------------------------------------------------------------------
__global__ __launch_bounds__(256) void msda_sample(
    const unsigned short* __restrict__ value, const unsigned short* __restrict__ off,
    const unsigned short* __restrict__ aw, const float* __restrict__ refp,
    unsigned short* __restrict__ out) {
  __shared__ __align__(16) int4   s_idx[8 * 16 * 8];   // [qi][i][h]
  __shared__ __align__(16) float4 s_w[8 * 16 * 8];
  const int t = threadIdx.x;
  const int bn0 = blockIdx.x * 8;
  const int b = bn0 / NN;

  #pragma unroll
  for (int ss = 0; ss < 4; ++ss) {
    const int s = t + ss * 256;
    const int qi = s >> 7;
    const int j  = s & 127;         // h*16 + l*4 + k
    const int bn = bn0 + qi;
    const int l  = (j >> 2) & 3;
    const int h  = j >> 4;
    const int i  = j & 15;
    const int szl = 128 >> l;
    const int st0l = (l == 0) ? 0 : (l == 1) ? 16384 : (l == 2) ? 20480 : 21504;

    unsigned op = *(const unsigned*)(off + (size_t)bn * 256 + j * 2);
    float ox = bflo(op);
    float oy = bfhi(op);
    float a  = bf2f(aw[(size_t)bn * 128 + j]);
    float rx = refp[(size_t)bn * 8 + l * 2 + 0];
    float ry = refp[(size_t)bn * 8 + l * 2 + 1];

    float x = rx * (float)szl + ox - 0.5f;
    float y = ry * (float)szl + oy - 0.5f;
    float x0f = floorf(x), y0f = floorf(y);
    float wx = x - x0f, wy = y - y0f;
    int x0 = (int)x0f, y0 = (int)y0f;
    int x1 = x0 + 1, y1 = y0 + 1;

    bool vx0 = (x0 >= 0) & (x0 < szl);
    bool vx1 = (x1 >= 0) & (x1 < szl);
    bool vy0 = (y0 >= 0) & (y0 < szl);
    bool vy1 = (y1 >= 0) & (y1 < szl);
    int cx0 = min(max(x0, 0), szl - 1);
    int cx1 = min(max(x1, 0), szl - 1);
    int cy0 = min(max(y0, 0), szl - 1);
    int cy1 = min(max(y1, 0), szl - 1);

    int base = st0l * 256 + h * 32;
    int4 iv;
    iv.x = base + (cy0 * szl + cx0) * 256;
    iv.y = base + (cy0 * szl + cx1) * 256;
    iv.z = base + (cy1 * szl + cx0) * 256;
    iv.w = base + (cy1 * szl + cx1) * 256;
    float4 wv;
    wv.x = (vx0 & vy0) ? a * (1.f - wx) * (1.f - wy) : 0.f;
    wv.y = (vx1 & vy0) ? a * wx * (1.f - wy) : 0.f;
    wv.z = (vx0 & vy1) ? a * (1.f - wx) * wy : 0.f;
    wv.w = (vx1 & vy1) ? a * wx * wy : 0.f;

    int slot = (qi * 16 + i) * 8 + h;
    s_idx[slot] = iv;
    s_w[slot] = wv;
  }
  __syncthreads();

  const int wv_ = t >> 6;
  const int lane = t & 63;
  const int qi = wv_ * 2 + (lane >> 5);
  const int h = (lane >> 2) & 7;
  const int d8 = lane & 3;
  const unsigned short* vcol = value + (size_t)b * PP * 256 + d8 * 8;

  float4 a0a = {0,0,0,0}, a0b = {0,0,0,0}, a1a = {0,0,0,0}, a1b = {0,0,0,0};
  float4 a2a = {0,0,0,0}, a2b = {0,0,0,0}, a3a = {0,0,0,0}, a3b = {0,0,0,0};
  #pragma unroll 4
  for (int i = 0; i < 16; ++i) {
    int slot = (qi * 16 + i) * 8 + h;
    int4 iv = s_idx[slot];
    float4 wv = s_w[slot];
    int4 u0 = *(const int4*)(vcol + iv.x);
    int4 u1 = *(const int4*)(vcol + iv.y);
    int4 u2 = *(const int4*)(vcol + iv.z);
    int4 u3 = *(const int4*)(vcol + iv.w);
    a0a.x += wv.x * bflo(u0.x); a0a.y += wv.x * bfhi(u0.x);
    a0a.z += wv.x * bflo(u0.y); a0a.w += wv.x * bfhi(u0.y);
    a0b.x += wv.x * bflo(u0.z); a0b.y += wv.x * bfhi(u0.z);
    a0b.z += wv.x * bflo(u0.w); a0b.w += wv.x * bfhi(u0.w);
    a1a.x += wv.y * bflo(u1.x); a1a.y += wv.y * bfhi(u1.x);
    a1a.z += wv.y * bflo(u1.y); a1a.w += wv.y * bfhi(u1.y);
    a1b.x += wv.y * bflo(u1.z); a1b.y += wv.y * bfhi(u1.z);
    a1b.z += wv.y * bflo(u1.w); a1b.w += wv.y * bfhi(u1.w);
    a2a.x += wv.z * bflo(u2.x); a2a.y += wv.z * bfhi(u2.x);
    a2a.z += wv.z * bflo(u2.y); a2a.w += wv.z * bfhi(u2.y);
    a2b.x += wv.z * bflo(u2.z); a2b.y += wv.z * bfhi(u2.z);
    a2b.z += wv.z * bflo(u2.w); a2b.w += wv.z * bfhi(u2.w);
    a3a.x += wv.w * bflo(u3.x); a3a.y += wv.w * bfhi(u3.x);
    a3a.z += wv.w * bflo(u3.y); a3a.w += wv.w * bfhi(u3.y);
    a3b.x += wv.w * bflo(u3.z); a3b.y += wv.w * bfhi(u3.z);
    a3b.z += wv.w * bflo(u3.w); a3b.w += wv.w * bfhi(u3.w);
  }
  float4 ra, rb;
  ra.x = (a0a.x + a1a.x) + (a2a.x + a3a.x);
  ra.y = (a0a.y + a1a.y) + (a2a.y + a3a.y);
  ra.z = (a0a.z + a1a.z) + (a2a.z + a3a.z);
  ra.w = (a0a.w + a1a.w) + (a2a.w + a3a.w);
  rb.x = (a0b.x + a1b.x) + (a2b.x + a3b.x);
  rb.y = (a0b.y + a1b.y) + (a2b.y + a3b.y);
  rb.z = (a0b.z + a1b.z) + (a2b.z + a3b.z);
  rb.w = (a0b.w + a1b.w) + (a2b.w + a3b.w);
  int4 ob;
  ob.x = (int)((unsigned)f2bf(ra.x) | ((unsigned)f2bf(ra.y) << 16));
  ob.y = (int)((unsigned)f2bf(ra.z) | ((unsigned)f2bf(ra.w) << 16));
  ob.z = (int)((unsigned)f2bf(rb.x) | ((unsigned)f2bf(rb.y) << 16));
  ob.w = (int)((unsigned)f2bf(rb.z) | ((unsigned)f2bf(rb.w) << 16));
  *(int4*)(out + (size_t)(bn0 + qi) * 256 + h * 32 + d8 * 8) = ob;
}

// ---------------------------------------------------------------------------
// Residual + LayerNorm1 v2: x = LN(attn + 2q), attn bf16 in, x bf16 out.
// One wave per row (proven structure; only load/store dtype changed).
// ---------------------------------------------------------------------------
__global__ __launch_bounds__(256) void resid_ln(
    const unsigned short* __restrict__ A, const float* __restrict__ q,
    const float* __restrict__ g, const float* __restrict__ be,
    unsigned short* __restrict__ X) {
  const int row = blockIdx.x * 4 + (threadIdx.x >> 6);
  const int lane = threadIdx.x & 63;
  const size_t base = (size_t)row * 256 + lane * 4;
  ushort4 au = *(const ushort4*)(A + base);
  float4 qv = *(const float4*)(q + base);
  float4 v;
  v.x = bf2f(au.x) + 2.f * qv.x;
  v.y = bf2f(au.y) + 2.f * qv.y;
  v.z = bf2f(au.z) + 2.f * qv.z;
  v.w = bf2f(au.w) + 2.f * qv.w;
  float s = v.x + v.y + v.z + v.w;
  float s2 = v.x * v.x + v.y * v.y + v.z * v.z + v.w * v.w;
  #pragma unroll
  for (int o = 1; o < 64; o <<= 1) {
    s += __shfl_xor(s, o, 64);
    s2 += __shfl_xor(s2, o, 64);
  }
  float mean = s * (1.f / 256.f);
  float var = s2 * (1.f / 256.f) - mean * mean;
  float rstd = rsqrtf(var + 1e-5f);
  float4 gv = *(const float4*)(g + lane * 4);
  float4 bev = *(const float4*)(be + lane * 4);
  ushort4 o4;
  o4.x = f2bf((v.x - mean) * rstd * gv.x + bev.x);
  o4.y = f2bf((v.y - mean) * rstd * gv.y + bev.y);
  o4.z = f2bf((v.z - mean) * rstd * gv.z + bev.z);
  o4.w = f2bf((v.w - mean) * rstd * gv.w + bev.w);
  *(ushort4*)(X + base) = o4;
}

// ---------------------------------------------------------------------------
// Fused FFN v5b: v5 GEMM structure (proven); X is now bf16 — staging uses
// the proven FSRC=0 ushort4 loop; epilogue residual reads bf16.
// M-tile=32, 8 waves, LDS 80KB, launch_bounds(512,4).
// ---------------------------------------------------------------------------
__global__ __launch_bounds__(512, 4) void ffn_mfma(
    const unsigned short* __restrict__ X, const unsigned short* __restrict__ W1T,
    const float* __restrict__ b1, const unsigned short* __restrict__ W2T,
    const float* __restrict__ b2, const float* __restrict__ g2,
    const float* __restrict__ be2, float* __restrict__ Out) {
  __shared__ __align__(16) char smem[16384 + 65536];
  char* xs = smem;            // 32 x 512 B
  char* hs = smem + 16384;    // 32 x 2048 B
  float* out_s = (float*)(smem + 16384);   // 32 x 260 f32, aliases hs

  const int row0 = blockIdx.x * 32;
  const int t = threadIdx.x;
  const int w = t >> 6, lane = t & 63;
  const int c = lane & 15, kg = lane >> 4;

  // ---- stage X tile (bf16 global -> swizzled LDS), proj-proven ----
  #pragma unroll
  for (int p = 0; p < 2; ++p) {
    int i = t + p * 512;          // 16B chunk id
    int m = i >> 5, c16 = i & 31;
    ushort4 v0 = *(const ushort4*)(X + (size_t)(row0 + m) * 256 + c16 * 8);
    ushort4 v1 = *(const ushort4*)(X + (size_t)(row0 + m) * 256 + c16 * 8 + 4);
    int byte = (m * 512 + c16 * 16) ^ ((m & 7) << 4);
    *(ushort4*)(xs + byte) = v0;
    *(ushort4*)(xs + byte + 8) = v1;
  }
  __syncthreads();

  // ---- GEMM1 in two nf-halves (64 cols each), B double-buffered ----
  #pragma unroll
  for (int half = 0; half < 2; ++half) {
    f32x4 acc1[2][4];
    #pragma unroll
    for (int mf = 0; mf < 2; ++mf)
      #pragma unroll
      for (int nf = 0; nf < 4; ++nf) acc1[mf][nf] = (f32x4){0.f, 0.f, 0.f, 0.f};

    const unsigned short* wp1 = W1T + (size_t)(w * 128 + half * 64) * 256 + kg * 8;
    bf16x8 bcur[4];
    #pragma unroll
    for (int nf = 0; nf < 4; ++nf)
      bcur[nf] = *(const bf16x8*)(wp1 + (size_t)(nf * 16 + c) * 256);
    #pragma unroll
    for (int kc = 0; kc < 8; ++kc) {
      bf16x8 bnext[4];
      #pragma unroll
      for (int nf = 0; nf < 4; ++nf)
        bnext[nf] = (kc < 7)
            ? *(const bf16x8*)(wp1 + (size_t)(nf * 16 + c) * 256 + (kc + 1) * 32)
            : bcur[nf];
      int ab0 = (c * 512 + kc * 64 + kg * 16) ^ ((c & 7) << 4);
      int ab1 = ((16 + c) * 512 + kc * 64 + kg * 16) ^ ((c & 7) << 4);
      bf16x8 a0 = *(const bf16x8*)(xs + ab0);
      bf16x8 a1 = *(const bf16x8*)(xs + ab1);
      #pragma unroll
      for (int nf = 0; nf < 4; ++nf) {
        acc1[0][nf] = __builtin_amdgcn_mfma_f32_16x16x32_bf16(a0, bcur[nf], acc1[0][nf], 0, 0, 0);
        acc1[1][nf] = __builtin_amdgcn_mfma_f32_16x16x32_bf16(a1, bcur[nf], acc1[1][nf], 0, 0, 0);
      }
      #pragma unroll
      for (int nf = 0; nf < 4; ++nf) bcur[nf] = bnext[nf];
    }
    // store this half's hidden: relu(acc1 + b1) -> hs bf16, swizzled
    #pragma unroll
    for (int nf = 0; nf < 4; ++nf) {
      int n = w * 128 + half * 64 + nf * 16 + c;
      float bb = b1[n];
      #pragma unroll
      for (int mf = 0; mf < 2; ++mf) {
        #pragma unroll
        for (int i = 0; i < 4; ++i) {
          int m = mf * 16 + kg * 4 + i;
          float v = fmaxf(acc1[mf][nf][i] + bb, 0.f);
          int byte = (m * 2048 + n * 2) ^ ((m & 7) << 4);
          *(unsigned short*)(hs + byte) = f2bf(v);
        }
      }
    }
  }
  __syncthreads();

  // ---- GEMM2: y[32][256] = hid @ W2, B double-buffered ----
  f32x4 acc2[2][2];
  #pragma unroll
  for (int mf = 0; mf < 2; ++mf)
    #pragma unroll
    for (int nf = 0; nf < 2; ++nf) acc2[mf][nf] = (f32x4){0.f, 0.f, 0.f, 0.f};
  const unsigned short* wp2 = W2T + (size_t)(w * 32) * 1024 + kg * 8;
  bf16x8 b2cur[2];
  #pragma unroll
  for (int nf = 0; nf < 2; ++nf)
    b2cur[nf] = *(const bf16x8*)(wp2 + (size_t)(nf * 16 + c) * 1024);
  #pragma unroll
  for (int kc = 0; kc < 32; ++kc) {
    bf16x8 b2next[2];
    #pragma unroll
    for (int nf = 0; nf < 2; ++nf)
      b2next[nf] = (kc < 31)
          ? *(const bf16x8*)(wp2 + (size_t)(nf * 16 + c) * 1024 + (kc + 1) * 32)
          : b2cur[nf];
    int ab0 = (c * 2048 + kc * 64 + kg * 16) ^ ((c & 7) << 4);
    int ab1 = ((16 + c) * 2048 + kc * 64 + kg * 16) ^ ((c & 7) << 4);
    bf16x8 a0 = *(const bf16x8*)(hs + ab0);
    bf16x8 a1 = *(const bf16x8*)(hs + ab1);
    #pragma unroll
    for (int nf = 0; nf < 2; ++nf) {
      acc2[0][nf] = __builtin_amdgcn_mfma_f32_16x16x32_bf16(a0, b2cur[nf], acc2[0][nf], 0, 0, 0);
      acc2[1][nf] = __builtin_amdgcn_mfma_f32_16x16x32_bf16(a1, b2cur[nf], acc2[1][nf], 0, 0, 0);
    }
    #pragma unroll
    for (int nf = 0; nf < 2; ++nf) b2cur[nf] = b2next[nf];
  }
  __syncthreads();

  // ---- epilogue: + b2 + residual(X bf16) -> out_s ----
  #pragma unroll
  for (int nf = 0; nf < 2; ++nf) {
    int n2 = w * 32 + nf * 16 + c;
    float bb = b2[n2];
    #pragma unroll
    for (int mf = 0; mf < 2; ++mf) {
      #pragma unroll
      for (int i = 0; i < 4; ++i) {
        int m = mf * 16 + kg * 4 + i;
        float xres = bf2f(X[(size_t)(row0 + m) * 256 + n2]);
        out_s[m * 260 + n2] = acc2[mf][nf][i] + bb + xres;
      }
    }
  }
  __syncthreads();

  float4 gv = *(const float4*)(g2 + lane * 4);
  float4 bev = *(const float4*)(be2 + lane * 4);
  #pragma unroll
  for (int rr = 0; rr < 4; ++rr) {
    int r = w * 4 + rr;
    float4 v = *(const float4*)(out_s + r * 260 + lane * 4);
    float s = v.x + v.y + v.z + v.w;
    float s2 = v.x * v.x + v.y * v.y + v.z * v.z + v.w * v.w;
    #pragma unroll
    for (int o = 1; o < 64; o <<= 1) {
      s += __shfl_xor(s, o, 64);
      s2 += __shfl_xor(s2, o, 64);
    }
    float mean = s * (1.f / 256.f);
    float var = s2 * (1.f / 256.f) - mean * mean;
    float rstd = rsqrtf(var + 1e-5f);
    float4 o4;
    o4.x = (v.x - mean) * rstd * gv.x + bev.x;
    o4.y = (v.y - mean) * rstd * gv.y + bev.y;
    o4.z = (v.z - mean) * rstd * gv.z + bev.z;
    o4.w = (v.w - mean) * rstd * gv.w + bev.w;
    *(float4*)(Out + (size_t)(row0 + r) * 256 + lane * 4) = o4;
  }
}

// ---------------------------------------------------------------------------
// Launch
// ---------------------------------------------------------------------------
extern "C" void kernel_launch(void* const* d_in, const int* in_sizes, int n_in,
                              void* d_out, int out_size, void* d_ws, size_t ws_size,
                              hipStream_t stream) {
  const float* q     = (const float*)d_in[0];
  const float* v     = (const float*)d_in[2];
  const float* refp  = (const float*)d_in[3];
  const float* W_off = (const float*)d_in[6];
  const float* b_off = (const float*)d_in[7];
  const float* W_at  = (const float*)d_in[8];
  const float* b_at  = (const float*)d_in[9];
  const float* W_val = (const float*)d_in[10];
  const float* b_val = (const float*)d_in[11];
  const float* W_out = (const float*)d_in[12];
  const float* b_out = (const float*)d_in[13];
  const float* W1    = (const float*)d_in[14];
  const float* b1    = (const float*)d_in[15];
  const float* W2    = (const float*)d_in[16];
  const float* b2    = (const float*)d_in[17];
  const float* g1    = (const float*)d_in[18];
  const float* be1   = (const float*)d_in[19];
  const float* g2    = (const float*)d_in[20];
  const float* be2   = (const float*)d_in[21];
  float* out = (float*)d_out;

  // Workspace layout (same region map as R18; attnb/xb now bf16 in-place)
  float* ws   = (float*)d_ws;
  float* valb = ws;                                   // region A
  unsigned short* valbB = (unsigned short*)valb;      // bf16 [M][256]
  float* offb = valb + (size_t)VROWS * 256;           // region B
  unsigned short* offbB = (unsigned short*)offb;      // bf16 [M][256]
  unsigned short* qb = (unsigned short*)(offb + (size_t)MROWS * 256); // slot
  unsigned short* vb = qb + (size_t)MROWS * 256;      // slot
  unsigned short* msdaB = qb;                         // msda output bf16 [M][256]
  unsigned short* awb = vb + (size_t)MROWS * 256;     // bf16 [M][128]
  unsigned short* WoffT  = awb + (size_t)MROWS * 128; // [256][256]  (= WqT base)
  unsigned short* WattnT = WoffT + 65536;             // [128][256]
  unsigned short* WvalT  = WattnT + 32768;            // [256][256]
  unsigned short* W1T    = WvalT + 65536;             // [1024][256]
  unsigned short* W2T    = W1T + 262144;              // [256][1024]
  unsigned short* WoutT  = W2T + 262144;              // [256][256]
  unsigned short* attnbB = offbB;                     // alias: offbB dead after msda
  unsigned short* xbB    = valbB;                     // alias: valbB dead after msda

  prep_all<<<2944, 256, 0, stream>>>(W_off, W_at, W_val, W_out, W1, W2,
                                     WoffT, WattnT, WvalT, WoutT, W1T, W2T);
  // value projection: fp32 v in, bf16 out
  proj_mfma<256, 3, 1><<<MROWS / 32, 512, 0, stream>>>(v, WvalT, b_val, nullptr, valbB);
  // fused offset + attention-weight projection (one q staging)
  proj_qfused<<<MROWS / 32, 512, 0, stream>>>(q, WoffT, b_off, b_at, offbB, awb);
  // deformable bilinear sampling v7
  msda_sample<<<MROWS / 8, 256, 0, stream>>>(valbB, offbB, awb, refp, msdaB);
  // out-projection: bf16 msda in -> bf16 attn (EPI3, into dead offb region)
  proj_mfma<256, 3, 0><<<MROWS / 32, 512, 0, stream>>>(msdaB, WoutT, b_out, nullptr, attnbB);
  // residual + LayerNorm1 (bf16 attn in, bf16 x out)
  resid_ln<<<MROWS / 4, 256, 0, stream>>>(attnbB, q, g1, be1, xbB);
  // fused FFN v5b + residual + LayerNorm2 (bf16 x in)
  ffn_mfma<<<MROWS / 32, 512, 0, stream>>>(xbB, W1T, b1, W2T, b2, g2, be2, out);
}

// Round 20
// 397.950 us; speedup vs baseline: 1.2095x; 1.0241x over previous
//
#include <hip/hip_runtime.h>
#include <hip/hip_bf16.h>
#include <math.h>

// Problem constants (fixed by the reference file)
#define BB 2
#define NN 21760
#define CC 256
#define HH 8
#define PP 21760
#define MROWS (BB * NN)   // 43520 query rows
#define VROWS (BB * PP)   // 43520 value rows

typedef __attribute__((ext_vector_type(8))) short bf16x8;
typedef __attribute__((ext_vector_type(4))) float f32x4;

__device__ __forceinline__ unsigned short f2bf(float f) {
  unsigned u = __float_as_uint(f);
  u += 0x7fff + ((u >> 16) & 1);   // RNE
  return (unsigned short)(u >> 16);
}
__device__ __forceinline__ float bf2f(unsigned short s) {
  return __uint_as_float(((unsigned)s) << 16);
}
// packed-u32 bf16 pair -> two floats (lo = bits[15:0], hi = bits[31:16])
__device__ __forceinline__ float bflo(unsigned u) { return __uint_as_float(u << 16); }
__device__ __forceinline__ float bfhi(unsigned u) { return __uint_as_float(u & 0xffff0000u); }
// fp8 encode (one value -> byte 0 of pack) / decode (byte sel of u32)
__device__ __forceinline__ unsigned char f2fp8(float f) {
  int p = __builtin_amdgcn_cvt_pk_fp8_f32(f, f, 0, false);
  return (unsigned char)(p & 0xff);
}

// ---------------------------------------------------------------------------
// Weights -> transposed bf16 [N][K].  R7-proven 6-weight version.
// ---------------------------------------------------------------------------
__global__ __launch_bounds__(256) void prep_all(
    const float* __restrict__ W_off, const float* __restrict__ W_at,
    const float* __restrict__ W_val, const float* __restrict__ W_out,
    const float* __restrict__ W1, const float* __restrict__ W2,
    unsigned short* __restrict__ WoffT, unsigned short* __restrict__ WattnT,
    unsigned short* __restrict__ WvalT, unsigned short* __restrict__ WoutT,
    unsigned short* __restrict__ W1T, unsigned short* __restrict__ W2T) {
  int i = blockIdx.x * 256 + threadIdx.x;
  if (i < 65536) {                    // WoffT[256][256]
    WoffT[i] = f2bf(W_off[(size_t)(i & 255) * 256 + (i >> 8)]);
  } else if (i < 98304) {             // WattnT[128][256]
    int j = i - 65536;
    WattnT[j] = f2bf(W_at[(size_t)(j & 255) * 128 + (j >> 8)]);
  } else if (i < 163840) {            // WvalT[256][256]
    int j = i - 98304;
    WvalT[j] = f2bf(W_val[(size_t)(j & 255) * 256 + (j >> 8)]);
  } else if (i < 229376) {            // WoutT[256][256]
    int j = i - 163840;
    WoutT[j] = f2bf(W_out[(size_t)(j & 255) * 256 + (j >> 8)]);
  } else if (i < 491520) {            // W1T[1024][256]
    int j = i - 229376;
    W1T[j] = f2bf(W1[(size_t)(j & 255) * 1024 + (j >> 8)]);
  } else if (i < 753664) {            // W2T[256][1024]
    int j = i - 491520;
    W2T[j] = f2bf(W2[(size_t)(j & 1023) * 256 + (j >> 10)]);
  }
}

// ---------------------------------------------------------------------------
// Projection GEMM via bf16 MFMA: C[M][NC] = A[M][256] @ BT^T + bias
// 8 waves, 512 threads.  M-tile 32.
// EPI: 0 = +bias -> fp32;  3 = +bias -> bf16;  4 = +bias -> fp8 (outB cast)
// FSRC: 0 = A bf16;  1 = A fp32 (staged with the ffn-proven convert loop)
// ---------------------------------------------------------------------------
template <int NC, int EPI, int FSRC>
__global__ __launch_bounds__(512, 4) void proj_mfma(
    const void* __restrict__ Ain, const unsigned short* __restrict__ BT,
    const float* __restrict__ bias,
    float* __restrict__ outF, unsigned short* __restrict__ outB) {
  constexpr int MTILE = 32;
  __shared__ __align__(16) char xs[MTILE * 512];

  const int row0 = blockIdx.x * MTILE;
  const int t = threadIdx.x;
  const int w = t >> 6, lane = t & 63;
  const int c = lane & 15, kg = lane >> 4;
  const int nbase = w * 32;

  // ---- stage A tile -> swizzled bf16 LDS ----
  if (FSRC) {
    const float* A = (const float*)Ain;
    for (int i = t; i < MTILE * 128; i += 512) {
      int m = i >> 7;
      int np = i & 127;
      float2 xv = *(const float2*)(A + (size_t)(row0 + m) * 256 + np * 2);
      unsigned pk = (unsigned)f2bf(xv.x) | ((unsigned)f2bf(xv.y) << 16);
      int byte = (m * 512 + np * 4) ^ ((m & 7) << 4);
      *(unsigned*)(xs + byte) = pk;
    }
  } else {
    const unsigned short* A = (const unsigned short*)Ain;
    #pragma unroll
    for (int p = 0; p < MTILE / 16; ++p) {
      int i = t + p * 512;          // 16B chunk id
      int m = i >> 5, c16 = i & 31;
      ushort4 v0 = *(const ushort4*)(A + (size_t)(row0 + m) * 256 + c16 * 8);
      ushort4 v1 = *(const ushort4*)(A + (size_t)(row0 + m) * 256 + c16 * 8 + 4);
      int byte = (m * 512 + c16 * 16) ^ ((m & 7) << 4);
      *(ushort4*)(xs + byte) = v0;
      *(ushort4*)(xs + byte + 8) = v1;
    }
  }
  __syncthreads();

  // ---- GEMM ----
  f32x4 acc[2][2];
  #pragma unroll
  for (int mf = 0; mf < 2; ++mf)
    #pragma unroll
    for (int nf = 0; nf < 2; ++nf) acc[mf][nf] = (f32x4){0.f, 0.f, 0.f, 0.f};
  #pragma unroll
  for (int kc = 0; kc < 8; ++kc) {
    int ab0 = (c * 512 + kc * 64 + kg * 16) ^ ((c & 7) << 4);
    int ab1 = ((16 + c) * 512 + kc * 64 + kg * 16) ^ ((c & 7) << 4);
    bf16x8 a0 = *(const bf16x8*)(xs + ab0);
    bf16x8 a1 = *(const bf16x8*)(xs + ab1);
    #pragma unroll
    for (int nf = 0; nf < 2; ++nf) {
      bf16x8 b = *(const bf16x8*)(BT + (size_t)(nbase + nf * 16 + c) * 256 + kc * 32 + kg * 8);
      acc[0][nf] = __builtin_amdgcn_mfma_f32_16x16x32_bf16(a0, b, acc[0][nf], 0, 0, 0);
      acc[1][nf] = __builtin_amdgcn_mfma_f32_16x16x32_bf16(a1, b, acc[1][nf], 0, 0, 0);
    }
  }

  // ---- epilogue ----
  if (EPI == 0) {
    #pragma unroll
    for (int nf = 0; nf < 2; ++nf) {
      int n = nbase + nf * 16 + c;
      float bb = bias[n];
      #pragma unroll
      for (int mf = 0; mf < 2; ++mf)
        #pragma unroll
        for (int i = 0; i < 4; ++i) {
          int m = mf * 16 + kg * 4 + i;
          outF[(size_t)(row0 + m) * NC + n] = acc[mf][nf][i] + bb;
        }
    }
  } else if (EPI == 3) {
    #pragma unroll
    for (int nf = 0; nf < 2; ++nf) {
      int n = nbase + nf * 16 + c;
      float bb = bias[n];
      #pragma unroll
      for (int mf = 0; mf < 2; ++mf)
        #pragma unroll
        for (int i = 0; i < 4; ++i) {
          int m = mf * 16 + kg * 4 + i;
          outB[(size_t)(row0 + m) * NC + n] = f2bf(acc[mf][nf][i] + bb);
        }
    }
  } else {  // EPI == 4: fp8 output
    unsigned char* o8 = (unsigned char*)outB;
    #pragma unroll
    for (int nf = 0; nf < 2; ++nf) {
      int n = nbase + nf * 16 + c;
      float bb = bias[n];
      #pragma unroll
      for (int mf = 0; mf < 2; ++mf)
        #pragma unroll
        for (int i = 0; i < 4; ++i) {
          int m = mf * 16 + kg * 4 + i;
          o8[(size_t)(row0 + m) * NC + n] = f2fp8(acc[mf][nf][i] + bb);
        }
    }
  }
}

// ---------------------------------------------------------------------------
// Fused q-projection (R18, proven): C[M][384] = q @ [W_off | W_attn]^T.
// ---------------------------------------------------------------------------
__global__ __launch_bounds__(512, 4) void proj_qfused(
    const float* __restrict__ Q, const unsigned short* __restrict__ WqT,
    const float* __restrict__ b_off, const float* __restrict__ b_at,
    unsigned short* __restrict__ offB, unsigned short* __restrict__ awB) {
  __shared__ __align__(16) char xs[32 * 512];

  const int row0 = blockIdx.x * 32;
  const int t = threadIdx.x;
  const int w = t >> 6, lane = t & 63;
  const int c = lane & 15, kg = lane >> 4;
  const int nbase = w * 48;

  for (int i = t; i < 4096; i += 512) {
    int m = i >> 7;
    int np = i & 127;
    float2 xv = *(const float2*)(Q + (size_t)(row0 + m) * 256 + np * 2);
    unsigned pk = (unsigned)f2bf(xv.x) | ((unsigned)f2bf(xv.y) << 16);
    int byte = (m * 512 + np * 4) ^ ((m & 7) << 4);
    *(unsigned*)(xs + byte) = pk;
  }
  __syncthreads();

  f32x4 acc[2][3];
  #pragma unroll
  for (int mf = 0; mf < 2; ++mf)
    #pragma unroll
    for (int nf = 0; nf < 3; ++nf) acc[mf][nf] = (f32x4){0.f, 0.f, 0.f, 0.f};
  #pragma unroll
  for (int kc = 0; kc < 8; ++kc) {
    int ab0 = (c * 512 + kc * 64 + kg * 16) ^ ((c & 7) << 4);
    int ab1 = ((16 + c) * 512 + kc * 64 + kg * 16) ^ ((c & 7) << 4);
    bf16x8 a0 = *(const bf16x8*)(xs + ab0);
    bf16x8 a1 = *(const bf16x8*)(xs + ab1);
    #pragma unroll
    for (int nf = 0; nf < 3; ++nf) {
      bf16x8 b = *(const bf16x8*)(WqT + (size_t)(nbase + nf * 16 + c) * 256 + kc * 32 + kg * 8);
      acc[0][nf] = __builtin_amdgcn_mfma_f32_16x16x32_bf16(a0, b, acc[0][nf], 0, 0, 0);
      acc[1][nf] = __builtin_amdgcn_mfma_f32_16x16x32_bf16(a1, b, acc[1][nf], 0, 0, 0);
    }
  }

  #pragma unroll
  for (int nf = 0; nf < 3; ++nf) {
    int n = nbase + nf * 16 + c;
    if (nbase + nf * 16 < 256) {
      float bb = b_off[n];
      #pragma unroll
      for (int mf = 0; mf < 2; ++mf)
        #pragma unroll
        for (int i = 0; i < 4; ++i) {
          int m = mf * 16 + kg * 4 + i;
          offB[(size_t)(row0 + m) * 256 + n] = f2bf(acc[mf][nf][i] + bb);
        }
    } else {
      int na = n - 256;
      float bb = b_at[na];
      #pragma unroll
      for (int mf = 0; mf < 2; ++mf)
        #pragma unroll
        for (int i = 0; i < 4; ++i) {
          float vv = acc[mf][nf][i] + bb;
          float mx = vv;
          mx = fmaxf(mx, __shfl_xor(mx, 1, 64));
          mx = fmaxf(mx, __shfl_xor(mx, 2, 64));
          mx = fmaxf(mx, __shfl_xor(mx, 4, 64));
          mx = fmaxf(mx, __shfl_xor(mx, 8, 64));
          float e = expf(vv - mx);
          float s = e;
          s += __shfl_xor(s, 1, 64);
          s += __shfl_xor(s, 2, 64);
          s += __shfl_xor(s, 4, 64);
          s += __shfl_xor(s, 8, 64);
          int m = mf * 16 + kg * 4 + i;
          awB[(size_t)(row0 + m) * 128 + na] = f2bf(e / s);
        }
    }
  }
}

// ---------------------------------------------------------------------------
// Deformable sampling v8: v7 structure; value is fp8 (8B int2 gathers,
// HW cvt decode).  Half the gather bytes of v7.
// ---------------------------------------------------------------------------
__global__ __launch_bounds__(256) void msda_sample(
    const unsigned char* __restrict__ value, const unsigned short* __restrict__ off,
    const unsigned short* __restrict__ aw, const float* __restrict__ refp,
    unsigned short* __restrict__ out) {
  __shared__ __align__(16) int4   s_idx[8 * 16 * 8];   // [qi][i][h]
  __shared__ __align__(16) float4 s_w[8 * 16 * 8];
  const int t = threadIdx.x;
  const int bn0 = blockIdx.x * 8;
  const int b = bn0 / NN;

  #pragma unroll
  for (int ss = 0; ss < 4; ++ss) {
    const int s = t + ss * 256;
    const int qi = s >> 7;
    const int j  = s & 127;         // h*16 + l*4 + k
    const int bn = bn0 + qi;
    const int l  = (j >> 2) & 3;
    const int h  = j >> 4;
    const int i  = j & 15;
    const int szl = 128 >> l;
    const int st0l = (l == 0) ? 0 : (l == 1) ? 16384 : (l == 2) ? 20480 : 21504;

    unsigned op = *(const unsigned*)(off + (size_t)bn * 256 + j * 2);
    float ox = bflo(op);
    float oy = bfhi(op);
    float a  = bf2f(aw[(size_t)bn * 128 + j]);
    float rx = refp[(size_t)bn * 8 + l * 2 + 0];
    float ry = refp[(size_t)bn * 8 + l * 2 + 1];

    float x = rx * (float)szl + ox - 0.5f;
    float y = ry * (float)szl + oy - 0.5f;
    float x0f = floorf(x), y0f = floorf(y);
    float wx = x - x0f, wy = y - y0f;
    int x0 = (int)x0f, y0 = (int)y0f;
    int x1 = x0 + 1, y1 = y0 + 1;

    bool vx0 = (x0 >= 0) & (x0 < szl);
    bool vx1 = (x1 >= 0) & (x1 < szl);
    bool vy0 = (y0 >= 0) & (y0 < szl);
    bool vy1 = (y1 >= 0) & (y1 < szl);
    int cx0 = min(max(x0, 0), szl - 1);
    int cx1 = min(max(x1, 0), szl - 1);
    int cy0 = min(max(y0, 0), szl - 1);
    int cy1 = min(max(y1, 0), szl - 1);

    int base = st0l * 256 + h * 32;
    int4 iv;
    iv.x = base + (cy0 * szl + cx0) * 256;
    iv.y = base + (cy0 * szl + cx1) * 256;
    iv.z = base + (cy1 * szl + cx0) * 256;
    iv.w = base + (cy1 * szl + cx1) * 256;
    float4 wv;
    wv.x = (vx0 & vy0) ? a * (1.f - wx) * (1.f - wy) : 0.f;
    wv.y = (vx1 & vy0) ? a * wx * (1.f - wy) : 0.f;
    wv.z = (vx0 & vy1) ? a * (1.f - wx) * wy : 0.f;
    wv.w = (vx1 & vy1) ? a * wx * wy : 0.f;

    int slot = (qi * 16 + i) * 8 + h;
    s_idx[slot] = iv;
    s_w[slot] = wv;
  }
  __syncthreads();

  const int wv_ = t >> 6;
  const int lane = t & 63;
  const int qi = wv_ * 2 + (lane >> 5);
  const int h = (lane >> 2) & 7;
  const int d8 = lane & 3;
  const unsigned char* vcol = value + (size_t)b * PP * 256 + d8 * 8;

  float4 a0a = {0,0,0,0}, a0b = {0,0,0,0}, a1a = {0,0,0,0}, a1b = {0,0,0,0};
  float4 a2a = {0,0,0,0}, a2b = {0,0,0,0}, a3a = {0,0,0,0}, a3b = {0,0,0,0};
  #pragma unroll 4
  for (int i = 0; i < 16; ++i) {
    int slot = (qi * 16 + i) * 8 + h;
    int4 iv = s_idx[slot];
    float4 wv = s_w[slot];
    int2 u0 = *(const int2*)(vcol + iv.x);   // 8 fp8
    int2 u1 = *(const int2*)(vcol + iv.y);
    int2 u2 = *(const int2*)(vcol + iv.z);
    int2 u3 = *(const int2*)(vcol + iv.w);
    a0a.x += wv.x * __builtin_amdgcn_cvt_f32_fp8((unsigned)u0.x, 0);
    a0a.y += wv.x * __builtin_amdgcn_cvt_f32_fp8((unsigned)u0.x, 1);
    a0a.z += wv.x * __builtin_amdgcn_cvt_f32_fp8((unsigned)u0.x, 2);
    a0a.w += wv.x * __builtin_amdgcn_cvt_f32_fp8((unsigned)u0.x, 3);
    a0b.x += wv.x * __builtin_amdgcn_cvt_f32_fp8((unsigned)u0.y, 0);
    a0b.y += wv.x * __builtin_amdgcn_cvt_f32_fp8((unsigned)u0.y, 1);
    a0b.z += wv.x * __builtin_amdgcn_cvt_f32_fp8((unsigned)u0.y, 2);
    a0b.w += wv.x * __builtin_amdgcn_cvt_f32_fp8((unsigned)u0.y, 3);
    a1a.x += wv.y * __builtin_amdgcn_cvt_f32_fp8((unsigned)u1.x, 0);
    a1a.y += wv.y * __builtin_amdgcn_cvt_f32_fp8((unsigned)u1.x, 1);
    a1a.z += wv.y * __builtin_amdgcn_cvt_f32_fp8((unsigned)u1.x, 2);
    a1a.w += wv.y * __builtin_amdgcn_cvt_f32_fp8((unsigned)u1.x, 3);
    a1b.x += wv.y * __builtin_amdgcn_cvt_f32_fp8((unsigned)u1.y, 0);
    a1b.y += wv.y * __builtin_amdgcn_cvt_f32_fp8((unsigned)u1.y, 1);
    a1b.z += wv.y * __builtin_amdgcn_cvt_f32_fp8((unsigned)u1.y, 2);
    a1b.w += wv.y * __builtin_amdgcn_cvt_f32_fp8((unsigned)u1.y, 3);
    a2a.x += wv.z * __builtin_amdgcn_cvt_f32_fp8((unsigned)u2.x, 0);
    a2a.y += wv.z * __builtin_amdgcn_cvt_f32_fp8((unsigned)u2.x, 1);
    a2a.z += wv.z * __builtin_amdgcn_cvt_f32_fp8((unsigned)u2.x, 2);
    a2a.w += wv.z * __builtin_amdgcn_cvt_f32_fp8((unsigned)u2.x, 3);
    a2b.x += wv.z * __builtin_amdgcn_cvt_f32_fp8((unsigned)u2.y, 0);
    a2b.y += wv.z * __builtin_amdgcn_cvt_f32_fp8((unsigned)u2.y, 1);
    a2b.z += wv.z * __builtin_amdgcn_cvt_f32_fp8((unsigned)u2.y, 2);
    a2b.w += wv.z * __builtin_amdgcn_cvt_f32_fp8((unsigned)u2.y, 3);
    a3a.x += wv.w * __builtin_amdgcn_cvt_f32_fp8((unsigned)u3.x, 0);
    a3a.y += wv.w * __builtin_amdgcn_cvt_f32_fp8((unsigned)u3.x, 1);
    a3a.z += wv.w * __builtin_amdgcn_cvt_f32_fp8((unsigned)u3.x, 2);
    a3a.w += wv.w * __builtin_amdgcn_cvt_f32_fp8((unsigned)u3.x, 3);
    a3b.x += wv.w * __builtin_amdgcn_cvt_f32_fp8((unsigned)u3.y, 0);
    a3b.y += wv.w * __builtin_amdgcn_cvt_f32_fp8((unsigned)u3.y, 1);
    a3b.z += wv.w * __builtin_amdgcn_cvt_f32_fp8((unsigned)u3.y, 2);
    a3b.w += wv.w * __builtin_amdgcn_cvt_f32_fp8((unsigned)u3.y, 3);
  }
  float4 ra, rb;
  ra.x = (a0a.x + a1a.x) + (a2a.x + a3a.x);
  ra.y = (a0a.y + a1a.y) + (a2a.y + a3a.y);
  ra.z = (a0a.z + a1a.z) + (a2a.z + a3a.z);
  ra.w = (a0a.w + a1a.w) + (a2a.w + a3a.w);
  rb.x = (a0b.x + a1b.x) + (a2b.x + a3b.x);
  rb.y = (a0b.y + a1b.y) + (a2b.y + a3b.y);
  rb.z = (a0b.z + a1b.z) + (a2b.z + a3b.z);
  rb.w = (a0b.w + a1b.w) + (a2b.w + a3b.w);
  int4 ob;
  ob.x = (int)((unsigned)f2bf(ra.x) | ((unsigned)f2bf(ra.y) << 16));
  ob.y = (int)((unsigned)f2bf(ra.z) | ((unsigned)f2bf(ra.w) << 16));
  ob.z = (int)((unsigned)f2bf(rb.x) | ((unsigned)f2bf(rb.y) << 16));
  ob.w = (int)((unsigned)f2bf(rb.z) | ((unsigned)f2bf(rb.w) << 16));
  *(int4*)(out + (size_t)(bn0 + qi) * 256 + h * 32 + d8 * 8) = ob;
}

// ---------------------------------------------------------------------------
// Residual + LayerNorm1 v2 (proven): attn bf16 in, x bf16 out.
// ---------------------------------------------------------------------------
__global__ __launch_bounds__(256) void resid_ln(
    const unsigned short* __restrict__ A, const float* __restrict__ q,
    const float* __restrict__ g, const float* __restrict__ be,
    unsigned short* __restrict__ X) {
  const int row = blockIdx.x * 4 + (threadIdx.x >> 6);
  const int lane = threadIdx.x & 63;
  const size_t base = (size_t)row * 256 + lane * 4;
  ushort4 au = *(const ushort4*)(A + base);
  float4 qv = *(const float4*)(q + base);
  float4 v;
  v.x = bf2f(au.x) + 2.f * qv.x;
  v.y = bf2f(au.y) + 2.f * qv.y;
  v.z = bf2f(au.z) + 2.f * qv.z;
  v.w = bf2f(au.w) + 2.f * qv.w;
  float s = v.x + v.y + v.z + v.w;
  float s2 = v.x * v.x + v.y * v.y + v.z * v.z + v.w * v.w;
  #pragma unroll
  for (int o = 1; o < 64; o <<= 1) {
    s += __shfl_xor(s, o, 64);
    s2 += __shfl_xor(s2, o, 64);
  }
  float mean = s * (1.f / 256.f);
  float var = s2 * (1.f / 256.f) - mean * mean;
  float rstd = rsqrtf(var + 1e-5f);
  float4 gv = *(const float4*)(g + lane * 4);
  float4 bev = *(const float4*)(be + lane * 4);
  ushort4 o4;
  o4.x = f2bf((v.x - mean) * rstd * gv.x + bev.x);
  o4.y = f2bf((v.y - mean) * rstd * gv.y + bev.y);
  o4.z = f2bf((v.z - mean) * rstd * gv.z + bev.z);
  o4.w = f2bf((v.w - mean) * rstd * gv.w + bev.w);
  *(ushort4*)(X + base) = o4;
}

// ---------------------------------------------------------------------------
// Fused FFN v5b (proven): bf16 X; M-tile=32, 8 waves, LDS 80KB.
// ---------------------------------------------------------------------------
__global__ __launch_bounds__(512, 4) void ffn_mfma(
    const unsigned short* __restrict__ X, const unsigned short* __restrict__ W1T,
    const float* __restrict__ b1, const unsigned short* __restrict__ W2T,
    const float* __restrict__ b2, const float* __restrict__ g2,
    const float* __restrict__ be2, float* __restrict__ Out) {
  __shared__ __align__(16) char smem[16384 + 65536];
  char* xs = smem;            // 32 x 512 B
  char* hs = smem + 16384;    // 32 x 2048 B
  float* out_s = (float*)(smem + 16384);   // 32 x 260 f32, aliases hs

  const int row0 = blockIdx.x * 32;
  const int t = threadIdx.x;
  const int w = t >> 6, lane = t & 63;
  const int c = lane & 15, kg = lane >> 4;

  // ---- stage X tile (bf16 global -> swizzled LDS) ----
  #pragma unroll
  for (int p = 0; p < 2; ++p) {
    int i = t + p * 512;          // 16B chunk id
    int m = i >> 5, c16 = i & 31;
    ushort4 v0 = *(const ushort4*)(X + (size_t)(row0 + m) * 256 + c16 * 8);
    ushort4 v1 = *(const ushort4*)(X + (size_t)(row0 + m) * 256 + c16 * 8 + 4);
    int byte = (m * 512 + c16 * 16) ^ ((m & 7) << 4);
    *(ushort4*)(xs + byte) = v0;
    *(ushort4*)(xs + byte + 8) = v1;
  }
  __syncthreads();

  // ---- GEMM1 in two nf-halves (64 cols each), B double-buffered ----
  #pragma unroll
  for (int half = 0; half < 2; ++half) {
    f32x4 acc1[2][4];
    #pragma unroll
    for (int mf = 0; mf < 2; ++mf)
      #pragma unroll
      for (int nf = 0; nf < 4; ++nf) acc1[mf][nf] = (f32x4){0.f, 0.f, 0.f, 0.f};

    const unsigned short* wp1 = W1T + (size_t)(w * 128 + half * 64) * 256 + kg * 8;
    bf16x8 bcur[4];
    #pragma unroll
    for (int nf = 0; nf < 4; ++nf)
      bcur[nf] = *(const bf16x8*)(wp1 + (size_t)(nf * 16 + c) * 256);
    #pragma unroll
    for (int kc = 0; kc < 8; ++kc) {
      bf16x8 bnext[4];
      #pragma unroll
      for (int nf = 0; nf < 4; ++nf)
        bnext[nf] = (kc < 7)
            ? *(const bf16x8*)(wp1 + (size_t)(nf * 16 + c) * 256 + (kc + 1) * 32)
            : bcur[nf];
      int ab0 = (c * 512 + kc * 64 + kg * 16) ^ ((c & 7) << 4);
      int ab1 = ((16 + c) * 512 + kc * 64 + kg * 16) ^ ((c & 7) << 4);
      bf16x8 a0 = *(const bf16x8*)(xs + ab0);
      bf16x8 a1 = *(const bf16x8*)(xs + ab1);
      #pragma unroll
      for (int nf = 0; nf < 4; ++nf) {
        acc1[0][nf] = __builtin_amdgcn_mfma_f32_16x16x32_bf16(a0, bcur[nf], acc1[0][nf], 0, 0, 0);
        acc1[1][nf] = __builtin_amdgcn_mfma_f32_16x16x32_bf16(a1, bcur[nf], acc1[1][nf], 0, 0, 0);
      }
      #pragma unroll
      for (int nf = 0; nf < 4; ++nf) bcur[nf] = bnext[nf];
    }
    // store this half's hidden: relu(acc1 + b1) -> hs bf16, swizzled
    #pragma unroll
    for (int nf = 0; nf < 4; ++nf) {
      int n = w * 128 + half * 64 + nf * 16 + c;
      float bb = b1[n];
      #pragma unroll
      for (int mf = 0; mf < 2; ++mf) {
        #pragma unroll
        for (int i = 0; i < 4; ++i) {
          int m = mf * 16 + kg * 4 + i;
          float v = fmaxf(acc1[mf][nf][i] + bb, 0.f);
          int byte = (m * 2048 + n * 2) ^ ((m & 7) << 4);
          *(unsigned short*)(hs + byte) = f2bf(v);
        }
      }
    }
  }
  __syncthreads();

  // ---- GEMM2: y[32][256] = hid @ W2, B double-buffered ----
  f32x4 acc2[2][2];
  #pragma unroll
  for (int mf = 0; mf < 2; ++mf)
    #pragma unroll
    for (int nf = 0; nf < 2; ++nf) acc2[mf][nf] = (f32x4){0.f, 0.f, 0.f, 0.f};
  const unsigned short* wp2 = W2T + (size_t)(w * 32) * 1024 + kg * 8;
  bf16x8 b2cur[2];
  #pragma unroll
  for (int nf = 0; nf < 2; ++nf)
    b2cur[nf] = *(const bf16x8*)(wp2 + (size_t)(nf * 16 + c) * 1024);
  #pragma unroll
  for (int kc = 0; kc < 32; ++kc) {
    bf16x8 b2next[2];
    #pragma unroll
    for (int nf = 0; nf < 2; ++nf)
      b2next[nf] = (kc < 31)
          ? *(const bf16x8*)(wp2 + (size_t)(nf * 16 + c) * 1024 + (kc + 1) * 32)
          : b2cur[nf];
    int ab0 = (c * 2048 + kc * 64 + kg * 16) ^ ((c & 7) << 4);
    int ab1 = ((16 + c) * 2048 + kc * 64 + kg * 16) ^ ((c & 7) << 4);
    bf16x8 a0 = *(const bf16x8*)(hs + ab0);
    bf16x8 a1 = *(const bf16x8*)(hs + ab1);
    #pragma unroll
    for (int nf = 0; nf < 2; ++nf) {
      acc2[0][nf] = __builtin_amdgcn_mfma_f32_16x16x32_bf16(a0, b2cur[nf], acc2[0][nf], 0, 0, 0);
      acc2[1][nf] = __builtin_amdgcn_mfma_f32_16x16x32_bf16(a1, b2cur[nf], acc2[1][nf], 0, 0, 0);
    }
    #pragma unroll
    for (int nf = 0; nf < 2; ++nf) b2cur[nf] = b2next[nf];
  }
  __syncthreads();

  // ---- epilogue: + b2 + residual(X bf16) -> out_s ----
  #pragma unroll
  for (int nf = 0; nf < 2; ++nf) {
    int n2 = w * 32 + nf * 16 + c;
    float bb = b2[n2];
    #pragma unroll
    for (int mf = 0; mf < 2; ++mf) {
      #pragma unroll
      for (int i = 0; i < 4; ++i) {
        int m = mf * 16 + kg * 4 + i;
        float xres = bf2f(X[(size_t)(row0 + m) * 256 + n2]);
        out_s[m * 260 + n2] = acc2[mf][nf][i] + bb + xres;
      }
    }
  }
  __syncthreads();

  float4 gv = *(const float4*)(g2 + lane * 4);
  float4 bev = *(const float4*)(be2 + lane * 4);
  #pragma unroll
  for (int rr = 0; rr < 4; ++rr) {
    int r = w * 4 + rr;
    float4 v = *(const float4*)(out_s + r * 260 + lane * 4);
    float s = v.x + v.y + v.z + v.w;
    float s2 = v.x * v.x + v.y * v.y + v.z * v.z + v.w * v.w;
    #pragma unroll
    for (int o = 1; o < 64; o <<= 1) {
      s += __shfl_xor(s, o, 64);
      s2 += __shfl_xor(s2, o, 64);
    }
    float mean = s * (1.f / 256.f);
    float var = s2 * (1.f / 256.f) - mean * mean;
    float rstd = rsqrtf(var + 1e-5f);
    float4 o4;
    o4.x = (v.x - mean) * rstd * gv.x + bev.x;
    o4.y = (v.y - mean) * rstd * gv.y + bev.y;
    o4.z = (v.z - mean) * rstd * gv.z + bev.z;
    o4.w = (v.w - mean) * rstd * gv.w + bev.w;
    *(float4*)(Out + (size_t)(row0 + r) * 256 + lane * 4) = o4;
  }
}

// ---------------------------------------------------------------------------
// Launch
// ---------------------------------------------------------------------------
extern "C" void kernel_launch(void* const* d_in, const int* in_sizes, int n_in,
                              void* d_out, int out_size, void* d_ws, size_t ws_size,
                              hipStream_t stream) {
  const float* q     = (const float*)d_in[0];
  const float* v     = (const float*)d_in[2];
  const float* refp  = (const float*)d_in[3];
  const float* W_off = (const float*)d_in[6];
  const float* b_off = (const float*)d_in[7];
  const float* W_at  = (const float*)d_in[8];
  const float* b_at  = (const float*)d_in[9];
  const float* W_val = (const float*)d_in[10];
  const float* b_val = (const float*)d_in[11];
  const float* W_out = (const float*)d_in[12];
  const float* b_out = (const float*)d_in[13];
  const float* W1    = (const float*)d_in[14];
  const float* b1    = (const float*)d_in[15];
  const float* W2    = (const float*)d_in[16];
  const float* b2    = (const float*)d_in[17];
  const float* g1    = (const float*)d_in[18];
  const float* be1   = (const float*)d_in[19];
  const float* g2    = (const float*)d_in[20];
  const float* be2   = (const float*)d_in[21];
  float* out = (float*)d_out;

  // Workspace layout (same region map as R19; value now fp8 in region A)
  float* ws   = (float*)d_ws;
  float* valb = ws;                                   // region A
  unsigned char*  valbF8 = (unsigned char*)valb;      // fp8 [M][256]
  unsigned short* xbB    = (unsigned short*)valb;     // bf16 [M][256] (after msda)
  float* offb = valb + (size_t)VROWS * 256;           // region B
  unsigned short* offbB = (unsigned short*)offb;      // bf16 [M][256]
  unsigned short* qb = (unsigned short*)(offb + (size_t)MROWS * 256); // slot
  unsigned short* vb = qb + (size_t)MROWS * 256;      // slot
  unsigned short* msdaB = qb;                         // msda output bf16 [M][256]
  unsigned short* awb = vb + (size_t)MROWS * 256;     // bf16 [M][128]
  unsigned short* WoffT  = awb + (size_t)MROWS * 128; // [256][256]  (= WqT base)
  unsigned short* WattnT = WoffT + 65536;             // [128][256]
  unsigned short* WvalT  = WattnT + 32768;            // [256][256]
  unsigned short* W1T    = WvalT + 65536;             // [1024][256]
  unsigned short* W2T    = W1T + 262144;              // [256][1024]
  unsigned short* WoutT  = W2T + 262144;              // [256][256]
  unsigned short* attnbB = offbB;                     // alias: offbB dead after msda

  prep_all<<<2944, 256, 0, stream>>>(W_off, W_at, W_val, W_out, W1, W2,
                                     WoffT, WattnT, WvalT, WoutT, W1T, W2T);
  // value projection: fp32 v in, fp8 out (EPI=4)
  proj_mfma<256, 4, 1><<<MROWS / 32, 512, 0, stream>>>(
      v, WvalT, b_val, nullptr, (unsigned short*)valbF8);
  // fused offset + attention-weight projection (one q staging)
  proj_qfused<<<MROWS / 32, 512, 0, stream>>>(q, WoffT, b_off, b_at, offbB, awb);
  // deformable bilinear sampling v8 (fp8 value gathers)
  msda_sample<<<MROWS / 8, 256, 0, stream>>>(valbF8, offbB, awb, refp, msdaB);
  // out-projection: bf16 msda in -> bf16 attn (EPI3, into dead offb region)
  proj_mfma<256, 3, 0><<<MROWS / 32, 512, 0, stream>>>(msdaB, WoutT, b_out, nullptr, attnbB);
  // residual + LayerNorm1 (bf16 attn in, bf16 x out; x into dead region A)
  resid_ln<<<MROWS / 4, 256, 0, stream>>>(attnbB, q, g1, be1, xbB);
  // fused FFN v5b + residual + LayerNorm2 (bf16 x in)
  ffn_mfma<<<MROWS / 32, 512, 0, stream>>>(xbB, W1T, b1, W2T, b2, g2, be2, out);
}